// Round 12
// baseline (691.930 us; speedup 1.0000x reference)
//
#include <hip/hip_runtime.h>
#include <hip/hip_bf16.h>
#include <cstdint>

typedef __bf16 bf16_t;
typedef __bf16 bf16x8 __attribute__((ext_vector_type(8)));
typedef float f32x4 __attribute__((ext_vector_type(4)));

#define DEV_INLINE __device__ __forceinline__

#define NTOK 8192
#define DDIM 1024
#define HDIM 4096
#define SDIM 1024
#define NEXP 8
#define HEXP 512
#define TSEQ 2048
#define MAXTILES 136
#define MAXROWS (MAXTILES * 128)

#define VMCNT(n) asm volatile("s_waitcnt vmcnt(" #n ")" ::: "memory")
#define BARF() asm volatile("s_barrier" ::: "memory")

// ---------------- conversion: f32 -> bf16, 8 elems/thread ----------------
__global__ __launch_bounds__(256) void k_f32_to_bf16(const float* __restrict__ src,
                                                     bf16_t* __restrict__ dst, int n8) {
  int i = blockIdx.x * 256 + threadIdx.x;
  if (i >= n8) return;
  const float4* s = (const float4*)src + (size_t)i * 2;
  float4 v0 = s[0], v1 = s[1];
  bf16x8 o;
  o[0] = (bf16_t)v0.x; o[1] = (bf16_t)v0.y; o[2] = (bf16_t)v0.z; o[3] = (bf16_t)v0.w;
  o[4] = (bf16_t)v1.x; o[5] = (bf16_t)v1.y; o[6] = (bf16_t)v1.z; o[7] = (bf16_t)v1.w;
  *((bf16x8*)dst + i) = o;
}

// ------------- conv weight: [S][S][K] f32 -> [S][K*S] bf16 (k-major) -------------
__global__ __launch_bounds__(256) void k_convw(const float* __restrict__ src,
                                               bf16_t* __restrict__ dst) {
  int i = blockIdx.x * 256 + threadIdx.x;
  size_t flat = (size_t)i * 8;
  int s = (int)(flat >> 12);
  int col = (int)(flat & 4095);
  int k = col >> 10;
  int si0 = col & 1023;
  const float* sp = src + (size_t)s * 4096 + k;
  bf16x8 o;
#pragma unroll
  for (int j = 0; j < 8; ++j) o[j] = (bf16_t)sp[(size_t)(si0 + j) * 4];
  *(bf16x8*)(dst + flat) = o;
}

// ------------- MoE bookkeeping (contention-free) -------------
__global__ __launch_bounds__(256) void k_zero(int* cnt, int* fill, int* idx,
                                              bf16_t* zpad) {
  int i = blockIdx.x * 256 + threadIdx.x;
  if (i < NEXP) { cnt[i] = 0; fill[i] = 0; }
  if (i < 128) zpad[i] = (bf16_t)0.f;
  if (i < MAXROWS) idx[i] = 0;
}

__global__ __launch_bounds__(1024) void k_count(const int* __restrict__ top2e,
                                                int* __restrict__ cnt) {
  __shared__ int hist[NEXP];
  const int tid = threadIdx.x;
  if (tid < NEXP) hist[tid] = 0;
  __syncthreads();
  int c[NEXP];
#pragma unroll
  for (int e = 0; e < NEXP; ++e) c[e] = 0;
#pragma unroll
  for (int j = 0; j < 2 * NTOK / 1024; ++j) {
    int v = top2e[j * 1024 + tid];
#pragma unroll
    for (int e = 0; e < NEXP; ++e) c[e] += (v == e) ? 1 : 0;
  }
#pragma unroll
  for (int e = 0; e < NEXP; ++e)
    for (int off = 32; off; off >>= 1) c[e] += __shfl_xor(c[e], off);
  if ((tid & 63) == 0) {
#pragma unroll
    for (int e = 0; e < NEXP; ++e) atomicAdd(&hist[e], c[e]);
  }
  __syncthreads();
  if (tid < NEXP) cnt[tid] = hist[tid];
}

__global__ void k_scan(const int* __restrict__ cnt, int* __restrict__ base,
                       int* __restrict__ ntiles, int* __restrict__ tile_e,
                       int* __restrict__ tile_row) {
  if (threadIdx.x == 0 && blockIdx.x == 0) {
    int b = 0, tt = 0;
    for (int e = 0; e < NEXP; ++e) {
      base[e] = b;
      int nt = (cnt[e] + 127) >> 7;
      for (int j = 0; j < nt; ++j) { tile_e[tt] = e; tile_row[tt] = b + j * 128; ++tt; }
      b += nt * 128;
    }
    *ntiles = tt;
  }
}

// two-level scatter; also records the inverse map slotmap[token][2]
__global__ __launch_bounds__(256) void k_scatter(const int* __restrict__ top2e,
                                                 const float* __restrict__ top2w,
                                                 const int* __restrict__ base,
                                                 int* __restrict__ fill,
                                                 int* __restrict__ idx,
                                                 int* __restrict__ slotmap) {
  __shared__ int lcnt[NEXP];
  __shared__ int lbase[NEXP];
  const int tid = threadIdx.x;
  const int t = blockIdx.x * 256 + tid;
  if (tid < NEXP) lcnt[tid] = 0;
  __syncthreads();
  const int e0 = top2e[t * 2 + 0], e1 = top2e[t * 2 + 1];
  const int s0 = atomicAdd(&lcnt[e0], 1);
  const int s1 = atomicAdd(&lcnt[e1], 1);
  __syncthreads();
  if (tid < NEXP) lbase[tid] = atomicAdd(&fill[tid], lcnt[tid]);
  __syncthreads();
  const int p0 = base[e0] + lbase[e0] + s0;
  const int p1 = base[e1] + lbase[e1] + s1;
  idx[p0] = t; idx[p1] = t;
  slotmap[t * 2 + 0] = p0;
  slotmap[t * 2 + 1] = p1;
}

// ------------- router (no atomics) -------------
__global__ __launch_bounds__(256) void k_router(const float* __restrict__ x,
                                                const float* __restrict__ rW,
                                                const float* __restrict__ rb,
                                                const float* __restrict__ mW,
                                                const float* __restrict__ mb,
                                                float* __restrict__ bw3,
                                                int* __restrict__ top2e,
                                                float* __restrict__ top2w) {
  int wave = threadIdx.x >> 6, lane = threadIdx.x & 63;
  int t = blockIdx.x * 4 + wave;
  const float* xr = x + (size_t)t * DDIM;
  float xv[16];
#pragma unroll
  for (int i = 0; i < 16; i += 4) *(float4*)&xv[i] = *(const float4*)&xr[lane * 16 + i];
  float acc[11];
#pragma unroll
  for (int j = 0; j < 11; ++j) {
    const float* w = (j < 3) ? (rW + j * DDIM) : (mW + (j - 3) * DDIM);
    float s = 0.f;
#pragma unroll
    for (int i = 0; i < 16; i += 4) {
      float4 wv = *(const float4*)&w[lane * 16 + i];
      s += xv[i] * wv.x + xv[i + 1] * wv.y + xv[i + 2] * wv.z + xv[i + 3] * wv.w;
    }
    acc[j] = s;
  }
#pragma unroll
  for (int j = 0; j < 11; ++j)
    for (int off = 32; off; off >>= 1) acc[j] += __shfl_xor(acc[j], off);
  if (lane == 0) {
    float l0 = acc[0] + rb[0], l1 = acc[1] + rb[1], l2 = acc[2] + rb[2];
    float mx = fmaxf(l0, fmaxf(l1, l2));
    float e0 = expf(l0 - mx), e1 = expf(l1 - mx), e2 = expf(l2 - mx);
    float inv = 1.f / (e0 + e1 + e2);
    float w2 = e2 * inv;
    bw3[t * 3 + 0] = e0 * inv; bw3[t * 3 + 1] = e1 * inv; bw3[t * 3 + 2] = w2;
    float lg[8];
#pragma unroll
    for (int e = 0; e < 8; ++e) lg[e] = acc[3 + e] + mb[e];
    int i0 = 0;
#pragma unroll
    for (int e = 1; e < 8; ++e) if (lg[e] > lg[i0]) i0 = e;
    int i1 = -1;
#pragma unroll
    for (int e = 0; e < 8; ++e) {
      if (e == i0) continue;
      if (i1 < 0 || lg[e] > lg[i1]) i1 = e;
    }
    float ee = expf(lg[i1] - lg[i0]);
    float w0 = 1.f / (1.f + ee), w1 = ee / (1.f + ee);
    top2e[t * 2 + 0] = i0; top2e[t * 2 + 1] = i1;
    top2w[t * 2 + 0] = w2 * w0; top2w[t * 2 + 1] = w2 * w1;
  }
}

// ------------- MoE combine: out[t] += g0*eo[s0] + g1*eo[s1] (one wave/token) -------------
__global__ __launch_bounds__(256) void k_combine(const bf16_t* __restrict__ eo,
                                                 const int* __restrict__ slotmap,
                                                 const float* __restrict__ top2w,
                                                 float* __restrict__ out) {
  int wave = threadIdx.x >> 6, lane = threadIdx.x & 63;
  int t = blockIdx.x * 4 + wave;
  const int s0 = slotmap[t * 2 + 0], s1 = slotmap[t * 2 + 1];
  const float g0 = top2w[t * 2 + 0], g1 = top2w[t * 2 + 1];
  const bf16x8* r0 = (const bf16x8*)(eo + (size_t)s0 * DDIM);
  const bf16x8* r1 = (const bf16x8*)(eo + (size_t)s1 * DDIM);
  float* orow = out + (size_t)t * DDIM;
#pragma unroll
  for (int i = 0; i < 2; ++i) {
    const int d = lane + i * 64;
    bf16x8 a = r0[d], b = r1[d];
    float vo[8];
    *(float4*)&vo[0] = *(const float4*)&orow[d * 8];
    *(float4*)&vo[4] = *(const float4*)&orow[d * 8 + 4];
#pragma unroll
    for (int j = 0; j < 8; ++j) vo[j] += g0 * (float)a[j] + g1 * (float)b[j];
    *(float4*)&orow[d * 8] = *(float4*)&vo[0];
    *(float4*)&orow[d * 8 + 4] = *(float4*)&vo[4];
  }
}

// =======================================================================
// m97-style GEMM core: 128x128 tile, 256 thr = 4 waves (2x2), BK=32,
// double-buffered 32 KB LDS, plain XCD swizzle (supertile remap reverted:
// round-9 vs round-11 A/B showed it cost 8% -- latency-bound, not BW).
// Conflict-free swizzle slot' = hi^((row>>1)&3) via pre-swizzled global
// source + XOR on ds_read.
// =======================================================================
DEV_INLINE void gload16(const bf16_t* g, bf16_t* l) {
  __builtin_amdgcn_global_load_lds((const __attribute__((address_space(1))) void*)g,
                                   (__attribute__((address_space(3))) void*)l, 16, 0, 0);
}

DEV_INLINE void blockmap(int& bx, int& by) {
  const int nbx = gridDim.x, nby = gridDim.y;
  int id = blockIdx.x + nbx * blockIdx.y;
  const int nwg = nbx * nby;
  if ((nwg & 7) == 0) id = (id & 7) * (nwg >> 3) + (id >> 3);
  bx = id % nbx;
  by = id / nbx;
}

constexpr int EPI_BF16 = 0;   // Cb = bf16(v + bias[col])
constexpr int EPI_OUT_W = 1;  // Cf = scale[row]*(v+bias)
constexpr int EPI_OUT_A = 2;  // Cf += scale[row]*(v+bias)

template <int EPI>
__global__ __launch_bounds__(256) void k_gemm(
    const bf16_t* __restrict__ A, const bf16_t* __restrict__ B,
    bf16_t* __restrict__ Cb, float* __restrict__ Cf,
    const float* __restrict__ bias, const float* __restrict__ scale, int sstride,
    int N, int K) {
  constexpr int BUF = 16384;
  __shared__ __align__(16) char lds[2 * BUF];

  const int tid = threadIdx.x;
  const int lane = tid & 63;
  const int wave = tid >> 6;
  const int lr = lane & 15;
  const int hi = lane >> 4;

  int bx, by;
  blockmap(bx, by);

  const int bm = by * 128;
  const int bn = bx * 128;
  const int wm = (wave >> 1) * 64;
  const int wn = (wave & 1) * 64;

  const int srow = tid >> 2;
  const int scol = 8 * ((tid & 3) ^ ((tid >> 3) & 3));
  const bf16_t* Asrc = A + (size_t)(bm + srow) * K + scol;
  const bf16_t* Bsrc = B + (size_t)(bn + srow) * K + scol;
  const size_t r64K = (size_t)64 * K;
  const int NT = K >> 5;

  f32x4 acc[4][4];
#pragma unroll
  for (int a = 0; a < 4; ++a)
#pragma unroll
    for (int b = 0; b < 4; ++b)
#pragma unroll
      for (int j = 0; j < 4; ++j) acc[a][b][j] = 0.f;

  auto stage = [&](int t) {
    char* l = lds + (t & 1) * BUF + tid * 16;
    const bf16_t* ga = Asrc + (size_t)t * 32;
    const bf16_t* gb = Bsrc + (size_t)t * 32;
    gload16(ga, (bf16_t*)l);
    gload16(ga + r64K, (bf16_t*)(l + 4096));
    gload16(gb, (bf16_t*)(l + 8192));
    gload16(gb + r64K, (bf16_t*)(l + 12288));
  };
  auto rdA = [&](int buf, int row) -> bf16x8 {
    int off = buf + (row << 6) + ((hi ^ ((row >> 1) & 3)) << 4);
    return *(const bf16x8*)(lds + off);
  };
  auto rdB = [&](int buf, int row) -> bf16x8 {
    int off = buf + 8192 + (row << 6) + ((hi ^ ((row >> 1) & 3)) << 4);
    return *(const bf16x8*)(lds + off);
  };

  stage(0);

  for (int t = 0; t < NT; ++t) {
    VMCNT(0);
    BARF();
    const int buf = (t & 1) * BUF;
    bf16x8 bfr[4], afr[4];
#pragma unroll
    for (int ni = 0; ni < 4; ++ni) bfr[ni] = rdB(buf, wn + ni * 16 + lr);
#pragma unroll
    for (int i = 0; i < 4; ++i) afr[i] = rdA(buf, wm + i * 16 + lr);
    if (t + 1 < NT) stage(t + 1);
    __builtin_amdgcn_s_setprio(1);
#pragma unroll
    for (int i = 0; i < 4; ++i)
#pragma unroll
      for (int ni = 0; ni < 4; ++ni)
        acc[i][ni] = __builtin_amdgcn_mfma_f32_16x16x32_bf16(afr[i], bfr[ni], acc[i][ni], 0, 0, 0);
    __builtin_amdgcn_s_setprio(0);
  }

  float bv[4];
#pragma unroll
  for (int ni = 0; ni < 4; ++ni) bv[ni] = bias[bn + wn + ni * 16 + lr];
#pragma unroll
  for (int mi = 0; mi < 4; ++mi) {
#pragma unroll
    for (int j = 0; j < 4; ++j) {
      const int rowg = bm + wm + mi * 16 + hi * 4 + j;
      float sc = 0.f;
      if constexpr (EPI == EPI_OUT_W || EPI == EPI_OUT_A)
        sc = scale[(size_t)rowg * sstride];
#pragma unroll
      for (int ni = 0; ni < 4; ++ni) {
        const int colg = bn + wn + ni * 16 + lr;
        float v = acc[mi][ni][j] + bv[ni];
        if constexpr (EPI == EPI_BF16) {
          Cb[(size_t)rowg * N + colg] = (bf16_t)v;
        } else if constexpr (EPI == EPI_OUT_W) {
          Cf[(size_t)rowg * N + colg] = sc * v;
        } else {
          Cf[(size_t)rowg * N + colg] += sc * v;
        }
      }
    }
  }
}

// =======================================================================
// Dual-N fused fc1 GEMM: computes a = A@Ba^T+ba and b = A@Bb^T+bb for the
// SAME (m,n) tile in one block (A staged once, both B halves staged), then
// writes C = bf16(silu(a)*b). 32 MFMA/wave/tile (vs 16) amortizes the
// per-tile drain+barrier; kills the fc1-b intermediate round-trip.
// LDS: (8+8+8) KB x 2 buffers = 48 KB.
// =======================================================================
__global__ __launch_bounds__(256) void k_gemm_fc1(
    const bf16_t* __restrict__ A, const bf16_t* __restrict__ Ba,
    const bf16_t* __restrict__ Bb, bf16_t* __restrict__ C,
    const float* __restrict__ bias_a, const float* __restrict__ bias_b,
    int N, int K) {
  constexpr int BUF = 24576;
  __shared__ __align__(16) char lds[2 * BUF];

  const int tid = threadIdx.x;
  const int lane = tid & 63;
  const int wave = tid >> 6;
  const int lr = lane & 15;
  const int hi = lane >> 4;

  int bx, by;
  blockmap(bx, by);

  const int bm = by * 128;
  const int bn = bx * 128;
  const int wm = (wave >> 1) * 64;
  const int wn = (wave & 1) * 64;

  const int srow = tid >> 2;
  const int scol = 8 * ((tid & 3) ^ ((tid >> 3) & 3));
  const bf16_t* Asrc = A + (size_t)(bm + srow) * K + scol;
  const bf16_t* Basrc = Ba + (size_t)(bn + srow) * K + scol;
  const bf16_t* Bbsrc = Bb + (size_t)(bn + srow) * K + scol;
  const size_t r64K = (size_t)64 * K;
  const int NT = K >> 5;

  f32x4 aca[4][4], acb[4][4];
#pragma unroll
  for (int a = 0; a < 4; ++a)
#pragma unroll
    for (int b = 0; b < 4; ++b)
#pragma unroll
      for (int j = 0; j < 4; ++j) { aca[a][b][j] = 0.f; acb[a][b][j] = 0.f; }

  auto stage = [&](int t) {
    char* l = lds + (t & 1) * BUF + tid * 16;
    const bf16_t* ga = Asrc + (size_t)t * 32;
    const bf16_t* gba = Basrc + (size_t)t * 32;
    const bf16_t* gbb = Bbsrc + (size_t)t * 32;
    gload16(ga, (bf16_t*)l);
    gload16(ga + r64K, (bf16_t*)(l + 4096));
    gload16(gba, (bf16_t*)(l + 8192));
    gload16(gba + r64K, (bf16_t*)(l + 12288));
    gload16(gbb, (bf16_t*)(l + 16384));
    gload16(gbb + r64K, (bf16_t*)(l + 20480));
  };
  auto rd = [&](int base, int row) -> bf16x8 {
    int off = base + (row << 6) + ((hi ^ ((row >> 1) & 3)) << 4);
    return *(const bf16x8*)(lds + off);
  };

  stage(0);

  for (int t = 0; t < NT; ++t) {
    VMCNT(0);
    BARF();
    const int buf = (t & 1) * BUF;
    bf16x8 afr[4], bfa[4], bfb[4];
#pragma unroll
    for (int i = 0; i < 4; ++i) afr[i] = rd(buf, wm + i * 16 + lr);
#pragma unroll
    for (int ni = 0; ni < 4; ++ni) bfa[ni] = rd(buf + 8192, wn + ni * 16 + lr);
#pragma unroll
    for (int ni = 0; ni < 4; ++ni) bfb[ni] = rd(buf + 16384, wn + ni * 16 + lr);
    if (t + 1 < NT) stage(t + 1);
    __builtin_amdgcn_s_setprio(1);
#pragma unroll
    for (int i = 0; i < 4; ++i)
#pragma unroll
      for (int ni = 0; ni < 4; ++ni) {
        aca[i][ni] = __builtin_amdgcn_mfma_f32_16x16x32_bf16(afr[i], bfa[ni], aca[i][ni], 0, 0, 0);
        acb[i][ni] = __builtin_amdgcn_mfma_f32_16x16x32_bf16(afr[i], bfb[ni], acb[i][ni], 0, 0, 0);
      }
    __builtin_amdgcn_s_setprio(0);
  }

  float bva[4], bvb[4];
#pragma unroll
  for (int ni = 0; ni < 4; ++ni) {
    bva[ni] = bias_a[bn + wn + ni * 16 + lr];
    bvb[ni] = bias_b[bn + wn + ni * 16 + lr];
  }
#pragma unroll
  for (int mi = 0; mi < 4; ++mi) {
#pragma unroll
    for (int j = 0; j < 4; ++j) {
      const int rowg = bm + wm + mi * 16 + hi * 4 + j;
#pragma unroll
      for (int ni = 0; ni < 4; ++ni) {
        const int colg = bn + wn + ni * 16 + lr;
        float va = aca[mi][ni][j] + bva[ni];
        float vb = acb[mi][ni][j] + bvb[ni];
        float s = va / (1.f + __expf(-va));
        C[(size_t)rowg * N + colg] = (bf16_t)(s * vb);
      }
    }
  }
}

// =======================================================================
// Causal-conv GEMM, no im2col (round-11 proven).
// =======================================================================
__global__ __launch_bounds__(256) void k_gemm_conv(
    const bf16_t* __restrict__ h, const bf16_t* __restrict__ Bw,
    bf16_t* __restrict__ Cb, const float* __restrict__ bias,
    const bf16_t* __restrict__ zpad) {
  constexpr int N = SDIM;
  constexpr int K = SDIM * 4;
  constexpr int BUF = 16384;
  __shared__ __align__(16) char lds[2 * BUF];

  const int tid = threadIdx.x;
  const int lane = tid & 63;
  const int wave = tid >> 6;
  const int lr = lane & 15;
  const int hi = lane >> 4;

  int bx, by;
  blockmap(bx, by);

  const int bm = by * 128;
  const int bn = bx * 128;
  const int wm = (wave >> 1) * 64;
  const int wn = (wave & 1) * 64;

  const int srow = tid >> 2;
  const int scol = 8 * ((tid & 3) ^ ((tid >> 3) & 3));
  const int row0 = bm + srow;
  const int tt0 = row0 & (TSEQ - 1);
  const bf16_t* Bsrc = Bw + (size_t)(bn + srow) * K + scol;
  const size_t r64K = (size_t)64 * K;
  const int NT = K >> 5;

  f32x4 acc[4][4];
#pragma unroll
  for (int a = 0; a < 4; ++a)
#pragma unroll
    for (int b = 0; b < 4; ++b)
#pragma unroll
      for (int j = 0; j < 4; ++j) acc[a][b][j] = 0.f;

  auto stage = [&](int t) {
    char* l = lds + (t & 1) * BUF + tid * 16;
    const int k = t >> 5;
    const int si = (t & 31) * 32 + scol;
    const bf16_t* ga0 = (tt0 + k >= 3)
        ? h + (size_t)(row0 + k - 3) * SDIM + si : zpad;
    const bf16_t* ga1 = h + (size_t)(row0 + 64 + k - 3) * SDIM + si;
    gload16(ga0, (bf16_t*)l);
    gload16(ga1, (bf16_t*)(l + 4096));
    const bf16_t* gb = Bsrc + (size_t)t * 32;
    gload16(gb, (bf16_t*)(l + 8192));
    gload16(gb + r64K, (bf16_t*)(l + 12288));
  };
  auto rdA = [&](int buf, int row) -> bf16x8 {
    int off = buf + (row << 6) + ((hi ^ ((row >> 1) & 3)) << 4);
    return *(const bf16x8*)(lds + off);
  };
  auto rdB = [&](int buf, int row) -> bf16x8 {
    int off = buf + 8192 + (row << 6) + ((hi ^ ((row >> 1) & 3)) << 4);
    return *(const bf16x8*)(lds + off);
  };

  stage(0);

  for (int t = 0; t < NT; ++t) {
    VMCNT(0);
    BARF();
    const int buf = (t & 1) * BUF;
    bf16x8 bfr[4], afr[4];
#pragma unroll
    for (int ni = 0; ni < 4; ++ni) bfr[ni] = rdB(buf, wn + ni * 16 + lr);
#pragma unroll
    for (int i = 0; i < 4; ++i) afr[i] = rdA(buf, wm + i * 16 + lr);
    if (t + 1 < NT) stage(t + 1);
    __builtin_amdgcn_s_setprio(1);
#pragma unroll
    for (int i = 0; i < 4; ++i)
#pragma unroll
      for (int ni = 0; ni < 4; ++ni)
        acc[i][ni] = __builtin_amdgcn_mfma_f32_16x16x32_bf16(afr[i], bfr[ni], acc[i][ni], 0, 0, 0);
    __builtin_amdgcn_s_setprio(0);
  }

  float bv[4];
#pragma unroll
  for (int ni = 0; ni < 4; ++ni) bv[ni] = bias[bn + wn + ni * 16 + lr];
#pragma unroll
  for (int mi = 0; mi < 4; ++mi) {
#pragma unroll
    for (int j = 0; j < 4; ++j) {
      const int rowg = bm + wm + mi * 16 + hi * 4 + j;
#pragma unroll
      for (int ni = 0; ni < 4; ++ni) {
        const int colg = bn + wn + ni * 16 + lr;
        Cb[(size_t)rowg * N + colg] = (bf16_t)(acc[mi][ni][j] + bv[ni]);
      }
    }
  }
}

// =======================================================================
// Dual-N fused MoE fc1: gathered A rows, both weight halves, fused swiglu.
// Writes Cc[slot][HEXP]. Same structure as k_gemm_fc1.
// =======================================================================
__global__ __launch_bounds__(256) void k_moe_fc1(
    const bf16_t* __restrict__ A, const bf16_t* __restrict__ Bw, size_t zB,
    bf16_t* __restrict__ C, const float* __restrict__ bias, int bstride,
    const int* __restrict__ ntiles_p, const int* __restrict__ tile_e,
    const int* __restrict__ tile_row, const int* __restrict__ idx,
    int N, int K) {
  constexpr int BUF = 24576;
  __shared__ __align__(16) char lds[2 * BUF];

  const int tid = threadIdx.x;
  const int lane = tid & 63;
  const int wave = tid >> 6;
  const int lr = lane & 15;
  const int hi = lane >> 4;

  const int nbx = gridDim.x, nby = gridDim.y;
  int id = blockIdx.x + nbx * blockIdx.y;
  const int nwg = nbx * nby;
  if ((nwg & 7) == 0) id = (id & 7) * (nwg >> 3) + (id >> 3);
  const int bx = id % nbx;
  const int by = id / nbx;

  const int ntiles = *ntiles_p;
  if (bx >= ntiles) return;
  const int e = tile_e[bx];
  const int bm = tile_row[bx];
  const int bn = by * 128;
  const int wm = (wave >> 1) * 64;
  const int wn = (wave & 1) * 64;

  const int srow = tid >> 2;
  const int scol = 8 * ((tid & 3) ^ ((tid >> 3) & 3));
  const int atok0 = idx[bm + srow];
  const int atok1 = idx[bm + srow + 64];
  const bf16_t* Asrc0 = A + (size_t)atok0 * K + scol;
  const bf16_t* Asrc1 = A + (size_t)atok1 * K + scol;
  const bf16_t* Basrc = Bw + (size_t)e * zB + (size_t)(bn + srow) * K + scol;
  const bf16_t* Bbsrc = Basrc + (size_t)HEXP * K;
  const size_t r64K = (size_t)64 * K;
  const int NT = K >> 5;

  f32x4 aca[4][4], acb[4][4];
#pragma unroll
  for (int a = 0; a < 4; ++a)
#pragma unroll
    for (int b = 0; b < 4; ++b)
#pragma unroll
      for (int j = 0; j < 4; ++j) { aca[a][b][j] = 0.f; acb[a][b][j] = 0.f; }

  auto stage = [&](int t) {
    char* l = lds + (t & 1) * BUF + tid * 16;
    gload16(Asrc0 + (size_t)t * 32, (bf16_t*)l);
    gload16(Asrc1 + (size_t)t * 32, (bf16_t*)(l + 4096));
    gload16(Basrc + (size_t)t * 32, (bf16_t*)(l + 8192));
    gload16(Basrc + (size_t)t * 32 + r64K, (bf16_t*)(l + 12288));
    gload16(Bbsrc + (size_t)t * 32, (bf16_t*)(l + 16384));
    gload16(Bbsrc + (size_t)t * 32 + r64K, (bf16_t*)(l + 20480));
  };
  auto rd = [&](int base, int row) -> bf16x8 {
    int off = base + (row << 6) + ((hi ^ ((row >> 1) & 3)) << 4);
    return *(const bf16x8*)(lds + off);
  };

  stage(0);

  for (int t = 0; t < NT; ++t) {
    VMCNT(0);
    BARF();
    const int buf = (t & 1) * BUF;
    bf16x8 afr[4], bfa[4], bfb[4];
#pragma unroll
    for (int i = 0; i < 4; ++i) afr[i] = rd(buf, wm + i * 16 + lr);
#pragma unroll
    for (int ni = 0; ni < 4; ++ni) bfa[ni] = rd(buf + 8192, wn + ni * 16 + lr);
#pragma unroll
    for (int ni = 0; ni < 4; ++ni) bfb[ni] = rd(buf + 16384, wn + ni * 16 + lr);
    if (t + 1 < NT) stage(t + 1);
    __builtin_amdgcn_s_setprio(1);
#pragma unroll
    for (int i = 0; i < 4; ++i)
#pragma unroll
      for (int ni = 0; ni < 4; ++ni) {
        aca[i][ni] = __builtin_amdgcn_mfma_f32_16x16x32_bf16(afr[i], bfa[ni], aca[i][ni], 0, 0, 0);
        acb[i][ni] = __builtin_amdgcn_mfma_f32_16x16x32_bf16(afr[i], bfb[ni], acb[i][ni], 0, 0, 0);
      }
    __builtin_amdgcn_s_setprio(0);
  }

  const float* bpa = bias + (size_t)e * bstride;
  const float* bpb = bpa + HEXP;
  float bva[4], bvb[4];
#pragma unroll
  for (int ni = 0; ni < 4; ++ni) {
    bva[ni] = bpa[bn + wn + ni * 16 + lr];
    bvb[ni] = bpb[bn + wn + ni * 16 + lr];
  }
#pragma unroll
  for (int mi = 0; mi < 4; ++mi) {
#pragma unroll
    for (int j = 0; j < 4; ++j) {
      const int slot = bm + wm + mi * 16 + hi * 4 + j;
#pragma unroll
      for (int ni = 0; ni < 4; ++ni) {
        const int colg = bn + wn + ni * 16 + lr;
        float va = aca[mi][ni][j] + bva[ni];
        float vb = acb[mi][ni][j] + bvb[ni];
        float s = va / (1.f + __expf(-va));
        C[(size_t)slot * N + colg] = (bf16_t)(s * vb);
      }
    }
  }
}

// =======================================================================
// MoE fc2: slot-linear A, writes bf16 slot rows eo (combined by k_combine).
// =======================================================================
__global__ __launch_bounds__(256) void k_moe_fc2(
    const bf16_t* __restrict__ A, const bf16_t* __restrict__ Bw, size_t zB,
    bf16_t* __restrict__ Cb, const float* __restrict__ bias, int bstride,
    const int* __restrict__ ntiles_p, const int* __restrict__ tile_e,
    const int* __restrict__ tile_row,
    int N, int K) {
  constexpr int BUF = 16384;
  __shared__ __align__(16) char lds[2 * BUF];

  const int tid = threadIdx.x;
  const int lane = tid & 63;
  const int wave = tid >> 6;
  const int lr = lane & 15;
  const int hi = lane >> 4;

  const int nbx = gridDim.x, nby = gridDim.y;
  int id = blockIdx.x + nbx * blockIdx.y;
  const int nwg = nbx * nby;
  if ((nwg & 7) == 0) id = (id & 7) * (nwg >> 3) + (id >> 3);
  const int bx = id % nbx;
  const int by = id / nbx;

  const int ntiles = *ntiles_p;
  if (bx >= ntiles) return;
  const int e = tile_e[bx];
  const int bm = tile_row[bx];
  const int bn = by * 128;
  const int wm = (wave >> 1) * 64;
  const int wn = (wave & 1) * 64;

  const int srow = tid >> 2;
  const int scol = 8 * ((tid & 3) ^ ((tid >> 3) & 3));
  const bf16_t* Asrc = A + (size_t)(bm + srow) * K + scol;
  const bf16_t* Bsrc = Bw + (size_t)e * zB + (size_t)(bn + srow) * K + scol;
  const size_t r64K = (size_t)64 * K;
  const int NT = K >> 5;

  f32x4 acc[4][4];
#pragma unroll
  for (int a = 0; a < 4; ++a)
#pragma unroll
    for (int b = 0; b < 4; ++b)
#pragma unroll
      for (int j = 0; j < 4; ++j) acc[a][b][j] = 0.f;

  auto stage = [&](int t) {
    char* l = lds + (t & 1) * BUF + tid * 16;
    gload16(Asrc + (size_t)t * 32, (bf16_t*)l);
    gload16(Asrc + (size_t)t * 32 + r64K, (bf16_t*)(l + 4096));
    gload16(Bsrc + (size_t)t * 32, (bf16_t*)(l + 8192));
    gload16(Bsrc + (size_t)t * 32 + r64K, (bf16_t*)(l + 12288));
  };
  auto rdA = [&](int buf, int row) -> bf16x8 {
    int off = buf + (row << 6) + ((hi ^ ((row >> 1) & 3)) << 4);
    return *(const bf16x8*)(lds + off);
  };
  auto rdB = [&](int buf, int row) -> bf16x8 {
    int off = buf + 8192 + (row << 6) + ((hi ^ ((row >> 1) & 3)) << 4);
    return *(const bf16x8*)(lds + off);
  };

  stage(0);

  for (int t = 0; t < NT; ++t) {
    VMCNT(0);
    BARF();
    const int buf = (t & 1) * BUF;
    bf16x8 bfr[4], afr[4];
#pragma unroll
    for (int ni = 0; ni < 4; ++ni) bfr[ni] = rdB(buf, wn + ni * 16 + lr);
#pragma unroll
    for (int i = 0; i < 4; ++i) afr[i] = rdA(buf, wm + i * 16 + lr);
    if (t + 1 < NT) stage(t + 1);
    __builtin_amdgcn_s_setprio(1);
#pragma unroll
    for (int i = 0; i < 4; ++i)
#pragma unroll
      for (int ni = 0; ni < 4; ++ni)
        acc[i][ni] = __builtin_amdgcn_mfma_f32_16x16x32_bf16(afr[i], bfr[ni], acc[i][ni], 0, 0, 0);
    __builtin_amdgcn_s_setprio(0);
  }

  const float* bp = bias + (size_t)e * bstride;
  float bv[4];
#pragma unroll
  for (int ni = 0; ni < 4; ++ni) bv[ni] = bp[bn + wn + ni * 16 + lr];
#pragma unroll
  for (int mi = 0; mi < 4; ++mi) {
#pragma unroll
    for (int j = 0; j < 4; ++j) {
      const int slot = bm + wm + mi * 16 + hi * 4 + j;
#pragma unroll
      for (int ni = 0; ni < 4; ++ni) {
        const int colg = bn + wn + ni * 16 + lr;
        Cb[(size_t)slot * N + colg] = (bf16_t)(acc[mi][ni][j] + bv[ni]);
      }
    }
  }
}

// ---------------------------------------------------------------------------
extern "C" void kernel_launch(void* const* d_in, const int* in_sizes, int n_in,
                              void* d_out, int out_size, void* d_ws, size_t ws_size,
                              hipStream_t stream) {
  (void)in_sizes; (void)n_in; (void)out_size; (void)ws_size;
  const float* x    = (const float*)d_in[0];
  const float* rW   = (const float*)d_in[1];
  const float* rb   = (const float*)d_in[2];
  const float* d1W  = (const float*)d_in[3];
  const float* d1b  = (const float*)d_in[4];
  const float* d2W  = (const float*)d_in[5];
  const float* d2b  = (const float*)d_in[6];
  const float* sWin = (const float*)d_in[7];
  const float* sbin = (const float*)d_in[8];
  const float* sWc  = (const float*)d_in[9];
  const float* sbc  = (const float*)d_in[10];
  const float* sWo  = (const float*)d_in[11];
  const float* sbo  = (const float*)d_in[12];
  const float* mW   = (const float*)d_in[13];
  const float* mb   = (const float*)d_in[14];
  const float* eW1  = (const float*)d_in[15];
  const float* eb1  = (const float*)d_in[16];
  const float* eW2  = (const float*)d_in[17];
  const float* eb2  = (const float*)d_in[18];
  float* out = (float*)d_out;

  char* ws = (char*)d_ws;
  size_t off = 0;
  auto alloc = [&](size_t bytes) -> void* {
    void* p = ws + off;
    off += (bytes + 255) & ~(size_t)255;
    return p;
  };
  bf16_t* xb    = (bf16_t*)alloc((size_t)NTOK * DDIM * 2);
  bf16_t* wd1   = (bf16_t*)alloc((size_t)2 * HDIM * DDIM * 2);
  bf16_t* wd2   = (bf16_t*)alloc((size_t)DDIM * HDIM * 2);
  bf16_t* wsin  = (bf16_t*)alloc((size_t)SDIM * DDIM * 2);
  bf16_t* wconv = (bf16_t*)alloc((size_t)SDIM * SDIM * 4 * 2);
  bf16_t* wsout = (bf16_t*)alloc((size_t)DDIM * SDIM * 2);
  bf16_t* we1   = (bf16_t*)alloc((size_t)NEXP * 2 * HEXP * DDIM * 2);
  bf16_t* we2   = (bf16_t*)alloc((size_t)NEXP * DDIM * HEXP * 2);
  bf16_t* Cc    = (bf16_t*)alloc((size_t)NTOK * HDIM * 2);  // dense swiglu | MoE swiglu (slot)
  bf16_t* Dd    = (bf16_t*)alloc((size_t)NTOK * HDIM * 2);  // eo (MoE fc2 slot rows)
  bf16_t* th    = (bf16_t*)alloc((size_t)NTOK * SDIM * 2);
  bf16_t* tsq   = (bf16_t*)alloc((size_t)NTOK * SDIM * 2);
  float*  bw3   = (float*)alloc((size_t)NTOK * 3 * 4);
  int*    top2e = (int*)alloc((size_t)NTOK * 2 * 4);
  float*  top2w = (float*)alloc((size_t)NTOK * 2 * 4);
  int*    slotm = (int*)alloc((size_t)NTOK * 2 * 4);
  int*    cnt   = (int*)alloc(NEXP * 4);
  int*    fill  = (int*)alloc(NEXP * 4);
  int*    basep = (int*)alloc((NEXP + 1) * 4);
  int*    ntl   = (int*)alloc(4);
  int*    t_e   = (int*)alloc(MAXTILES * 4);
  int*    t_row = (int*)alloc(MAXTILES * 4);
  int*    idx   = (int*)alloc(MAXROWS * 4);
  bf16_t* zpad  = (bf16_t*)alloc(256);
  bf16_t* eo    = Dd;

  // conversions + router + MoE bookkeeping
  k_f32_to_bf16<<<4096, 256, 0, stream>>>(x, xb, NTOK * DDIM / 8);
  k_f32_to_bf16<<<4096, 256, 0, stream>>>(d1W, wd1, 2 * HDIM * DDIM / 8);
  k_f32_to_bf16<<<2048, 256, 0, stream>>>(d2W, wd2, DDIM * HDIM / 8);
  k_f32_to_bf16<<<512, 256, 0, stream>>>(sWin, wsin, SDIM * DDIM / 8);
  k_convw<<<2048, 256, 0, stream>>>(sWc, wconv);
  k_f32_to_bf16<<<512, 256, 0, stream>>>(sWo, wsout, DDIM * SDIM / 8);
  k_f32_to_bf16<<<4096, 256, 0, stream>>>(eW1, we1, NEXP * 2 * HEXP * DDIM / 8);
  k_f32_to_bf16<<<2048, 256, 0, stream>>>(eW2, we2, NEXP * DDIM * HEXP / 8);
  k_zero<<<(MAXROWS + 255) / 256, 256, 0, stream>>>(cnt, fill, idx, zpad);
  k_router<<<2048, 256, 0, stream>>>(x, rW, rb, mW, mb, bw3, top2e, top2w);
  k_count<<<1, 1024, 0, stream>>>(top2e, cnt);
  k_scan<<<1, 64, 0, stream>>>(cnt, basep, ntl, t_e, t_row);
  k_scatter<<<NTOK / 256, 256, 0, stream>>>(top2e, top2w, basep, fill, idx, slotm);

  // ---- dense branch: fused fc1(a,b)+swiglu, then d2 -> out ('=') ----
  k_gemm_fc1<<<dim3(32, 64), 256, 0, stream>>>(
      xb, wd1, wd1 + (size_t)HDIM * DDIM, Cc, d1b, d1b + HDIM, HDIM, DDIM);
  k_gemm<EPI_OUT_W><<<dim3(8, 64), 256, 0, stream>>>(
      Cc, wd2, nullptr, out, d2b, bw3, 3, DDIM, HDIM);

  // ---- sparse MoE: fused fc1+swiglu, fc2 -> eo, combine ----
  k_moe_fc1<<<dim3(MAXTILES, 4), 256, 0, stream>>>(
      xb, we1, (size_t)2 * HEXP * DDIM, Cc, eb1, 2 * HEXP,
      ntl, t_e, t_row, idx, HEXP, DDIM);
  k_moe_fc2<<<dim3(MAXTILES, 8), 256, 0, stream>>>(
      Cc, we2, (size_t)DDIM * HEXP, eo, eb2, DDIM,
      ntl, t_e, t_row, DDIM, HEXP);
  k_combine<<<NTOK / 4, 256, 0, stream>>>(eo, slotm, top2w, out);

  // ---- SSM branch (conv reads th directly, no im2col) ----
  k_gemm<EPI_BF16><<<dim3(8, 64), 256, 0, stream>>>(
      xb, wsin, th, nullptr, sbin, nullptr, 0, SDIM, DDIM);
  k_gemm_conv<<<dim3(8, 64), 256, 0, stream>>>(th, wconv, tsq, sbc, zpad);
  k_gemm<EPI_OUT_A><<<dim3(8, 64), 256, 0, stream>>>(
      tsq, wsout, nullptr, out, sbo, bw3 + 1, 3, DDIM, SDIM);
}

// Round 13
// 594.143 us; speedup vs baseline: 1.1646x; 1.1646x over previous
//
#include <hip/hip_runtime.h>
#include <hip/hip_bf16.h>
#include <cstdint>

typedef __bf16 bf16_t;
typedef __bf16 bf16x8 __attribute__((ext_vector_type(8)));
typedef float f32x4 __attribute__((ext_vector_type(4)));

#define DEV_INLINE __device__ __forceinline__

#define NTOK 8192
#define DDIM 1024
#define HDIM 4096
#define SDIM 1024
#define NEXP 8
#define HEXP 512
#define TSEQ 2048
#define MAXTILES 136
#define MAXROWS (MAXTILES * 128)

#define VMCNT(n) asm volatile("s_waitcnt vmcnt(" #n ")" ::: "memory")
#define BARF() asm volatile("s_barrier" ::: "memory")

// ---------------- conversion: f32 -> bf16, 8 elems/thread ----------------
__global__ __launch_bounds__(256) void k_f32_to_bf16(const float* __restrict__ src,
                                                     bf16_t* __restrict__ dst, int n8) {
  int i = blockIdx.x * 256 + threadIdx.x;
  if (i >= n8) return;
  const float4* s = (const float4*)src + (size_t)i * 2;
  float4 v0 = s[0], v1 = s[1];
  bf16x8 o;
  o[0] = (bf16_t)v0.x; o[1] = (bf16_t)v0.y; o[2] = (bf16_t)v0.z; o[3] = (bf16_t)v0.w;
  o[4] = (bf16_t)v1.x; o[5] = (bf16_t)v1.y; o[6] = (bf16_t)v1.z; o[7] = (bf16_t)v1.w;
  *((bf16x8*)dst + i) = o;
}

// ------------- conv weight: [S][S][K] f32 -> [S][K*S] bf16 (k-major) -------------
__global__ __launch_bounds__(256) void k_convw(const float* __restrict__ src,
                                               bf16_t* __restrict__ dst) {
  int i = blockIdx.x * 256 + threadIdx.x;
  size_t flat = (size_t)i * 8;
  int s = (int)(flat >> 12);
  int col = (int)(flat & 4095);
  int k = col >> 10;
  int si0 = col & 1023;
  const float* sp = src + (size_t)s * 4096 + k;
  bf16x8 o;
#pragma unroll
  for (int j = 0; j < 8; ++j) o[j] = (bf16_t)sp[(size_t)(si0 + j) * 4];
  *(bf16x8*)(dst + flat) = o;
}

// ------------- MoE bookkeeping (contention-free) -------------
__global__ __launch_bounds__(256) void k_zero(int* cnt, int* fill, int* idx,
                                              bf16_t* zpad) {
  int i = blockIdx.x * 256 + threadIdx.x;
  if (i < NEXP) { cnt[i] = 0; fill[i] = 0; }
  if (i < 128) zpad[i] = (bf16_t)0.f;
  if (i < MAXROWS) idx[i] = 0;
}

__global__ __launch_bounds__(1024) void k_count(const int* __restrict__ top2e,
                                                int* __restrict__ cnt) {
  __shared__ int hist[NEXP];
  const int tid = threadIdx.x;
  if (tid < NEXP) hist[tid] = 0;
  __syncthreads();
  int c[NEXP];
#pragma unroll
  for (int e = 0; e < NEXP; ++e) c[e] = 0;
#pragma unroll
  for (int j = 0; j < 2 * NTOK / 1024; ++j) {
    int v = top2e[j * 1024 + tid];
#pragma unroll
    for (int e = 0; e < NEXP; ++e) c[e] += (v == e) ? 1 : 0;
  }
#pragma unroll
  for (int e = 0; e < NEXP; ++e)
    for (int off = 32; off; off >>= 1) c[e] += __shfl_xor(c[e], off);
  if ((tid & 63) == 0) {
#pragma unroll
    for (int e = 0; e < NEXP; ++e) atomicAdd(&hist[e], c[e]);
  }
  __syncthreads();
  if (tid < NEXP) cnt[tid] = hist[tid];
}

__global__ void k_scan(const int* __restrict__ cnt, int* __restrict__ base,
                       int* __restrict__ ntiles, int* __restrict__ tile_e,
                       int* __restrict__ tile_row) {
  if (threadIdx.x == 0 && blockIdx.x == 0) {
    int b = 0, tt = 0;
    for (int e = 0; e < NEXP; ++e) {
      base[e] = b;
      int nt = (cnt[e] + 127) >> 7;
      for (int j = 0; j < nt; ++j) { tile_e[tt] = e; tile_row[tt] = b + j * 128; ++tt; }
      b += nt * 128;
    }
    *ntiles = tt;
  }
}

// two-level scatter; also records the inverse map slotmap[token][2]
__global__ __launch_bounds__(256) void k_scatter(const int* __restrict__ top2e,
                                                 const float* __restrict__ top2w,
                                                 const int* __restrict__ base,
                                                 int* __restrict__ fill,
                                                 int* __restrict__ idx,
                                                 int* __restrict__ slotmap) {
  __shared__ int lcnt[NEXP];
  __shared__ int lbase[NEXP];
  const int tid = threadIdx.x;
  const int t = blockIdx.x * 256 + tid;
  if (tid < NEXP) lcnt[tid] = 0;
  __syncthreads();
  const int e0 = top2e[t * 2 + 0], e1 = top2e[t * 2 + 1];
  const int s0 = atomicAdd(&lcnt[e0], 1);
  const int s1 = atomicAdd(&lcnt[e1], 1);
  __syncthreads();
  if (tid < NEXP) lbase[tid] = atomicAdd(&fill[tid], lcnt[tid]);
  __syncthreads();
  const int p0 = base[e0] + lbase[e0] + s0;
  const int p1 = base[e1] + lbase[e1] + s1;
  idx[p0] = t; idx[p1] = t;
  slotmap[t * 2 + 0] = p0;
  slotmap[t * 2 + 1] = p1;
}

// ------------- router (no atomics) -------------
__global__ __launch_bounds__(256) void k_router(const float* __restrict__ x,
                                                const float* __restrict__ rW,
                                                const float* __restrict__ rb,
                                                const float* __restrict__ mW,
                                                const float* __restrict__ mb,
                                                float* __restrict__ bw3,
                                                int* __restrict__ top2e,
                                                float* __restrict__ top2w) {
  int wave = threadIdx.x >> 6, lane = threadIdx.x & 63;
  int t = blockIdx.x * 4 + wave;
  const float* xr = x + (size_t)t * DDIM;
  float xv[16];
#pragma unroll
  for (int i = 0; i < 16; i += 4) *(float4*)&xv[i] = *(const float4*)&xr[lane * 16 + i];
  float acc[11];
#pragma unroll
  for (int j = 0; j < 11; ++j) {
    const float* w = (j < 3) ? (rW + j * DDIM) : (mW + (j - 3) * DDIM);
    float s = 0.f;
#pragma unroll
    for (int i = 0; i < 16; i += 4) {
      float4 wv = *(const float4*)&w[lane * 16 + i];
      s += xv[i] * wv.x + xv[i + 1] * wv.y + xv[i + 2] * wv.z + xv[i + 3] * wv.w;
    }
    acc[j] = s;
  }
#pragma unroll
  for (int j = 0; j < 11; ++j)
    for (int off = 32; off; off >>= 1) acc[j] += __shfl_xor(acc[j], off);
  if (lane == 0) {
    float l0 = acc[0] + rb[0], l1 = acc[1] + rb[1], l2 = acc[2] + rb[2];
    float mx = fmaxf(l0, fmaxf(l1, l2));
    float e0 = expf(l0 - mx), e1 = expf(l1 - mx), e2 = expf(l2 - mx);
    float inv = 1.f / (e0 + e1 + e2);
    float w2 = e2 * inv;
    bw3[t * 3 + 0] = e0 * inv; bw3[t * 3 + 1] = e1 * inv; bw3[t * 3 + 2] = w2;
    float lg[8];
#pragma unroll
    for (int e = 0; e < 8; ++e) lg[e] = acc[3 + e] + mb[e];
    int i0 = 0;
#pragma unroll
    for (int e = 1; e < 8; ++e) if (lg[e] > lg[i0]) i0 = e;
    int i1 = -1;
#pragma unroll
    for (int e = 0; e < 8; ++e) {
      if (e == i0) continue;
      if (i1 < 0 || lg[e] > lg[i1]) i1 = e;
    }
    float ee = expf(lg[i1] - lg[i0]);
    float w0 = 1.f / (1.f + ee), w1 = ee / (1.f + ee);
    top2e[t * 2 + 0] = i0; top2e[t * 2 + 1] = i1;
    top2w[t * 2 + 0] = w2 * w0; top2w[t * 2 + 1] = w2 * w1;
  }
}

// ------------- MoE combine: out[t] += g0*eo[s0] + g1*eo[s1] (one wave/token) -------------
__global__ __launch_bounds__(256) void k_combine(const bf16_t* __restrict__ eo,
                                                 const int* __restrict__ slotmap,
                                                 const float* __restrict__ top2w,
                                                 float* __restrict__ out) {
  int wave = threadIdx.x >> 6, lane = threadIdx.x & 63;
  int t = blockIdx.x * 4 + wave;
  const int s0 = slotmap[t * 2 + 0], s1 = slotmap[t * 2 + 1];
  const float g0 = top2w[t * 2 + 0], g1 = top2w[t * 2 + 1];
  const bf16x8* r0 = (const bf16x8*)(eo + (size_t)s0 * DDIM);
  const bf16x8* r1 = (const bf16x8*)(eo + (size_t)s1 * DDIM);
  float* orow = out + (size_t)t * DDIM;
#pragma unroll
  for (int i = 0; i < 2; ++i) {
    const int d = lane + i * 64;
    bf16x8 a = r0[d], b = r1[d];
    float vo[8];
    *(float4*)&vo[0] = *(const float4*)&orow[d * 8];
    *(float4*)&vo[4] = *(const float4*)&orow[d * 8 + 4];
#pragma unroll
    for (int j = 0; j < 8; ++j) vo[j] += g0 * (float)a[j] + g1 * (float)b[j];
    *(float4*)&orow[d * 8] = *(float4*)&vo[0];
    *(float4*)&orow[d * 8 + 4] = *(float4*)&vo[4];
  }
}

// =======================================================================
// m97-style GEMM core: 128x128 tile, 256 thr = 4 waves (2x2), BK=32,
// double-buffered 32 KB LDS, plain XCD swizzle. Conflict-free LDS swizzle
// slot' = hi^((row>>1)&3) via pre-swizzled global source + XOR on ds_read.
// =======================================================================
DEV_INLINE void gload16(const bf16_t* g, bf16_t* l) {
  __builtin_amdgcn_global_load_lds((const __attribute__((address_space(1))) void*)g,
                                   (__attribute__((address_space(3))) void*)l, 16, 0, 0);
}

DEV_INLINE void blockmap(int& bx, int& by) {
  const int nbx = gridDim.x, nby = gridDim.y;
  int id = blockIdx.x + nbx * blockIdx.y;
  const int nwg = nbx * nby;
  if ((nwg & 7) == 0) id = (id & 7) * (nwg >> 3) + (id >> 3);
  bx = id % nbx;
  by = id / nbx;
}

constexpr int EPI_BF16 = 0;   // Cb = bf16(v + bias[col])
constexpr int EPI_OUT_W = 1;  // Cf = scale[row]*(v+bias)
constexpr int EPI_OUT_A = 2;  // Cf += scale[row]*(v+bias)

template <int EPI>
__global__ __launch_bounds__(256) void k_gemm(
    const bf16_t* __restrict__ A, const bf16_t* __restrict__ B,
    bf16_t* __restrict__ Cb, float* __restrict__ Cf,
    const float* __restrict__ bias, const float* __restrict__ scale, int sstride,
    int N, int K) {
  constexpr int BUF = 16384;
  __shared__ __align__(16) char lds[2 * BUF];

  const int tid = threadIdx.x;
  const int lane = tid & 63;
  const int wave = tid >> 6;
  const int lr = lane & 15;
  const int hi = lane >> 4;

  int bx, by;
  blockmap(bx, by);

  const int bm = by * 128;
  const int bn = bx * 128;
  const int wm = (wave >> 1) * 64;
  const int wn = (wave & 1) * 64;

  const int srow = tid >> 2;
  const int scol = 8 * ((tid & 3) ^ ((tid >> 3) & 3));
  const bf16_t* Asrc = A + (size_t)(bm + srow) * K + scol;
  const bf16_t* Bsrc = B + (size_t)(bn + srow) * K + scol;
  const size_t r64K = (size_t)64 * K;
  const int NT = K >> 5;

  f32x4 acc[4][4];
#pragma unroll
  for (int a = 0; a < 4; ++a)
#pragma unroll
    for (int b = 0; b < 4; ++b)
#pragma unroll
      for (int j = 0; j < 4; ++j) acc[a][b][j] = 0.f;

  auto stage = [&](int t) {
    char* l = lds + (t & 1) * BUF + tid * 16;
    const bf16_t* ga = Asrc + (size_t)t * 32;
    const bf16_t* gb = Bsrc + (size_t)t * 32;
    gload16(ga, (bf16_t*)l);
    gload16(ga + r64K, (bf16_t*)(l + 4096));
    gload16(gb, (bf16_t*)(l + 8192));
    gload16(gb + r64K, (bf16_t*)(l + 12288));
  };
  auto rdA = [&](int buf, int row) -> bf16x8 {
    int off = buf + (row << 6) + ((hi ^ ((row >> 1) & 3)) << 4);
    return *(const bf16x8*)(lds + off);
  };
  auto rdB = [&](int buf, int row) -> bf16x8 {
    int off = buf + 8192 + (row << 6) + ((hi ^ ((row >> 1) & 3)) << 4);
    return *(const bf16x8*)(lds + off);
  };

  stage(0);

  for (int t = 0; t < NT; ++t) {
    VMCNT(0);
    BARF();
    const int buf = (t & 1) * BUF;
    bf16x8 bfr[4], afr[4];
#pragma unroll
    for (int ni = 0; ni < 4; ++ni) bfr[ni] = rdB(buf, wn + ni * 16 + lr);
#pragma unroll
    for (int i = 0; i < 4; ++i) afr[i] = rdA(buf, wm + i * 16 + lr);
    if (t + 1 < NT) stage(t + 1);
    __builtin_amdgcn_s_setprio(1);
#pragma unroll
    for (int i = 0; i < 4; ++i)
#pragma unroll
      for (int ni = 0; ni < 4; ++ni)
        acc[i][ni] = __builtin_amdgcn_mfma_f32_16x16x32_bf16(afr[i], bfr[ni], acc[i][ni], 0, 0, 0);
    __builtin_amdgcn_s_setprio(0);
  }

  float bv[4];
#pragma unroll
  for (int ni = 0; ni < 4; ++ni) bv[ni] = bias[bn + wn + ni * 16 + lr];
#pragma unroll
  for (int mi = 0; mi < 4; ++mi) {
#pragma unroll
    for (int j = 0; j < 4; ++j) {
      const int rowg = bm + wm + mi * 16 + hi * 4 + j;
      float sc = 0.f;
      if constexpr (EPI == EPI_OUT_W || EPI == EPI_OUT_A)
        sc = scale[(size_t)rowg * sstride];
#pragma unroll
      for (int ni = 0; ni < 4; ++ni) {
        const int colg = bn + wn + ni * 16 + lr;
        float v = acc[mi][ni][j] + bv[ni];
        if constexpr (EPI == EPI_BF16) {
          Cb[(size_t)rowg * N + colg] = (bf16_t)v;
        } else if constexpr (EPI == EPI_OUT_W) {
          Cf[(size_t)rowg * N + colg] = sc * v;
        } else {
          Cf[(size_t)rowg * N + colg] += sc * v;
        }
      }
    }
  }
}

// =======================================================================
// Fused fc1, BN=64 per half: tile = 128M x (64a + 64b). Per-wave acc =
// 2 x [4][2] f32x4 = 64 regs == plain k_gemm (no occupancy cliff; the
// round-12 BN=128 fusion hit VGPR 148+128acc -> 1 wave/SIMD, 287us).
// Per-tile cost identical to plain k_gemm (16 MFMA, 8 ds_reads, 4 stage
// loads/thread, 32 KB LDS); A staged once for both halves, no Dd
// round-trip, swiglu in-register.
// =======================================================================
__global__ __launch_bounds__(256) void k_gemm_fc1(
    const bf16_t* __restrict__ A, const bf16_t* __restrict__ Ba,
    const bf16_t* __restrict__ Bb, bf16_t* __restrict__ C,
    const float* __restrict__ bias_a, const float* __restrict__ bias_b,
    int N, int K) {
  constexpr int BUF = 16384;
  __shared__ __align__(16) char lds[2 * BUF];

  const int tid = threadIdx.x;
  const int lane = tid & 63;
  const int wave = tid >> 6;
  const int lr = lane & 15;
  const int hi = lane >> 4;

  int bx, by;
  blockmap(bx, by);

  const int bm = by * 128;
  const int bn = bx * 64;
  const int wm = (wave >> 1) * 64;
  const int wn = (wave & 1) * 32;

  const int srow = tid >> 2;
  const int scol = 8 * ((tid & 3) ^ ((tid >> 3) & 3));
  const bf16_t* Asrc = A + (size_t)(bm + srow) * K + scol;
  const bf16_t* Basrc = Ba + (size_t)(bn + srow) * K + scol;
  const bf16_t* Bbsrc = Bb + (size_t)(bn + srow) * K + scol;
  const size_t r64K = (size_t)64 * K;
  const int NT = K >> 5;

  f32x4 aca[4][2], acb[4][2];
#pragma unroll
  for (int a = 0; a < 4; ++a)
#pragma unroll
    for (int b = 0; b < 2; ++b)
#pragma unroll
      for (int j = 0; j < 4; ++j) { aca[a][b][j] = 0.f; acb[a][b][j] = 0.f; }

  auto stage = [&](int t) {
    char* l = lds + (t & 1) * BUF + tid * 16;
    const bf16_t* ga = Asrc + (size_t)t * 32;
    gload16(ga, (bf16_t*)l);                          // A rows 0..63
    gload16(ga + r64K, (bf16_t*)(l + 4096));          // A rows 64..127
    gload16(Basrc + (size_t)t * 32, (bf16_t*)(l + 8192));   // Ba 64 rows
    gload16(Bbsrc + (size_t)t * 32, (bf16_t*)(l + 12288));  // Bb 64 rows
  };
  auto rd = [&](int base, int row) -> bf16x8 {
    int off = base + (row << 6) + ((hi ^ ((row >> 1) & 3)) << 4);
    return *(const bf16x8*)(lds + off);
  };

  stage(0);

  for (int t = 0; t < NT; ++t) {
    VMCNT(0);
    BARF();
    const int buf = (t & 1) * BUF;
    bf16x8 afr[4], bfa[2], bfb[2];
#pragma unroll
    for (int i = 0; i < 4; ++i) afr[i] = rd(buf, wm + i * 16 + lr);
#pragma unroll
    for (int ni = 0; ni < 2; ++ni) bfa[ni] = rd(buf + 8192, wn + ni * 16 + lr);
#pragma unroll
    for (int ni = 0; ni < 2; ++ni) bfb[ni] = rd(buf + 12288, wn + ni * 16 + lr);
    if (t + 1 < NT) stage(t + 1);
    __builtin_amdgcn_s_setprio(1);
#pragma unroll
    for (int i = 0; i < 4; ++i)
#pragma unroll
      for (int ni = 0; ni < 2; ++ni) {
        aca[i][ni] = __builtin_amdgcn_mfma_f32_16x16x32_bf16(afr[i], bfa[ni], aca[i][ni], 0, 0, 0);
        acb[i][ni] = __builtin_amdgcn_mfma_f32_16x16x32_bf16(afr[i], bfb[ni], acb[i][ni], 0, 0, 0);
      }
    __builtin_amdgcn_s_setprio(0);
  }

  float bva[2], bvb[2];
#pragma unroll
  for (int ni = 0; ni < 2; ++ni) {
    bva[ni] = bias_a[bn + wn + ni * 16 + lr];
    bvb[ni] = bias_b[bn + wn + ni * 16 + lr];
  }
#pragma unroll
  for (int mi = 0; mi < 4; ++mi) {
#pragma unroll
    for (int j = 0; j < 4; ++j) {
      const int rowg = bm + wm + mi * 16 + hi * 4 + j;
#pragma unroll
      for (int ni = 0; ni < 2; ++ni) {
        const int colg = bn + wn + ni * 16 + lr;
        float va = aca[mi][ni][j] + bva[ni];
        float vb = acb[mi][ni][j] + bvb[ni];
        float s = va / (1.f + __expf(-va));
        C[(size_t)rowg * N + colg] = (bf16_t)(s * vb);
      }
    }
  }
}

// =======================================================================
// Causal-conv GEMM, no im2col (round-11 proven).
// =======================================================================
__global__ __launch_bounds__(256) void k_gemm_conv(
    const bf16_t* __restrict__ h, const bf16_t* __restrict__ Bw,
    bf16_t* __restrict__ Cb, const float* __restrict__ bias,
    const bf16_t* __restrict__ zpad) {
  constexpr int N = SDIM;
  constexpr int K = SDIM * 4;
  constexpr int BUF = 16384;
  __shared__ __align__(16) char lds[2 * BUF];

  const int tid = threadIdx.x;
  const int lane = tid & 63;
  const int wave = tid >> 6;
  const int lr = lane & 15;
  const int hi = lane >> 4;

  int bx, by;
  blockmap(bx, by);

  const int bm = by * 128;
  const int bn = bx * 128;
  const int wm = (wave >> 1) * 64;
  const int wn = (wave & 1) * 64;

  const int srow = tid >> 2;
  const int scol = 8 * ((tid & 3) ^ ((tid >> 3) & 3));
  const int row0 = bm + srow;
  const int tt0 = row0 & (TSEQ - 1);
  const bf16_t* Bsrc = Bw + (size_t)(bn + srow) * K + scol;
  const size_t r64K = (size_t)64 * K;
  const int NT = K >> 5;

  f32x4 acc[4][4];
#pragma unroll
  for (int a = 0; a < 4; ++a)
#pragma unroll
    for (int b = 0; b < 4; ++b)
#pragma unroll
      for (int j = 0; j < 4; ++j) acc[a][b][j] = 0.f;

  auto stage = [&](int t) {
    char* l = lds + (t & 1) * BUF + tid * 16;
    const int k = t >> 5;
    const int si = (t & 31) * 32 + scol;
    const bf16_t* ga0 = (tt0 + k >= 3)
        ? h + (size_t)(row0 + k - 3) * SDIM + si : zpad;
    const bf16_t* ga1 = h + (size_t)(row0 + 64 + k - 3) * SDIM + si;
    gload16(ga0, (bf16_t*)l);
    gload16(ga1, (bf16_t*)(l + 4096));
    const bf16_t* gb = Bsrc + (size_t)t * 32;
    gload16(gb, (bf16_t*)(l + 8192));
    gload16(gb + r64K, (bf16_t*)(l + 12288));
  };
  auto rdA = [&](int buf, int row) -> bf16x8 {
    int off = buf + (row << 6) + ((hi ^ ((row >> 1) & 3)) << 4);
    return *(const bf16x8*)(lds + off);
  };
  auto rdB = [&](int buf, int row) -> bf16x8 {
    int off = buf + 8192 + (row << 6) + ((hi ^ ((row >> 1) & 3)) << 4);
    return *(const bf16x8*)(lds + off);
  };

  stage(0);

  for (int t = 0; t < NT; ++t) {
    VMCNT(0);
    BARF();
    const int buf = (t & 1) * BUF;
    bf16x8 bfr[4], afr[4];
#pragma unroll
    for (int ni = 0; ni < 4; ++ni) bfr[ni] = rdB(buf, wn + ni * 16 + lr);
#pragma unroll
    for (int i = 0; i < 4; ++i) afr[i] = rdA(buf, wm + i * 16 + lr);
    if (t + 1 < NT) stage(t + 1);
    __builtin_amdgcn_s_setprio(1);
#pragma unroll
    for (int i = 0; i < 4; ++i)
#pragma unroll
      for (int ni = 0; ni < 4; ++ni)
        acc[i][ni] = __builtin_amdgcn_mfma_f32_16x16x32_bf16(afr[i], bfr[ni], acc[i][ni], 0, 0, 0);
    __builtin_amdgcn_s_setprio(0);
  }

  float bv[4];
#pragma unroll
  for (int ni = 0; ni < 4; ++ni) bv[ni] = bias[bn + wn + ni * 16 + lr];
#pragma unroll
  for (int mi = 0; mi < 4; ++mi) {
#pragma unroll
    for (int j = 0; j < 4; ++j) {
      const int rowg = bm + wm + mi * 16 + hi * 4 + j;
#pragma unroll
      for (int ni = 0; ni < 4; ++ni) {
        const int colg = bn + wn + ni * 16 + lr;
        Cb[(size_t)rowg * N + colg] = (bf16_t)(acc[mi][ni][j] + bv[ni]);
      }
    }
  }
}

// =======================================================================
// Fused MoE fc1, BN=64 per half: gathered A rows, both weight halves,
// in-register swiglu. Same acc budget as plain core.
// =======================================================================
__global__ __launch_bounds__(256) void k_moe_fc1(
    const bf16_t* __restrict__ A, const bf16_t* __restrict__ Bw, size_t zB,
    bf16_t* __restrict__ C, const float* __restrict__ bias, int bstride,
    const int* __restrict__ ntiles_p, const int* __restrict__ tile_e,
    const int* __restrict__ tile_row, const int* __restrict__ idx,
    int N, int K) {
  constexpr int BUF = 16384;
  __shared__ __align__(16) char lds[2 * BUF];

  const int tid = threadIdx.x;
  const int lane = tid & 63;
  const int wave = tid >> 6;
  const int lr = lane & 15;
  const int hi = lane >> 4;

  const int nbx = gridDim.x, nby = gridDim.y;
  int id = blockIdx.x + nbx * blockIdx.y;
  const int nwg = nbx * nby;
  if ((nwg & 7) == 0) id = (id & 7) * (nwg >> 3) + (id >> 3);
  const int bx = id % nbx;
  const int by = id / nbx;

  const int ntiles = *ntiles_p;
  if (bx >= ntiles) return;
  const int e = tile_e[bx];
  const int bm = tile_row[bx];
  const int bn = by * 64;
  const int wm = (wave >> 1) * 64;
  const int wn = (wave & 1) * 32;

  const int srow = tid >> 2;
  const int scol = 8 * ((tid & 3) ^ ((tid >> 3) & 3));
  const int atok0 = idx[bm + srow];
  const int atok1 = idx[bm + srow + 64];
  const bf16_t* Asrc0 = A + (size_t)atok0 * K + scol;
  const bf16_t* Asrc1 = A + (size_t)atok1 * K + scol;
  const bf16_t* Basrc = Bw + (size_t)e * zB + (size_t)(bn + srow) * K + scol;
  const bf16_t* Bbsrc = Basrc + (size_t)HEXP * K;
  const int NT = K >> 5;

  f32x4 aca[4][2], acb[4][2];
#pragma unroll
  for (int a = 0; a < 4; ++a)
#pragma unroll
    for (int b = 0; b < 2; ++b)
#pragma unroll
      for (int j = 0; j < 4; ++j) { aca[a][b][j] = 0.f; acb[a][b][j] = 0.f; }

  auto stage = [&](int t) {
    char* l = lds + (t & 1) * BUF + tid * 16;
    gload16(Asrc0 + (size_t)t * 32, (bf16_t*)l);
    gload16(Asrc1 + (size_t)t * 32, (bf16_t*)(l + 4096));
    gload16(Basrc + (size_t)t * 32, (bf16_t*)(l + 8192));
    gload16(Bbsrc + (size_t)t * 32, (bf16_t*)(l + 12288));
  };
  auto rd = [&](int base, int row) -> bf16x8 {
    int off = base + (row << 6) + ((hi ^ ((row >> 1) & 3)) << 4);
    return *(const bf16x8*)(lds + off);
  };

  stage(0);

  for (int t = 0; t < NT; ++t) {
    VMCNT(0);
    BARF();
    const int buf = (t & 1) * BUF;
    bf16x8 afr[4], bfa[2], bfb[2];
#pragma unroll
    for (int i = 0; i < 4; ++i) afr[i] = rd(buf, wm + i * 16 + lr);
#pragma unroll
    for (int ni = 0; ni < 2; ++ni) bfa[ni] = rd(buf + 8192, wn + ni * 16 + lr);
#pragma unroll
    for (int ni = 0; ni < 2; ++ni) bfb[ni] = rd(buf + 12288, wn + ni * 16 + lr);
    if (t + 1 < NT) stage(t + 1);
    __builtin_amdgcn_s_setprio(1);
#pragma unroll
    for (int i = 0; i < 4; ++i)
#pragma unroll
      for (int ni = 0; ni < 2; ++ni) {
        aca[i][ni] = __builtin_amdgcn_mfma_f32_16x16x32_bf16(afr[i], bfa[ni], aca[i][ni], 0, 0, 0);
        acb[i][ni] = __builtin_amdgcn_mfma_f32_16x16x32_bf16(afr[i], bfb[ni], acb[i][ni], 0, 0, 0);
      }
    __builtin_amdgcn_s_setprio(0);
  }

  const float* bpa = bias + (size_t)e * bstride;
  const float* bpb = bpa + HEXP;
  float bva[2], bvb[2];
#pragma unroll
  for (int ni = 0; ni < 2; ++ni) {
    bva[ni] = bpa[bn + wn + ni * 16 + lr];
    bvb[ni] = bpb[bn + wn + ni * 16 + lr];
  }
#pragma unroll
  for (int mi = 0; mi < 4; ++mi) {
#pragma unroll
    for (int j = 0; j < 4; ++j) {
      const int slot = bm + wm + mi * 16 + hi * 4 + j;
#pragma unroll
      for (int ni = 0; ni < 2; ++ni) {
        const int colg = bn + wn + ni * 16 + lr;
        float va = aca[mi][ni][j] + bva[ni];
        float vb = acb[mi][ni][j] + bvb[ni];
        float s = va / (1.f + __expf(-va));
        C[(size_t)slot * N + colg] = (bf16_t)(s * vb);
      }
    }
  }
}

// =======================================================================
// MoE fc2: slot-linear A, writes bf16 slot rows eo (combined by k_combine).
// =======================================================================
__global__ __launch_bounds__(256) void k_moe_fc2(
    const bf16_t* __restrict__ A, const bf16_t* __restrict__ Bw, size_t zB,
    bf16_t* __restrict__ Cb, const float* __restrict__ bias, int bstride,
    const int* __restrict__ ntiles_p, const int* __restrict__ tile_e,
    const int* __restrict__ tile_row,
    int N, int K) {
  constexpr int BUF = 16384;
  __shared__ __align__(16) char lds[2 * BUF];

  const int tid = threadIdx.x;
  const int lane = tid & 63;
  const int wave = tid >> 6;
  const int lr = lane & 15;
  const int hi = lane >> 4;

  const int nbx = gridDim.x, nby = gridDim.y;
  int id = blockIdx.x + nbx * blockIdx.y;
  const int nwg = nbx * nby;
  if ((nwg & 7) == 0) id = (id & 7) * (nwg >> 3) + (id >> 3);
  const int bx = id % nbx;
  const int by = id / nbx;

  const int ntiles = *ntiles_p;
  if (bx >= ntiles) return;
  const int e = tile_e[bx];
  const int bm = tile_row[bx];
  const int bn = by * 128;
  const int wm = (wave >> 1) * 64;
  const int wn = (wave & 1) * 64;

  const int srow = tid >> 2;
  const int scol = 8 * ((tid & 3) ^ ((tid >> 3) & 3));
  const bf16_t* Asrc = A + (size_t)(bm + srow) * K + scol;
  const bf16_t* Bsrc = Bw + (size_t)e * zB + (size_t)(bn + srow) * K + scol;
  const size_t r64K = (size_t)64 * K;
  const int NT = K >> 5;

  f32x4 acc[4][4];
#pragma unroll
  for (int a = 0; a < 4; ++a)
#pragma unroll
    for (int b = 0; b < 4; ++b)
#pragma unroll
      for (int j = 0; j < 4; ++j) acc[a][b][j] = 0.f;

  auto stage = [&](int t) {
    char* l = lds + (t & 1) * BUF + tid * 16;
    gload16(Asrc + (size_t)t * 32, (bf16_t*)l);
    gload16(Asrc + (size_t)t * 32 + r64K, (bf16_t*)(l + 4096));
    gload16(Bsrc + (size_t)t * 32, (bf16_t*)(l + 8192));
    gload16(Bsrc + (size_t)t * 32 + r64K, (bf16_t*)(l + 12288));
  };
  auto rdA = [&](int buf, int row) -> bf16x8 {
    int off = buf + (row << 6) + ((hi ^ ((row >> 1) & 3)) << 4);
    return *(const bf16x8*)(lds + off);
  };
  auto rdB = [&](int buf, int row) -> bf16x8 {
    int off = buf + 8192 + (row << 6) + ((hi ^ ((row >> 1) & 3)) << 4);
    return *(const bf16x8*)(lds + off);
  };

  stage(0);

  for (int t = 0; t < NT; ++t) {
    VMCNT(0);
    BARF();
    const int buf = (t & 1) * BUF;
    bf16x8 bfr[4], afr[4];
#pragma unroll
    for (int ni = 0; ni < 4; ++ni) bfr[ni] = rdB(buf, wn + ni * 16 + lr);
#pragma unroll
    for (int i = 0; i < 4; ++i) afr[i] = rdA(buf, wm + i * 16 + lr);
    if (t + 1 < NT) stage(t + 1);
    __builtin_amdgcn_s_setprio(1);
#pragma unroll
    for (int i = 0; i < 4; ++i)
#pragma unroll
      for (int ni = 0; ni < 4; ++ni)
        acc[i][ni] = __builtin_amdgcn_mfma_f32_16x16x32_bf16(afr[i], bfr[ni], acc[i][ni], 0, 0, 0);
    __builtin_amdgcn_s_setprio(0);
  }

  const float* bp = bias + (size_t)e * bstride;
  float bv[4];
#pragma unroll
  for (int ni = 0; ni < 4; ++ni) bv[ni] = bp[bn + wn + ni * 16 + lr];
#pragma unroll
  for (int mi = 0; mi < 4; ++mi) {
#pragma unroll
    for (int j = 0; j < 4; ++j) {
      const int slot = bm + wm + mi * 16 + hi * 4 + j;
#pragma unroll
      for (int ni = 0; ni < 4; ++ni) {
        const int colg = bn + wn + ni * 16 + lr;
        Cb[(size_t)slot * N + colg] = (bf16_t)(acc[mi][ni][j] + bv[ni]);
      }
    }
  }
}

// ---------------------------------------------------------------------------
extern "C" void kernel_launch(void* const* d_in, const int* in_sizes, int n_in,
                              void* d_out, int out_size, void* d_ws, size_t ws_size,
                              hipStream_t stream) {
  (void)in_sizes; (void)n_in; (void)out_size; (void)ws_size;
  const float* x    = (const float*)d_in[0];
  const float* rW   = (const float*)d_in[1];
  const float* rb   = (const float*)d_in[2];
  const float* d1W  = (const float*)d_in[3];
  const float* d1b  = (const float*)d_in[4];
  const float* d2W  = (const float*)d_in[5];
  const float* d2b  = (const float*)d_in[6];
  const float* sWin = (const float*)d_in[7];
  const float* sbin = (const float*)d_in[8];
  const float* sWc  = (const float*)d_in[9];
  const float* sbc  = (const float*)d_in[10];
  const float* sWo  = (const float*)d_in[11];
  const float* sbo  = (const float*)d_in[12];
  const float* mW   = (const float*)d_in[13];
  const float* mb   = (const float*)d_in[14];
  const float* eW1  = (const float*)d_in[15];
  const float* eb1  = (const float*)d_in[16];
  const float* eW2  = (const float*)d_in[17];
  const float* eb2  = (const float*)d_in[18];
  float* out = (float*)d_out;

  char* ws = (char*)d_ws;
  size_t off = 0;
  auto alloc = [&](size_t bytes) -> void* {
    void* p = ws + off;
    off += (bytes + 255) & ~(size_t)255;
    return p;
  };
  bf16_t* xb    = (bf16_t*)alloc((size_t)NTOK * DDIM * 2);
  bf16_t* wd1   = (bf16_t*)alloc((size_t)2 * HDIM * DDIM * 2);
  bf16_t* wd2   = (bf16_t*)alloc((size_t)DDIM * HDIM * 2);
  bf16_t* wsin  = (bf16_t*)alloc((size_t)SDIM * DDIM * 2);
  bf16_t* wconv = (bf16_t*)alloc((size_t)SDIM * SDIM * 4 * 2);
  bf16_t* wsout = (bf16_t*)alloc((size_t)DDIM * SDIM * 2);
  bf16_t* we1   = (bf16_t*)alloc((size_t)NEXP * 2 * HEXP * DDIM * 2);
  bf16_t* we2   = (bf16_t*)alloc((size_t)NEXP * DDIM * HEXP * 2);
  bf16_t* Cc    = (bf16_t*)alloc((size_t)NTOK * HDIM * 2);  // dense swiglu | MoE swiglu (slot)
  bf16_t* Dd    = (bf16_t*)alloc((size_t)NTOK * HDIM * 2);  // eo (MoE fc2 slot rows)
  bf16_t* th    = (bf16_t*)alloc((size_t)NTOK * SDIM * 2);
  bf16_t* tsq   = (bf16_t*)alloc((size_t)NTOK * SDIM * 2);
  float*  bw3   = (float*)alloc((size_t)NTOK * 3 * 4);
  int*    top2e = (int*)alloc((size_t)NTOK * 2 * 4);
  float*  top2w = (float*)alloc((size_t)NTOK * 2 * 4);
  int*    slotm = (int*)alloc((size_t)NTOK * 2 * 4);
  int*    cnt   = (int*)alloc(NEXP * 4);
  int*    fill  = (int*)alloc(NEXP * 4);
  int*    basep = (int*)alloc((NEXP + 1) * 4);
  int*    ntl   = (int*)alloc(4);
  int*    t_e   = (int*)alloc(MAXTILES * 4);
  int*    t_row = (int*)alloc(MAXTILES * 4);
  int*    idx   = (int*)alloc(MAXROWS * 4);
  bf16_t* zpad  = (bf16_t*)alloc(256);
  bf16_t* eo    = Dd;

  // conversions + router + MoE bookkeeping
  k_f32_to_bf16<<<4096, 256, 0, stream>>>(x, xb, NTOK * DDIM / 8);
  k_f32_to_bf16<<<4096, 256, 0, stream>>>(d1W, wd1, 2 * HDIM * DDIM / 8);
  k_f32_to_bf16<<<2048, 256, 0, stream>>>(d2W, wd2, DDIM * HDIM / 8);
  k_f32_to_bf16<<<512, 256, 0, stream>>>(sWin, wsin, SDIM * DDIM / 8);
  k_convw<<<2048, 256, 0, stream>>>(sWc, wconv);
  k_f32_to_bf16<<<512, 256, 0, stream>>>(sWo, wsout, DDIM * SDIM / 8);
  k_f32_to_bf16<<<4096, 256, 0, stream>>>(eW1, we1, NEXP * 2 * HEXP * DDIM / 8);
  k_f32_to_bf16<<<2048, 256, 0, stream>>>(eW2, we2, NEXP * DDIM * HEXP / 8);
  k_zero<<<(MAXROWS + 255) / 256, 256, 0, stream>>>(cnt, fill, idx, zpad);
  k_router<<<2048, 256, 0, stream>>>(x, rW, rb, mW, mb, bw3, top2e, top2w);
  k_count<<<1, 1024, 0, stream>>>(top2e, cnt);
  k_scan<<<1, 64, 0, stream>>>(cnt, basep, ntl, t_e, t_row);
  k_scatter<<<NTOK / 256, 256, 0, stream>>>(top2e, top2w, basep, fill, idx, slotm);

  // ---- dense branch: fused fc1(a,b)+swiglu (BN=64/half), d2 -> out ('=') ----
  k_gemm_fc1<<<dim3(64, 64), 256, 0, stream>>>(
      xb, wd1, wd1 + (size_t)HDIM * DDIM, Cc, d1b, d1b + HDIM, HDIM, DDIM);
  k_gemm<EPI_OUT_W><<<dim3(8, 64), 256, 0, stream>>>(
      Cc, wd2, nullptr, out, d2b, bw3, 3, DDIM, HDIM);

  // ---- sparse MoE: fused fc1+swiglu (BN=64/half), fc2 -> eo, combine ----
  k_moe_fc1<<<dim3(MAXTILES, 8), 256, 0, stream>>>(
      xb, we1, (size_t)2 * HEXP * DDIM, Cc, eb1, 2 * HEXP,
      ntl, t_e, t_row, idx, HEXP, DDIM);
  k_moe_fc2<<<dim3(MAXTILES, 8), 256, 0, stream>>>(
      Cc, we2, (size_t)DDIM * HEXP, eo, eb2, DDIM,
      ntl, t_e, t_row, DDIM, HEXP);
  k_combine<<<NTOK / 4, 256, 0, stream>>>(eo, slotm, top2w, out);

  // ---- SSM branch (conv reads th directly, no im2col) ----
  k_gemm<EPI_BF16><<<dim3(8, 64), 256, 0, stream>>>(
      xb, wsin, th, nullptr, sbin, nullptr, 0, SDIM, DDIM);
  k_gemm_conv<<<dim3(8, 64), 256, 0, stream>>>(th, wconv, tsq, sbc, zpad);
  k_gemm<EPI_OUT_A><<<dim3(8, 64), 256, 0, stream>>>(
      tsq, wsout, nullptr, out, sbo, bw3 + 1, 3, DDIM, SDIM);
}

// Round 15
// 593.003 us; speedup vs baseline: 1.1668x; 1.0019x over previous
//
#include <hip/hip_runtime.h>
#include <hip/hip_bf16.h>
#include <cstdint>

typedef __bf16 bf16_t;
typedef __bf16 bf16x8 __attribute__((ext_vector_type(8)));
typedef float f32x4 __attribute__((ext_vector_type(4)));

#define DEV_INLINE __device__ __forceinline__

#define NTOK 8192
#define DDIM 1024
#define HDIM 4096
#define SDIM 1024
#define NEXP 8
#define HEXP 512
#define TSEQ 2048
#define MAXTILES 136
#define MAXROWS (MAXTILES * 128)

#define VMCNT(n) asm volatile("s_waitcnt vmcnt(" #n ")" ::: "memory")
#define BARF() asm volatile("s_barrier" ::: "memory")

DEV_INLINE void gload16(const bf16_t* g, bf16_t* l) {
  __builtin_amdgcn_global_load_lds((const __attribute__((address_space(1))) void*)g,
                                   (__attribute__((address_space(3))) void*)l, 16, 0, 0);
}

// sub-grid XCD swizzle (sub-range bases are %8==0 so global mapping holds)
DEV_INLINE void submap(int sub, int nbx, int nby, int& bx, int& by) {
  const int nwg = nbx * nby;
  int id = sub;
  if ((nwg & 7) == 0) id = (id & 7) * (nwg >> 3) + (id >> 3);
  bx = id % nbx;
  by = id / nbx;
}

constexpr int EPI_BF16 = 0;
constexpr int EPI_OUT_W = 1;
constexpr int EPI_OUT_A = 2;

// ---------------- device GEMM cores (round-13 proven bodies) ----------------
template <int EPI>
DEV_INLINE void dev_gemm(char* lds, int sub, int nbx, int nby,
                         const bf16_t* __restrict__ A, const bf16_t* __restrict__ B,
                         bf16_t* __restrict__ Cb, float* __restrict__ Cf,
                         const float* __restrict__ bias,
                         const float* __restrict__ scale, int sstride,
                         int N, int K) {
  constexpr int BUF = 16384;
  const int tid = threadIdx.x;
  const int lane = tid & 63;
  const int wave = tid >> 6;
  const int lr = lane & 15;
  const int hi = lane >> 4;

  int bx, by;
  submap(sub, nbx, nby, bx, by);

  const int bm = by * 128;
  const int bn = bx * 128;
  const int wm = (wave >> 1) * 64;
  const int wn = (wave & 1) * 64;

  const int srow = tid >> 2;
  const int scol = 8 * ((tid & 3) ^ ((tid >> 3) & 3));
  const bf16_t* Asrc = A + (size_t)(bm + srow) * K + scol;
  const bf16_t* Bsrc = B + (size_t)(bn + srow) * K + scol;
  const size_t r64K = (size_t)64 * K;
  const int NT = K >> 5;

  f32x4 acc[4][4];
#pragma unroll
  for (int a = 0; a < 4; ++a)
#pragma unroll
    for (int b = 0; b < 4; ++b)
#pragma unroll
      for (int j = 0; j < 4; ++j) acc[a][b][j] = 0.f;

  auto stage = [&](int t) {
    char* l = lds + (t & 1) * BUF + tid * 16;
    const bf16_t* ga = Asrc + (size_t)t * 32;
    const bf16_t* gb = Bsrc + (size_t)t * 32;
    gload16(ga, (bf16_t*)l);
    gload16(ga + r64K, (bf16_t*)(l + 4096));
    gload16(gb, (bf16_t*)(l + 8192));
    gload16(gb + r64K, (bf16_t*)(l + 12288));
  };
  auto rdA = [&](int buf, int row) -> bf16x8 {
    int off = buf + (row << 6) + ((hi ^ ((row >> 1) & 3)) << 4);
    return *(const bf16x8*)(lds + off);
  };
  auto rdB = [&](int buf, int row) -> bf16x8 {
    int off = buf + 8192 + (row << 6) + ((hi ^ ((row >> 1) & 3)) << 4);
    return *(const bf16x8*)(lds + off);
  };

  stage(0);

  for (int t = 0; t < NT; ++t) {
    VMCNT(0);
    BARF();
    const int buf = (t & 1) * BUF;
    bf16x8 bfr[4], afr[4];
#pragma unroll
    for (int ni = 0; ni < 4; ++ni) bfr[ni] = rdB(buf, wn + ni * 16 + lr);
#pragma unroll
    for (int i = 0; i < 4; ++i) afr[i] = rdA(buf, wm + i * 16 + lr);
    if (t + 1 < NT) stage(t + 1);
    __builtin_amdgcn_s_setprio(1);
#pragma unroll
    for (int i = 0; i < 4; ++i)
#pragma unroll
      for (int ni = 0; ni < 4; ++ni)
        acc[i][ni] = __builtin_amdgcn_mfma_f32_16x16x32_bf16(afr[i], bfr[ni], acc[i][ni], 0, 0, 0);
    __builtin_amdgcn_s_setprio(0);
  }

  float bv[4];
#pragma unroll
  for (int ni = 0; ni < 4; ++ni) bv[ni] = bias[bn + wn + ni * 16 + lr];
#pragma unroll
  for (int mi = 0; mi < 4; ++mi) {
#pragma unroll
    for (int j = 0; j < 4; ++j) {
      const int rowg = bm + wm + mi * 16 + hi * 4 + j;
      float sc = 0.f;
      if constexpr (EPI == EPI_OUT_W || EPI == EPI_OUT_A)
        sc = scale[(size_t)rowg * sstride];
#pragma unroll
      for (int ni = 0; ni < 4; ++ni) {
        const int colg = bn + wn + ni * 16 + lr;
        float v = acc[mi][ni][j] + bv[ni];
        if constexpr (EPI == EPI_BF16) {
          Cb[(size_t)rowg * N + colg] = (bf16_t)v;
        } else if constexpr (EPI == EPI_OUT_W) {
          Cf[(size_t)rowg * N + colg] = sc * v;
        } else {
          Cf[(size_t)rowg * N + colg] += sc * v;
        }
      }
    }
  }
}

// fused fc1, BN=64/half (round-13 proven, 196us standalone)
DEV_INLINE void dev_gemm_fc1(char* lds, int sub,
                             const bf16_t* __restrict__ A, const bf16_t* __restrict__ Ba,
                             const bf16_t* __restrict__ Bb, bf16_t* __restrict__ C,
                             const float* __restrict__ bias_a, const float* __restrict__ bias_b,
                             int N, int K) {
  constexpr int BUF = 16384;
  const int tid = threadIdx.x;
  const int lane = tid & 63;
  const int wave = tid >> 6;
  const int lr = lane & 15;
  const int hi = lane >> 4;

  int bx, by;
  submap(sub, 64, 64, bx, by);

  const int bm = by * 128;
  const int bn = bx * 64;
  const int wm = (wave >> 1) * 64;
  const int wn = (wave & 1) * 32;

  const int srow = tid >> 2;
  const int scol = 8 * ((tid & 3) ^ ((tid >> 3) & 3));
  const bf16_t* Asrc = A + (size_t)(bm + srow) * K + scol;
  const bf16_t* Basrc = Ba + (size_t)(bn + srow) * K + scol;
  const bf16_t* Bbsrc = Bb + (size_t)(bn + srow) * K + scol;
  const size_t r64K = (size_t)64 * K;
  const int NT = K >> 5;

  f32x4 aca[4][2], acb[4][2];
#pragma unroll
  for (int a = 0; a < 4; ++a)
#pragma unroll
    for (int b = 0; b < 2; ++b)
#pragma unroll
      for (int j = 0; j < 4; ++j) { aca[a][b][j] = 0.f; acb[a][b][j] = 0.f; }

  auto stage = [&](int t) {
    char* l = lds + (t & 1) * BUF + tid * 16;
    const bf16_t* ga = Asrc + (size_t)t * 32;
    gload16(ga, (bf16_t*)l);
    gload16(ga + r64K, (bf16_t*)(l + 4096));
    gload16(Basrc + (size_t)t * 32, (bf16_t*)(l + 8192));
    gload16(Bbsrc + (size_t)t * 32, (bf16_t*)(l + 12288));
  };
  auto rd = [&](int base, int row) -> bf16x8 {
    int off = base + (row << 6) + ((hi ^ ((row >> 1) & 3)) << 4);
    return *(const bf16x8*)(lds + off);
  };

  stage(0);

  for (int t = 0; t < NT; ++t) {
    VMCNT(0);
    BARF();
    const int buf = (t & 1) * BUF;
    bf16x8 afr[4], bfa[2], bfb[2];
#pragma unroll
    for (int i = 0; i < 4; ++i) afr[i] = rd(buf, wm + i * 16 + lr);
#pragma unroll
    for (int ni = 0; ni < 2; ++ni) bfa[ni] = rd(buf + 8192, wn + ni * 16 + lr);
#pragma unroll
    for (int ni = 0; ni < 2; ++ni) bfb[ni] = rd(buf + 12288, wn + ni * 16 + lr);
    if (t + 1 < NT) stage(t + 1);
    __builtin_amdgcn_s_setprio(1);
#pragma unroll
    for (int i = 0; i < 4; ++i)
#pragma unroll
      for (int ni = 0; ni < 2; ++ni) {
        aca[i][ni] = __builtin_amdgcn_mfma_f32_16x16x32_bf16(afr[i], bfa[ni], aca[i][ni], 0, 0, 0);
        acb[i][ni] = __builtin_amdgcn_mfma_f32_16x16x32_bf16(afr[i], bfb[ni], acb[i][ni], 0, 0, 0);
      }
    __builtin_amdgcn_s_setprio(0);
  }

  float bva[2], bvb[2];
#pragma unroll
  for (int ni = 0; ni < 2; ++ni) {
    bva[ni] = bias_a[bn + wn + ni * 16 + lr];
    bvb[ni] = bias_b[bn + wn + ni * 16 + lr];
  }
#pragma unroll
  for (int mi = 0; mi < 4; ++mi) {
#pragma unroll
    for (int j = 0; j < 4; ++j) {
      const int rowg = bm + wm + mi * 16 + hi * 4 + j;
#pragma unroll
      for (int ni = 0; ni < 2; ++ni) {
        const int colg = bn + wn + ni * 16 + lr;
        float va = aca[mi][ni][j] + bva[ni];
        float vb = acb[mi][ni][j] + bvb[ni];
        float s = va / (1.f + __expf(-va));
        C[(size_t)rowg * N + colg] = (bf16_t)(s * vb);
      }
    }
  }
}

// causal-conv GEMM, no im2col (round-11 proven)
DEV_INLINE void dev_gemm_conv(char* lds, int sub,
                              const bf16_t* __restrict__ h, const bf16_t* __restrict__ Bw,
                              bf16_t* __restrict__ Cb, const float* __restrict__ bias,
                              const bf16_t* __restrict__ zpad) {
  constexpr int N = SDIM;
  constexpr int K = SDIM * 4;
  constexpr int BUF = 16384;
  const int tid = threadIdx.x;
  const int lane = tid & 63;
  const int wave = tid >> 6;
  const int lr = lane & 15;
  const int hi = lane >> 4;

  int bx, by;
  submap(sub, 8, 64, bx, by);

  const int bm = by * 128;
  const int bn = bx * 128;
  const int wm = (wave >> 1) * 64;
  const int wn = (wave & 1) * 64;

  const int srow = tid >> 2;
  const int scol = 8 * ((tid & 3) ^ ((tid >> 3) & 3));
  const int row0 = bm + srow;
  const int tt0 = row0 & (TSEQ - 1);
  const bf16_t* Bsrc = Bw + (size_t)(bn + srow) * K + scol;
  const size_t r64K = (size_t)64 * K;
  const int NT = K >> 5;

  f32x4 acc[4][4];
#pragma unroll
  for (int a = 0; a < 4; ++a)
#pragma unroll
    for (int b = 0; b < 4; ++b)
#pragma unroll
      for (int j = 0; j < 4; ++j) acc[a][b][j] = 0.f;

  auto stage = [&](int t) {
    char* l = lds + (t & 1) * BUF + tid * 16;
    const int k = t >> 5;
    const int si = (t & 31) * 32 + scol;
    const bf16_t* ga0 = (tt0 + k >= 3)
        ? h + (size_t)(row0 + k - 3) * SDIM + si : zpad;
    const bf16_t* ga1 = h + (size_t)(row0 + 64 + k - 3) * SDIM + si;
    gload16(ga0, (bf16_t*)l);
    gload16(ga1, (bf16_t*)(l + 4096));
    const bf16_t* gb = Bsrc + (size_t)t * 32;
    gload16(gb, (bf16_t*)(l + 8192));
    gload16(gb + r64K, (bf16_t*)(l + 12288));
  };
  auto rdA = [&](int buf, int row) -> bf16x8 {
    int off = buf + (row << 6) + ((hi ^ ((row >> 1) & 3)) << 4);
    return *(const bf16x8*)(lds + off);
  };
  auto rdB = [&](int buf, int row) -> bf16x8 {
    int off = buf + 8192 + (row << 6) + ((hi ^ ((row >> 1) & 3)) << 4);
    return *(const bf16x8*)(lds + off);
  };

  stage(0);

  for (int t = 0; t < NT; ++t) {
    VMCNT(0);
    BARF();
    const int buf = (t & 1) * BUF;
    bf16x8 bfr[4], afr[4];
#pragma unroll
    for (int ni = 0; ni < 4; ++ni) bfr[ni] = rdB(buf, wn + ni * 16 + lr);
#pragma unroll
    for (int i = 0; i < 4; ++i) afr[i] = rdA(buf, wm + i * 16 + lr);
    if (t + 1 < NT) stage(t + 1);
    __builtin_amdgcn_s_setprio(1);
#pragma unroll
    for (int i = 0; i < 4; ++i)
#pragma unroll
      for (int ni = 0; ni < 4; ++ni)
        acc[i][ni] = __builtin_amdgcn_mfma_f32_16x16x32_bf16(afr[i], bfr[ni], acc[i][ni], 0, 0, 0);
    __builtin_amdgcn_s_setprio(0);
  }

  float bv[4];
#pragma unroll
  for (int ni = 0; ni < 4; ++ni) bv[ni] = bias[bn + wn + ni * 16 + lr];
#pragma unroll
  for (int mi = 0; mi < 4; ++mi) {
#pragma unroll
    for (int j = 0; j < 4; ++j) {
      const int rowg = bm + wm + mi * 16 + hi * 4 + j;
#pragma unroll
      for (int ni = 0; ni < 4; ++ni) {
        const int colg = bn + wn + ni * 16 + lr;
        Cb[(size_t)rowg * N + colg] = (bf16_t)(acc[mi][ni][j] + bv[ni]);
      }
    }
  }
}

// fused MoE fc1, BN=64/half (round-13 proven)
DEV_INLINE void dev_moe_fc1(char* lds, int sub,
                            const bf16_t* __restrict__ A, const bf16_t* __restrict__ Bw, size_t zB,
                            bf16_t* __restrict__ C, const float* __restrict__ bias, int bstride,
                            const int* __restrict__ ntiles_p, const int* __restrict__ tile_e,
                            const int* __restrict__ tile_row, const int* __restrict__ idx,
                            int N, int K) {
  constexpr int BUF = 16384;
  const int tid = threadIdx.x;
  const int lane = tid & 63;
  const int wave = tid >> 6;
  const int lr = lane & 15;
  const int hi = lane >> 4;

  int bx, by;
  submap(sub, MAXTILES, 8, bx, by);

  const int ntiles = *ntiles_p;
  if (bx >= ntiles) return;
  const int e = tile_e[bx];
  const int bm = tile_row[bx];
  const int bn = by * 64;
  const int wm = (wave >> 1) * 64;
  const int wn = (wave & 1) * 32;

  const int srow = tid >> 2;
  const int scol = 8 * ((tid & 3) ^ ((tid >> 3) & 3));
  const int atok0 = idx[bm + srow];
  const int atok1 = idx[bm + srow + 64];
  const bf16_t* Asrc0 = A + (size_t)atok0 * K + scol;
  const bf16_t* Asrc1 = A + (size_t)atok1 * K + scol;
  const bf16_t* Basrc = Bw + (size_t)e * zB + (size_t)(bn + srow) * K + scol;
  const bf16_t* Bbsrc = Basrc + (size_t)HEXP * K;
  const int NT = K >> 5;

  f32x4 aca[4][2], acb[4][2];
#pragma unroll
  for (int a = 0; a < 4; ++a)
#pragma unroll
    for (int b = 0; b < 2; ++b)
#pragma unroll
      for (int j = 0; j < 4; ++j) { aca[a][b][j] = 0.f; acb[a][b][j] = 0.f; }

  auto stage = [&](int t) {
    char* l = lds + (t & 1) * BUF + tid * 16;
    gload16(Asrc0 + (size_t)t * 32, (bf16_t*)l);
    gload16(Asrc1 + (size_t)t * 32, (bf16_t*)(l + 4096));
    gload16(Basrc + (size_t)t * 32, (bf16_t*)(l + 8192));
    gload16(Bbsrc + (size_t)t * 32, (bf16_t*)(l + 12288));
  };
  auto rd = [&](int base, int row) -> bf16x8 {
    int off = base + (row << 6) + ((hi ^ ((row >> 1) & 3)) << 4);
    return *(const bf16x8*)(lds + off);
  };

  stage(0);

  for (int t = 0; t < NT; ++t) {
    VMCNT(0);
    BARF();
    const int buf = (t & 1) * BUF;
    bf16x8 afr[4], bfa[2], bfb[2];
#pragma unroll
    for (int i = 0; i < 4; ++i) afr[i] = rd(buf, wm + i * 16 + lr);
#pragma unroll
    for (int ni = 0; ni < 2; ++ni) bfa[ni] = rd(buf + 8192, wn + ni * 16 + lr);
#pragma unroll
    for (int ni = 0; ni < 2; ++ni) bfb[ni] = rd(buf + 12288, wn + ni * 16 + lr);
    if (t + 1 < NT) stage(t + 1);
    __builtin_amdgcn_s_setprio(1);
#pragma unroll
    for (int i = 0; i < 4; ++i)
#pragma unroll
      for (int ni = 0; ni < 2; ++ni) {
        aca[i][ni] = __builtin_amdgcn_mfma_f32_16x16x32_bf16(afr[i], bfa[ni], aca[i][ni], 0, 0, 0);
        acb[i][ni] = __builtin_amdgcn_mfma_f32_16x16x32_bf16(afr[i], bfb[ni], acb[i][ni], 0, 0, 0);
      }
    __builtin_amdgcn_s_setprio(0);
  }

  const float* bpa = bias + (size_t)e * bstride;
  const float* bpb = bpa + HEXP;
  float bva[2], bvb[2];
#pragma unroll
  for (int ni = 0; ni < 2; ++ni) {
    bva[ni] = bpa[bn + wn + ni * 16 + lr];
    bvb[ni] = bpb[bn + wn + ni * 16 + lr];
  }
#pragma unroll
  for (int mi = 0; mi < 4; ++mi) {
#pragma unroll
    for (int j = 0; j < 4; ++j) {
      const int slot = bm + wm + mi * 16 + hi * 4 + j;
#pragma unroll
      for (int ni = 0; ni < 2; ++ni) {
        const int colg = bn + wn + ni * 16 + lr;
        float va = aca[mi][ni][j] + bva[ni];
        float vb = acb[mi][ni][j] + bvb[ni];
        float s = va / (1.f + __expf(-va));
        C[(size_t)slot * N + colg] = (bf16_t)(s * vb);
      }
    }
  }
}

// MoE fc2: slot-linear A -> eo slot rows (round-11 proven)
DEV_INLINE void dev_moe_fc2(char* lds, int sub,
                            const bf16_t* __restrict__ A, const bf16_t* __restrict__ Bw, size_t zB,
                            bf16_t* __restrict__ Cb, const float* __restrict__ bias, int bstride,
                            const int* __restrict__ ntiles_p, const int* __restrict__ tile_e,
                            const int* __restrict__ tile_row,
                            int N, int K) {
  constexpr int BUF = 16384;
  const int tid = threadIdx.x;
  const int lane = tid & 63;
  const int wave = tid >> 6;
  const int lr = lane & 15;
  const int hi = lane >> 4;

  int bx, by;
  submap(sub, MAXTILES, 8, bx, by);

  const int ntiles = *ntiles_p;
  if (bx >= ntiles) return;
  const int e = tile_e[bx];
  const int bm = tile_row[bx];
  const int bn = by * 128;
  const int wm = (wave >> 1) * 64;
  const int wn = (wave & 1) * 64;

  const int srow = tid >> 2;
  const int scol = 8 * ((tid & 3) ^ ((tid >> 3) & 3));
  const bf16_t* Asrc = A + (size_t)(bm + srow) * K + scol;
  const bf16_t* Bsrc = Bw + (size_t)e * zB + (size_t)(bn + srow) * K + scol;
  const size_t r64K = (size_t)64 * K;
  const int NT = K >> 5;

  f32x4 acc[4][4];
#pragma unroll
  for (int a = 0; a < 4; ++a)
#pragma unroll
    for (int b = 0; b < 4; ++b)
#pragma unroll
      for (int j = 0; j < 4; ++j) acc[a][b][j] = 0.f;

  auto stage = [&](int t) {
    char* l = lds + (t & 1) * BUF + tid * 16;
    gload16(Asrc + (size_t)t * 32, (bf16_t*)l);
    gload16(Asrc + (size_t)t * 32 + r64K, (bf16_t*)(l + 4096));
    gload16(Bsrc + (size_t)t * 32, (bf16_t*)(l + 8192));
    gload16(Bsrc + (size_t)t * 32 + r64K, (bf16_t*)(l + 12288));
  };
  auto rdA = [&](int buf, int row) -> bf16x8 {
    int off = buf + (row << 6) + ((hi ^ ((row >> 1) & 3)) << 4);
    return *(const bf16x8*)(lds + off);
  };
  auto rdB = [&](int buf, int row) -> bf16x8 {
    int off = buf + 8192 + (row << 6) + ((hi ^ ((row >> 1) & 3)) << 4);
    return *(const bf16x8*)(lds + off);
  };

  stage(0);

  for (int t = 0; t < NT; ++t) {
    VMCNT(0);
    BARF();
    const int buf = (t & 1) * BUF;
    bf16x8 bfr[4], afr[4];
#pragma unroll
    for (int ni = 0; ni < 4; ++ni) bfr[ni] = rdB(buf, wn + ni * 16 + lr);
#pragma unroll
    for (int i = 0; i < 4; ++i) afr[i] = rdA(buf, wm + i * 16 + lr);
    if (t + 1 < NT) stage(t + 1);
    __builtin_amdgcn_s_setprio(1);
#pragma unroll
    for (int i = 0; i < 4; ++i)
#pragma unroll
      for (int ni = 0; ni < 4; ++ni)
        acc[i][ni] = __builtin_amdgcn_mfma_f32_16x16x32_bf16(afr[i], bfr[ni], acc[i][ni], 0, 0, 0);
    __builtin_amdgcn_s_setprio(0);
  }

  const float* bp = bias + (size_t)e * bstride;
  float bv[4];
#pragma unroll
  for (int ni = 0; ni < 4; ++ni) bv[ni] = bp[bn + wn + ni * 16 + lr];
#pragma unroll
  for (int mi = 0; mi < 4; ++mi) {
#pragma unroll
    for (int j = 0; j < 4; ++j) {
      const int slot = bm + wm + mi * 16 + hi * 4 + j;
#pragma unroll
      for (int ni = 0; ni < 4; ++ni) {
        const int colg = bn + wn + ni * 16 + lr;
        Cb[(size_t)slot * N + colg] = (bf16_t)(acc[mi][ni][j] + bv[ni]);
      }
    }
  }
}

// ---------------- setup mega-kernel: all conversions + router + zero ----------------
DEV_INLINE void dev_conv8(const float* __restrict__ src, bf16_t* __restrict__ dst, int sub) {
  int i = sub * 256 + threadIdx.x;
  const float4* s = (const float4*)src + (size_t)i * 2;
  float4 v0 = s[0], v1 = s[1];
  bf16x8 o;
  o[0] = (bf16_t)v0.x; o[1] = (bf16_t)v0.y; o[2] = (bf16_t)v0.z; o[3] = (bf16_t)v0.w;
  o[4] = (bf16_t)v1.x; o[5] = (bf16_t)v1.y; o[6] = (bf16_t)v1.z; o[7] = (bf16_t)v1.w;
  *((bf16x8*)dst + i) = o;
}

__global__ __launch_bounds__(256) void k_setup(
    const float* __restrict__ x, const float* __restrict__ d1W,
    const float* __restrict__ d2W, const float* __restrict__ sWin,
    const float* __restrict__ sWo, const float* __restrict__ eW1,
    const float* __restrict__ eW2, const float* __restrict__ sWc,
    const float* __restrict__ rW, const float* __restrict__ rb,
    const float* __restrict__ mW, const float* __restrict__ mb,
    bf16_t* __restrict__ xb, bf16_t* __restrict__ wd1, bf16_t* __restrict__ wd2,
    bf16_t* __restrict__ wsin, bf16_t* __restrict__ wsout,
    bf16_t* __restrict__ we1, bf16_t* __restrict__ we2, bf16_t* __restrict__ wconv,
    float* __restrict__ bw3, int* __restrict__ top2e, float* __restrict__ top2w,
    int* __restrict__ fill, int* __restrict__ idx, bf16_t* __restrict__ zpad) {
  const int b = blockIdx.x;
  if (b < 4096) { dev_conv8(x, xb, b); return; }
  if (b < 8192) { dev_conv8(d1W, wd1, b - 4096); return; }
  if (b < 10240) { dev_conv8(d2W, wd2, b - 8192); return; }
  if (b < 10752) { dev_conv8(sWin, wsin, b - 10240); return; }
  if (b < 11264) { dev_conv8(sWo, wsout, b - 10752); return; }
  if (b < 15360) { dev_conv8(eW1, we1, b - 11264); return; }
  if (b < 17408) { dev_conv8(eW2, we2, b - 15360); return; }
  if (b < 19456) {  // convw: [S][S][K] f32 -> [S][K*S] bf16
    int i = (b - 17408) * 256 + threadIdx.x;
    size_t flat = (size_t)i * 8;
    int s = (int)(flat >> 12);
    int col = (int)(flat & 4095);
    int k = col >> 10;
    int si0 = col & 1023;
    const float* sp = sWc + (size_t)s * 4096 + k;
    bf16x8 o;
#pragma unroll
    for (int j = 0; j < 8; ++j) o[j] = (bf16_t)sp[(size_t)(si0 + j) * 4];
    *(bf16x8*)(wconv + flat) = o;
    return;
  }
  if (b < 21504) {  // router
    int wave = threadIdx.x >> 6, lane = threadIdx.x & 63;
    int t = (b - 19456) * 4 + wave;
    const float* xr = x + (size_t)t * DDIM;
    float xv[16];
#pragma unroll
    for (int i = 0; i < 16; i += 4) *(float4*)&xv[i] = *(const float4*)&xr[lane * 16 + i];
    float acc[11];
#pragma unroll
    for (int j = 0; j < 11; ++j) {
      const float* w = (j < 3) ? (rW + j * DDIM) : (mW + (j - 3) * DDIM);
      float s = 0.f;
#pragma unroll
      for (int i = 0; i < 16; i += 4) {
        float4 wv = *(const float4*)&w[lane * 16 + i];
        s += xv[i] * wv.x + xv[i + 1] * wv.y + xv[i + 2] * wv.z + xv[i + 3] * wv.w;
      }
      acc[j] = s;
    }
#pragma unroll
    for (int j = 0; j < 11; ++j)
      for (int off = 32; off; off >>= 1) acc[j] += __shfl_xor(acc[j], off);
    if (lane == 0) {
      float l0 = acc[0] + rb[0], l1 = acc[1] + rb[1], l2 = acc[2] + rb[2];
      float mx = fmaxf(l0, fmaxf(l1, l2));
      float e0 = expf(l0 - mx), e1 = expf(l1 - mx), e2 = expf(l2 - mx);
      float inv = 1.f / (e0 + e1 + e2);
      float w2 = e2 * inv;
      bw3[t * 3 + 0] = e0 * inv; bw3[t * 3 + 1] = e1 * inv; bw3[t * 3 + 2] = w2;
      float lg[8];
#pragma unroll
      for (int e = 0; e < 8; ++e) lg[e] = acc[3 + e] + mb[e];
      int i0 = 0;
#pragma unroll
      for (int e = 1; e < 8; ++e) if (lg[e] > lg[i0]) i0 = e;
      int i1 = -1;
#pragma unroll
      for (int e = 0; e < 8; ++e) {
        if (e == i0) continue;
        if (i1 < 0 || lg[e] > lg[i1]) i1 = e;
      }
      float ee = expf(lg[i1] - lg[i0]);
      float w0 = 1.f / (1.f + ee), w1 = ee / (1.f + ee);
      top2e[t * 2 + 0] = i0; top2e[t * 2 + 1] = i1;
      top2w[t * 2 + 0] = w2 * w0; top2w[t * 2 + 1] = w2 * w1;
    }
    return;
  }
  // zero fill/idx/zpad  (68 blocks -> 17408 threads, covers all of idx!)
  int i = (b - 21504) * 256 + threadIdx.x;
  if (i < NEXP) fill[i] = 0;
  if (i < 128) zpad[i] = (bf16_t)0.f;
  if (i < MAXROWS) idx[i] = 0;
}

// ---------------- count + scan fused (one block) ----------------
__global__ __launch_bounds__(1024) void k_count_scan(const int* __restrict__ top2e,
                                                     int* __restrict__ base,
                                                     int* __restrict__ ntiles,
                                                     int* __restrict__ tile_e,
                                                     int* __restrict__ tile_row) {
  __shared__ int hist[NEXP];
  const int tid = threadIdx.x;
  if (tid < NEXP) hist[tid] = 0;
  __syncthreads();
  int c[NEXP];
#pragma unroll
  for (int e = 0; e < NEXP; ++e) c[e] = 0;
#pragma unroll
  for (int j = 0; j < 2 * NTOK / 1024; ++j) {
    int v = top2e[j * 1024 + tid];
#pragma unroll
    for (int e = 0; e < NEXP; ++e) c[e] += (v == e) ? 1 : 0;
  }
#pragma unroll
  for (int e = 0; e < NEXP; ++e)
    for (int off = 32; off; off >>= 1) c[e] += __shfl_xor(c[e], off);
  if ((tid & 63) == 0) {
#pragma unroll
    for (int e = 0; e < NEXP; ++e) atomicAdd(&hist[e], c[e]);
  }
  __syncthreads();
  if (tid == 0) {
    int b = 0, tt = 0;
    for (int e = 0; e < NEXP; ++e) {
      base[e] = b;
      int nt = (hist[e] + 127) >> 7;
      for (int j = 0; j < nt; ++j) { tile_e[tt] = e; tile_row[tt] = b + j * 128; ++tt; }
      b += nt * 128;
    }
    *ntiles = tt;
  }
}

// ---------------- scatter (round-8 proven) ----------------
__global__ __launch_bounds__(256) void k_scatter(const int* __restrict__ top2e,
                                                 const float* __restrict__ top2w,
                                                 const int* __restrict__ base,
                                                 int* __restrict__ fill,
                                                 int* __restrict__ idx,
                                                 int* __restrict__ slotmap) {
  __shared__ int lcnt[NEXP];
  __shared__ int lbase[NEXP];
  const int tid = threadIdx.x;
  const int t = blockIdx.x * 256 + tid;
  if (tid < NEXP) lcnt[tid] = 0;
  __syncthreads();
  const int e0 = top2e[t * 2 + 0], e1 = top2e[t * 2 + 1];
  const int s0 = atomicAdd(&lcnt[e0], 1);
  const int s1 = atomicAdd(&lcnt[e1], 1);
  __syncthreads();
  if (tid < NEXP) lbase[tid] = atomicAdd(&fill[tid], lcnt[tid]);
  __syncthreads();
  const int p0 = base[e0] + lbase[e0] + s0;
  const int p1 = base[e1] + lbase[e1] + s1;
  idx[p0] = t; idx[p1] = t;
  slotmap[t * 2 + 0] = p0;
  slotmap[t * 2 + 1] = p1;
}

// ---------------- phase 1: dense fc1 | moe fc1 | wsin ----------------
__global__ __launch_bounds__(256) void k_phase1(
    const bf16_t* __restrict__ xb, const bf16_t* __restrict__ wd1,
    const float* __restrict__ d1b, bf16_t* __restrict__ Cc,
    const bf16_t* __restrict__ we1, const float* __restrict__ eb1,
    bf16_t* __restrict__ mo,
    const int* __restrict__ ntl, const int* __restrict__ t_e,
    const int* __restrict__ t_row, const int* __restrict__ idx,
    const bf16_t* __restrict__ wsin, const float* __restrict__ sbin,
    bf16_t* __restrict__ th) {
  __shared__ __align__(16) char lds[32768];
  const int b = blockIdx.x;
  if (b < 4096) {
    dev_gemm_fc1(lds, b, xb, wd1, wd1 + (size_t)HDIM * DDIM, Cc, d1b, d1b + HDIM,
                 HDIM, DDIM);
  } else if (b < 5184) {
    dev_moe_fc1(lds, b - 4096, xb, we1, (size_t)2 * HEXP * DDIM, mo, eb1, 2 * HEXP,
                ntl, t_e, t_row, idx, HEXP, DDIM);
  } else {
    dev_gemm<EPI_BF16>(lds, b - 5184, 8, 64, xb, wsin, th, nullptr, sbin,
                       nullptr, 0, SDIM, DDIM);
  }
}

// ---------------- phase 2: d2 | conv | moe fc2 ----------------
__global__ __launch_bounds__(256) void k_phase2(
    const bf16_t* __restrict__ Cc, const bf16_t* __restrict__ wd2,
    const float* __restrict__ d2b, const float* __restrict__ bw3,
    float* __restrict__ out,
    const bf16_t* __restrict__ th, const bf16_t* __restrict__ wconv,
    const float* __restrict__ sbc, bf16_t* __restrict__ tsq,
    const bf16_t* __restrict__ zpad,
    const bf16_t* __restrict__ mo, const bf16_t* __restrict__ we2,
    const float* __restrict__ eb2, bf16_t* __restrict__ eo,
    const int* __restrict__ ntl, const int* __restrict__ t_e,
    const int* __restrict__ t_row) {
  __shared__ __align__(16) char lds[32768];
  const int b = blockIdx.x;
  if (b < 512) {
    dev_gemm<EPI_OUT_W>(lds, b, 8, 64, Cc, wd2, nullptr, out, d2b, bw3, 3,
                        DDIM, HDIM);
  } else if (b < 1024) {
    dev_gemm_conv(lds, b - 512, th, wconv, tsq, sbc, zpad);
  } else {
    dev_moe_fc2(lds, b - 1024, mo, we2, (size_t)DDIM * HEXP, eo, eb2, DDIM,
                ntl, t_e, t_row, DDIM, HEXP);
  }
}

// ---------------- wsout (standalone: += out, must not overlap combine) ----------------
__global__ __launch_bounds__(256) void k_wsout(
    const bf16_t* __restrict__ tsq, const bf16_t* __restrict__ wsout,
    float* __restrict__ out, const float* __restrict__ sbo,
    const float* __restrict__ bw3) {
  __shared__ __align__(16) char lds[32768];
  dev_gemm<EPI_OUT_A>(lds, blockIdx.x, 8, 64, tsq, wsout, nullptr, out, sbo,
                      bw3 + 1, 3, DDIM, SDIM);
}

// ---------------- MoE combine: out[t] += g0*eo[s0] + g1*eo[s1] ----------------
__global__ __launch_bounds__(256) void k_combine(const bf16_t* __restrict__ eo,
                                                 const int* __restrict__ slotmap,
                                                 const float* __restrict__ top2w,
                                                 float* __restrict__ out) {
  int wave = threadIdx.x >> 6, lane = threadIdx.x & 63;
  int t = blockIdx.x * 4 + wave;
  const int s0 = slotmap[t * 2 + 0], s1 = slotmap[t * 2 + 1];
  const float g0 = top2w[t * 2 + 0], g1 = top2w[t * 2 + 1];
  const bf16x8* r0 = (const bf16x8*)(eo + (size_t)s0 * DDIM);
  const bf16x8* r1 = (const bf16x8*)(eo + (size_t)s1 * DDIM);
  float* orow = out + (size_t)t * DDIM;
#pragma unroll
  for (int i = 0; i < 2; ++i) {
    const int d = lane + i * 64;
    bf16x8 a = r0[d], b = r1[d];
    float vo[8];
    *(float4*)&vo[0] = *(const float4*)&orow[d * 8];
    *(float4*)&vo[4] = *(const float4*)&orow[d * 8 + 4];
#pragma unroll
    for (int j = 0; j < 8; ++j) vo[j] += g0 * (float)a[j] + g1 * (float)b[j];
    *(float4*)&orow[d * 8] = *(float4*)&vo[0];
    *(float4*)&orow[d * 8 + 4] = *(float4*)&vo[4];
  }
}

// ---------------------------------------------------------------------------
extern "C" void kernel_launch(void* const* d_in, const int* in_sizes, int n_in,
                              void* d_out, int out_size, void* d_ws, size_t ws_size,
                              hipStream_t stream) {
  (void)in_sizes; (void)n_in; (void)out_size; (void)ws_size;
  const float* x    = (const float*)d_in[0];
  const float* rW   = (const float*)d_in[1];
  const float* rb   = (const float*)d_in[2];
  const float* d1W  = (const float*)d_in[3];
  const float* d1b  = (const float*)d_in[4];
  const float* d2W  = (const float*)d_in[5];
  const float* d2b  = (const float*)d_in[6];
  const float* sWin = (const float*)d_in[7];
  const float* sbin = (const float*)d_in[8];
  const float* sWc  = (const float*)d_in[9];
  const float* sbc  = (const float*)d_in[10];
  const float* sWo  = (const float*)d_in[11];
  const float* sbo  = (const float*)d_in[12];
  const float* mW   = (const float*)d_in[13];
  const float* mb   = (const float*)d_in[14];
  const float* eW1  = (const float*)d_in[15];
  const float* eb1  = (const float*)d_in[16];
  const float* eW2  = (const float*)d_in[17];
  const float* eb2  = (const float*)d_in[18];
  float* out = (float*)d_out;

  char* ws = (char*)d_ws;
  size_t off = 0;
  auto alloc = [&](size_t bytes) -> void* {
    void* p = ws + off;
    off += (bytes + 255) & ~(size_t)255;
    return p;
  };
  bf16_t* xb    = (bf16_t*)alloc((size_t)NTOK * DDIM * 2);
  bf16_t* wd1   = (bf16_t*)alloc((size_t)2 * HDIM * DDIM * 2);
  bf16_t* wd2   = (bf16_t*)alloc((size_t)DDIM * HDIM * 2);
  bf16_t* wsin  = (bf16_t*)alloc((size_t)SDIM * DDIM * 2);
  bf16_t* wconv = (bf16_t*)alloc((size_t)SDIM * SDIM * 4 * 2);
  bf16_t* wsout = (bf16_t*)alloc((size_t)DDIM * SDIM * 2);
  bf16_t* we1   = (bf16_t*)alloc((size_t)NEXP * 2 * HEXP * DDIM * 2);
  bf16_t* we2   = (bf16_t*)alloc((size_t)NEXP * DDIM * HEXP * 2);
  bf16_t* Cc    = (bf16_t*)alloc((size_t)NTOK * HDIM * 2);  // dense swiglu | MoE swiglu (via mo? no: dense only)
  bf16_t* Dd    = (bf16_t*)alloc((size_t)NTOK * HDIM * 2);  // eo [0,35.7MB) | mo @36MB
  bf16_t* th    = (bf16_t*)alloc((size_t)NTOK * SDIM * 2);
  bf16_t* tsq   = (bf16_t*)alloc((size_t)NTOK * SDIM * 2);
  float*  bw3   = (float*)alloc((size_t)NTOK * 3 * 4);
  int*    top2e = (int*)alloc((size_t)NTOK * 2 * 4);
  float*  top2w = (float*)alloc((size_t)NTOK * 2 * 4);
  int*    slotm = (int*)alloc((size_t)NTOK * 2 * 4);
  int*    fill  = (int*)alloc(NEXP * 4);
  int*    basep = (int*)alloc((NEXP + 1) * 4);
  int*    ntl   = (int*)alloc(4);
  int*    t_e   = (int*)alloc(MAXTILES * 4);
  int*    t_row = (int*)alloc(MAXTILES * 4);
  int*    idx   = (int*)alloc(MAXROWS * 4);
  bf16_t* zpad  = (bf16_t*)alloc(256);
  // Dd partition: eo = slot rows [MAXROWS][1024] (35.7 MB) at offset 0;
  // mo = moe swiglu [MAXROWS][512] (17.8 MB) at elem offset 18M (36 MB). Disjoint.
  bf16_t* eo = Dd;
  bf16_t* mo = Dd + (size_t)18 * 1024 * 1024;

  // grid = 21504 work blocks + 68 zero blocks (MAXROWS/256) = 21572.
  // Round-14 bug: launched 21538 -> idx[8704..17407] kept 0xAA poison ->
  // moe_fc1 gather faulted. 68 blocks cover all of idx.
  k_setup<<<21572, 256, 0, stream>>>(
      x, d1W, d2W, sWin, sWo, eW1, eW2, sWc, rW, rb, mW, mb,
      xb, wd1, wd2, wsin, wsout, we1, we2, wconv,
      bw3, top2e, top2w, fill, idx, zpad);
  k_count_scan<<<1, 1024, 0, stream>>>(top2e, basep, ntl, t_e, t_row);
  k_scatter<<<NTOK / 256, 256, 0, stream>>>(top2e, top2w, basep, fill, idx, slotm);

  k_phase1<<<5696, 256, 0, stream>>>(
      xb, wd1, d1b, Cc, we1, eb1, mo, ntl, t_e, t_row, idx, wsin, sbin, th);
  k_phase2<<<2112, 256, 0, stream>>>(
      Cc, wd2, d2b, bw3, out, th, wconv, sbc, tsq, zpad,
      mo, we2, eb2, eo, ntl, t_e, t_row);
  k_wsout<<<512, 256, 0, stream>>>(tsq, wsout, out, sbo, bw3);
  k_combine<<<NTOK / 4, 256, 0, stream>>>(eo, slotm, top2w, out);
}

// Round 17
// 589.000 us; speedup vs baseline: 1.1748x; 1.0068x over previous
//
#include <hip/hip_runtime.h>
#include <hip/hip_bf16.h>
#include <cstdint>

typedef __bf16 bf16_t;
typedef __bf16 bf16x8 __attribute__((ext_vector_type(8)));
typedef float f32x4 __attribute__((ext_vector_type(4)));

#define DEV_INLINE __device__ __forceinline__

#define NTOK 8192
#define DDIM 1024
#define HDIM 4096
#define SDIM 1024
#define NEXP 8
#define HEXP 512
#define TSEQ 2048
#define MAXTILES 136
#define MAXROWS (MAXTILES * 128)

#define VMCNT(n) asm volatile("s_waitcnt vmcnt(" #n ")" ::: "memory")
#define BARF() asm volatile("s_barrier" ::: "memory")

DEV_INLINE void gload16(const bf16_t* g, bf16_t* l) {
  __builtin_amdgcn_global_load_lds((const __attribute__((address_space(1))) void*)g,
                                   (__attribute__((address_space(3))) void*)l, 16, 0, 0);
}

// sub-grid XCD swizzle (sub-range bases are %8==0 so global mapping holds)
DEV_INLINE void submap(int sub, int nbx, int nby, int& bx, int& by) {
  const int nwg = nbx * nby;
  int id = sub;
  if ((nwg & 7) == 0) id = (id & 7) * (nwg >> 3) + (id >> 3);
  bx = id % nbx;
  by = id / nbx;
}

constexpr int EPI_BF16 = 0;
constexpr int EPI_OUT_W = 1;
constexpr int EPI_OUT_A = 2;

// ---------------- device GEMM cores (round-13/15 proven bodies) ----------------
template <int EPI>
DEV_INLINE void dev_gemm(char* lds, int sub, int nbx, int nby,
                         const bf16_t* __restrict__ A, const bf16_t* __restrict__ B,
                         bf16_t* __restrict__ Cb, float* __restrict__ Cf,
                         const float* __restrict__ bias,
                         const float* __restrict__ scale, int sstride,
                         int N, int K) {
  constexpr int BUF = 16384;
  const int tid = threadIdx.x;
  const int lane = tid & 63;
  const int wave = tid >> 6;
  const int lr = lane & 15;
  const int hi = lane >> 4;

  int bx, by;
  submap(sub, nbx, nby, bx, by);

  const int bm = by * 128;
  const int bn = bx * 128;
  const int wm = (wave >> 1) * 64;
  const int wn = (wave & 1) * 64;

  const int srow = tid >> 2;
  const int scol = 8 * ((tid & 3) ^ ((tid >> 3) & 3));
  const bf16_t* Asrc = A + (size_t)(bm + srow) * K + scol;
  const bf16_t* Bsrc = B + (size_t)(bn + srow) * K + scol;
  const size_t r64K = (size_t)64 * K;
  const int NT = K >> 5;

  f32x4 acc[4][4];
#pragma unroll
  for (int a = 0; a < 4; ++a)
#pragma unroll
    for (int b = 0; b < 4; ++b)
#pragma unroll
      for (int j = 0; j < 4; ++j) acc[a][b][j] = 0.f;

  auto stage = [&](int t) {
    char* l = lds + (t & 1) * BUF + tid * 16;
    const bf16_t* ga = Asrc + (size_t)t * 32;
    const bf16_t* gb = Bsrc + (size_t)t * 32;
    gload16(ga, (bf16_t*)l);
    gload16(ga + r64K, (bf16_t*)(l + 4096));
    gload16(gb, (bf16_t*)(l + 8192));
    gload16(gb + r64K, (bf16_t*)(l + 12288));
  };
  auto rdA = [&](int buf, int row) -> bf16x8 {
    int off = buf + (row << 6) + ((hi ^ ((row >> 1) & 3)) << 4);
    return *(const bf16x8*)(lds + off);
  };
  auto rdB = [&](int buf, int row) -> bf16x8 {
    int off = buf + 8192 + (row << 6) + ((hi ^ ((row >> 1) & 3)) << 4);
    return *(const bf16x8*)(lds + off);
  };

  stage(0);

  for (int t = 0; t < NT; ++t) {
    VMCNT(0);
    BARF();
    const int buf = (t & 1) * BUF;
    bf16x8 bfr[4], afr[4];
#pragma unroll
    for (int ni = 0; ni < 4; ++ni) bfr[ni] = rdB(buf, wn + ni * 16 + lr);
#pragma unroll
    for (int i = 0; i < 4; ++i) afr[i] = rdA(buf, wm + i * 16 + lr);
    if (t + 1 < NT) stage(t + 1);
    __builtin_amdgcn_s_setprio(1);
#pragma unroll
    for (int i = 0; i < 4; ++i)
#pragma unroll
      for (int ni = 0; ni < 4; ++ni)
        acc[i][ni] = __builtin_amdgcn_mfma_f32_16x16x32_bf16(afr[i], bfr[ni], acc[i][ni], 0, 0, 0);
    __builtin_amdgcn_s_setprio(0);
  }

  float bv[4];
#pragma unroll
  for (int ni = 0; ni < 4; ++ni) bv[ni] = bias[bn + wn + ni * 16 + lr];
#pragma unroll
  for (int mi = 0; mi < 4; ++mi) {
#pragma unroll
    for (int j = 0; j < 4; ++j) {
      const int rowg = bm + wm + mi * 16 + hi * 4 + j;
      float sc = 0.f;
      if constexpr (EPI == EPI_OUT_W || EPI == EPI_OUT_A)
        sc = scale[(size_t)rowg * sstride];
#pragma unroll
      for (int ni = 0; ni < 4; ++ni) {
        const int colg = bn + wn + ni * 16 + lr;
        float v = acc[mi][ni][j] + bv[ni];
        if constexpr (EPI == EPI_BF16) {
          Cb[(size_t)rowg * N + colg] = (bf16_t)v;
        } else if constexpr (EPI == EPI_OUT_W) {
          Cf[(size_t)rowg * N + colg] = sc * v;
        } else {
          Cf[(size_t)rowg * N + colg] += sc * v;
        }
      }
    }
  }
}

// fused fc1, BN=64/half (round-13 proven, 196us standalone)
DEV_INLINE void dev_gemm_fc1(char* lds, int sub,
                             const bf16_t* __restrict__ A, const bf16_t* __restrict__ Ba,
                             const bf16_t* __restrict__ Bb, bf16_t* __restrict__ C,
                             const float* __restrict__ bias_a, const float* __restrict__ bias_b,
                             int N, int K) {
  constexpr int BUF = 16384;
  const int tid = threadIdx.x;
  const int lane = tid & 63;
  const int wave = tid >> 6;
  const int lr = lane & 15;
  const int hi = lane >> 4;

  int bx, by;
  submap(sub, 64, 64, bx, by);

  const int bm = by * 128;
  const int bn = bx * 64;
  const int wm = (wave >> 1) * 64;
  const int wn = (wave & 1) * 32;

  const int srow = tid >> 2;
  const int scol = 8 * ((tid & 3) ^ ((tid >> 3) & 3));
  const bf16_t* Asrc = A + (size_t)(bm + srow) * K + scol;
  const bf16_t* Basrc = Ba + (size_t)(bn + srow) * K + scol;
  const bf16_t* Bbsrc = Bb + (size_t)(bn + srow) * K + scol;
  const size_t r64K = (size_t)64 * K;
  const int NT = K >> 5;

  f32x4 aca[4][2], acb[4][2];
#pragma unroll
  for (int a = 0; a < 4; ++a)
#pragma unroll
    for (int b = 0; b < 2; ++b)
#pragma unroll
      for (int j = 0; j < 4; ++j) { aca[a][b][j] = 0.f; acb[a][b][j] = 0.f; }

  auto stage = [&](int t) {
    char* l = lds + (t & 1) * BUF + tid * 16;
    const bf16_t* ga = Asrc + (size_t)t * 32;
    gload16(ga, (bf16_t*)l);
    gload16(ga + r64K, (bf16_t*)(l + 4096));
    gload16(Basrc + (size_t)t * 32, (bf16_t*)(l + 8192));
    gload16(Bbsrc + (size_t)t * 32, (bf16_t*)(l + 12288));
  };
  auto rd = [&](int base, int row) -> bf16x8 {
    int off = base + (row << 6) + ((hi ^ ((row >> 1) & 3)) << 4);
    return *(const bf16x8*)(lds + off);
  };

  stage(0);

  for (int t = 0; t < NT; ++t) {
    VMCNT(0);
    BARF();
    const int buf = (t & 1) * BUF;
    bf16x8 afr[4], bfa[2], bfb[2];
#pragma unroll
    for (int i = 0; i < 4; ++i) afr[i] = rd(buf, wm + i * 16 + lr);
#pragma unroll
    for (int ni = 0; ni < 2; ++ni) bfa[ni] = rd(buf + 8192, wn + ni * 16 + lr);
#pragma unroll
    for (int ni = 0; ni < 2; ++ni) bfb[ni] = rd(buf + 12288, wn + ni * 16 + lr);
    if (t + 1 < NT) stage(t + 1);
    __builtin_amdgcn_s_setprio(1);
#pragma unroll
    for (int i = 0; i < 4; ++i)
#pragma unroll
      for (int ni = 0; ni < 2; ++ni) {
        aca[i][ni] = __builtin_amdgcn_mfma_f32_16x16x32_bf16(afr[i], bfa[ni], aca[i][ni], 0, 0, 0);
        acb[i][ni] = __builtin_amdgcn_mfma_f32_16x16x32_bf16(afr[i], bfb[ni], acb[i][ni], 0, 0, 0);
      }
    __builtin_amdgcn_s_setprio(0);
  }

  float bva[2], bvb[2];
#pragma unroll
  for (int ni = 0; ni < 2; ++ni) {
    bva[ni] = bias_a[bn + wn + ni * 16 + lr];
    bvb[ni] = bias_b[bn + wn + ni * 16 + lr];
  }
#pragma unroll
  for (int mi = 0; mi < 4; ++mi) {
#pragma unroll
    for (int j = 0; j < 4; ++j) {
      const int rowg = bm + wm + mi * 16 + hi * 4 + j;
#pragma unroll
      for (int ni = 0; ni < 2; ++ni) {
        const int colg = bn + wn + ni * 16 + lr;
        float va = aca[mi][ni][j] + bva[ni];
        float vb = acb[mi][ni][j] + bvb[ni];
        float s = va / (1.f + __expf(-va));
        C[(size_t)rowg * N + colg] = (bf16_t)(s * vb);
      }
    }
  }
}

// causal-conv GEMM, no im2col (round-11 proven)
DEV_INLINE void dev_gemm_conv(char* lds, int sub,
                              const bf16_t* __restrict__ h, const bf16_t* __restrict__ Bw,
                              bf16_t* __restrict__ Cb, const float* __restrict__ bias,
                              const bf16_t* __restrict__ zpad) {
  constexpr int N = SDIM;
  constexpr int K = SDIM * 4;
  constexpr int BUF = 16384;
  const int tid = threadIdx.x;
  const int lane = tid & 63;
  const int wave = tid >> 6;
  const int lr = lane & 15;
  const int hi = lane >> 4;

  int bx, by;
  submap(sub, 8, 64, bx, by);

  const int bm = by * 128;
  const int bn = bx * 128;
  const int wm = (wave >> 1) * 64;
  const int wn = (wave & 1) * 64;

  const int srow = tid >> 2;
  const int scol = 8 * ((tid & 3) ^ ((tid >> 3) & 3));
  const int row0 = bm + srow;
  const int tt0 = row0 & (TSEQ - 1);
  const bf16_t* Bsrc = Bw + (size_t)(bn + srow) * K + scol;
  const size_t r64K = (size_t)64 * K;
  const int NT = K >> 5;

  f32x4 acc[4][4];
#pragma unroll
  for (int a = 0; a < 4; ++a)
#pragma unroll
    for (int b = 0; b < 4; ++b)
#pragma unroll
      for (int j = 0; j < 4; ++j) acc[a][b][j] = 0.f;

  auto stage = [&](int t) {
    char* l = lds + (t & 1) * BUF + tid * 16;
    const int k = t >> 5;
    const int si = (t & 31) * 32 + scol;
    const bf16_t* ga0 = (tt0 + k >= 3)
        ? h + (size_t)(row0 + k - 3) * SDIM + si : zpad;
    const bf16_t* ga1 = h + (size_t)(row0 + 64 + k - 3) * SDIM + si;
    gload16(ga0, (bf16_t*)l);
    gload16(ga1, (bf16_t*)(l + 4096));
    const bf16_t* gb = Bsrc + (size_t)t * 32;
    gload16(gb, (bf16_t*)(l + 8192));
    gload16(gb + r64K, (bf16_t*)(l + 12288));
  };
  auto rdA = [&](int buf, int row) -> bf16x8 {
    int off = buf + (row << 6) + ((hi ^ ((row >> 1) & 3)) << 4);
    return *(const bf16x8*)(lds + off);
  };
  auto rdB = [&](int buf, int row) -> bf16x8 {
    int off = buf + 8192 + (row << 6) + ((hi ^ ((row >> 1) & 3)) << 4);
    return *(const bf16x8*)(lds + off);
  };

  stage(0);

  for (int t = 0; t < NT; ++t) {
    VMCNT(0);
    BARF();
    const int buf = (t & 1) * BUF;
    bf16x8 bfr[4], afr[4];
#pragma unroll
    for (int ni = 0; ni < 4; ++ni) bfr[ni] = rdB(buf, wn + ni * 16 + lr);
#pragma unroll
    for (int i = 0; i < 4; ++i) afr[i] = rdA(buf, wm + i * 16 + lr);
    if (t + 1 < NT) stage(t + 1);
    __builtin_amdgcn_s_setprio(1);
#pragma unroll
    for (int i = 0; i < 4; ++i)
#pragma unroll
      for (int ni = 0; ni < 4; ++ni)
        acc[i][ni] = __builtin_amdgcn_mfma_f32_16x16x32_bf16(afr[i], bfr[ni], acc[i][ni], 0, 0, 0);
    __builtin_amdgcn_s_setprio(0);
  }

  float bv[4];
#pragma unroll
  for (int ni = 0; ni < 4; ++ni) bv[ni] = bias[bn + wn + ni * 16 + lr];
#pragma unroll
  for (int mi = 0; mi < 4; ++mi) {
#pragma unroll
    for (int j = 0; j < 4; ++j) {
      const int rowg = bm + wm + mi * 16 + hi * 4 + j;
#pragma unroll
      for (int ni = 0; ni < 4; ++ni) {
        const int colg = bn + wn + ni * 16 + lr;
        Cb[(size_t)rowg * N + colg] = (bf16_t)(acc[mi][ni][j] + bv[ni]);
      }
    }
  }
}

// fused MoE fc1, BN=64/half (round-13 proven)
DEV_INLINE void dev_moe_fc1(char* lds, int sub,
                            const bf16_t* __restrict__ A, const bf16_t* __restrict__ Bw, size_t zB,
                            bf16_t* __restrict__ C, const float* __restrict__ bias, int bstride,
                            const int* __restrict__ ntiles_p, const int* __restrict__ tile_e,
                            const int* __restrict__ tile_row, const int* __restrict__ idx,
                            int N, int K) {
  constexpr int BUF = 16384;
  const int tid = threadIdx.x;
  const int lane = tid & 63;
  const int wave = tid >> 6;
  const int lr = lane & 15;
  const int hi = lane >> 4;

  int bx, by;
  submap(sub, MAXTILES, 8, bx, by);

  const int ntiles = *ntiles_p;
  if (bx >= ntiles) return;
  const int e = tile_e[bx];
  const int bm = tile_row[bx];
  const int bn = by * 64;
  const int wm = (wave >> 1) * 64;
  const int wn = (wave & 1) * 32;

  const int srow = tid >> 2;
  const int scol = 8 * ((tid & 3) ^ ((tid >> 3) & 3));
  const int atok0 = idx[bm + srow];
  const int atok1 = idx[bm + srow + 64];
  const bf16_t* Asrc0 = A + (size_t)atok0 * K + scol;
  const bf16_t* Asrc1 = A + (size_t)atok1 * K + scol;
  const bf16_t* Basrc = Bw + (size_t)e * zB + (size_t)(bn + srow) * K + scol;
  const bf16_t* Bbsrc = Basrc + (size_t)HEXP * K;
  const int NT = K >> 5;

  f32x4 aca[4][2], acb[4][2];
#pragma unroll
  for (int a = 0; a < 4; ++a)
#pragma unroll
    for (int b = 0; b < 2; ++b)
#pragma unroll
      for (int j = 0; j < 4; ++j) { aca[a][b][j] = 0.f; acb[a][b][j] = 0.f; }

  auto stage = [&](int t) {
    char* l = lds + (t & 1) * BUF + tid * 16;
    gload16(Asrc0 + (size_t)t * 32, (bf16_t*)l);
    gload16(Asrc1 + (size_t)t * 32, (bf16_t*)(l + 4096));
    gload16(Basrc + (size_t)t * 32, (bf16_t*)(l + 8192));
    gload16(Bbsrc + (size_t)t * 32, (bf16_t*)(l + 12288));
  };
  auto rd = [&](int base, int row) -> bf16x8 {
    int off = base + (row << 6) + ((hi ^ ((row >> 1) & 3)) << 4);
    return *(const bf16x8*)(lds + off);
  };

  stage(0);

  for (int t = 0; t < NT; ++t) {
    VMCNT(0);
    BARF();
    const int buf = (t & 1) * BUF;
    bf16x8 afr[4], bfa[2], bfb[2];
#pragma unroll
    for (int i = 0; i < 4; ++i) afr[i] = rd(buf, wm + i * 16 + lr);
#pragma unroll
    for (int ni = 0; ni < 2; ++ni) bfa[ni] = rd(buf + 8192, wn + ni * 16 + lr);
#pragma unroll
    for (int ni = 0; ni < 2; ++ni) bfb[ni] = rd(buf + 12288, wn + ni * 16 + lr);
    if (t + 1 < NT) stage(t + 1);
    __builtin_amdgcn_s_setprio(1);
#pragma unroll
    for (int i = 0; i < 4; ++i)
#pragma unroll
      for (int ni = 0; ni < 2; ++ni) {
        aca[i][ni] = __builtin_amdgcn_mfma_f32_16x16x32_bf16(afr[i], bfa[ni], aca[i][ni], 0, 0, 0);
        acb[i][ni] = __builtin_amdgcn_mfma_f32_16x16x32_bf16(afr[i], bfb[ni], acb[i][ni], 0, 0, 0);
      }
    __builtin_amdgcn_s_setprio(0);
  }

  const float* bpa = bias + (size_t)e * bstride;
  const float* bpb = bpa + HEXP;
  float bva[2], bvb[2];
#pragma unroll
  for (int ni = 0; ni < 2; ++ni) {
    bva[ni] = bpa[bn + wn + ni * 16 + lr];
    bvb[ni] = bpb[bn + wn + ni * 16 + lr];
  }
#pragma unroll
  for (int mi = 0; mi < 4; ++mi) {
#pragma unroll
    for (int j = 0; j < 4; ++j) {
      const int slot = bm + wm + mi * 16 + hi * 4 + j;
#pragma unroll
      for (int ni = 0; ni < 2; ++ni) {
        const int colg = bn + wn + ni * 16 + lr;
        float va = aca[mi][ni][j] + bva[ni];
        float vb = acb[mi][ni][j] + bvb[ni];
        float s = va / (1.f + __expf(-va));
        C[(size_t)slot * N + colg] = (bf16_t)(s * vb);
      }
    }
  }
}

// MoE fc2: slot-linear A -> eo slot rows (round-11 proven)
DEV_INLINE void dev_moe_fc2(char* lds, int sub,
                            const bf16_t* __restrict__ A, const bf16_t* __restrict__ Bw, size_t zB,
                            bf16_t* __restrict__ Cb, const float* __restrict__ bias, int bstride,
                            const int* __restrict__ ntiles_p, const int* __restrict__ tile_e,
                            const int* __restrict__ tile_row,
                            int N, int K) {
  constexpr int BUF = 16384;
  const int tid = threadIdx.x;
  const int lane = tid & 63;
  const int wave = tid >> 6;
  const int lr = lane & 15;
  const int hi = lane >> 4;

  int bx, by;
  submap(sub, MAXTILES, 8, bx, by);

  const int ntiles = *ntiles_p;
  if (bx >= ntiles) return;
  const int e = tile_e[bx];
  const int bm = tile_row[bx];
  const int bn = by * 128;
  const int wm = (wave >> 1) * 64;
  const int wn = (wave & 1) * 64;

  const int srow = tid >> 2;
  const int scol = 8 * ((tid & 3) ^ ((tid >> 3) & 3));
  const bf16_t* Asrc = A + (size_t)(bm + srow) * K + scol;
  const bf16_t* Bsrc = Bw + (size_t)e * zB + (size_t)(bn + srow) * K + scol;
  const size_t r64K = (size_t)64 * K;
  const int NT = K >> 5;

  f32x4 acc[4][4];
#pragma unroll
  for (int a = 0; a < 4; ++a)
#pragma unroll
    for (int b = 0; b < 4; ++b)
#pragma unroll
      for (int j = 0; j < 4; ++j) acc[a][b][j] = 0.f;

  auto stage = [&](int t) {
    char* l = lds + (t & 1) * BUF + tid * 16;
    gload16(Asrc + (size_t)t * 32, (bf16_t*)l);
    gload16(Asrc + (size_t)t * 32 + r64K, (bf16_t*)(l + 4096));
    gload16(Bsrc + (size_t)t * 32, (bf16_t*)(l + 8192));
    gload16(Bsrc + (size_t)t * 32 + r64K, (bf16_t*)(l + 12288));
  };
  auto rdA = [&](int buf, int row) -> bf16x8 {
    int off = buf + (row << 6) + ((hi ^ ((row >> 1) & 3)) << 4);
    return *(const bf16x8*)(lds + off);
  };
  auto rdB = [&](int buf, int row) -> bf16x8 {
    int off = buf + 8192 + (row << 6) + ((hi ^ ((row >> 1) & 3)) << 4);
    return *(const bf16x8*)(lds + off);
  };

  stage(0);

  for (int t = 0; t < NT; ++t) {
    VMCNT(0);
    BARF();
    const int buf = (t & 1) * BUF;
    bf16x8 bfr[4], afr[4];
#pragma unroll
    for (int ni = 0; ni < 4; ++ni) bfr[ni] = rdB(buf, wn + ni * 16 + lr);
#pragma unroll
    for (int i = 0; i < 4; ++i) afr[i] = rdA(buf, wm + i * 16 + lr);
    if (t + 1 < NT) stage(t + 1);
    __builtin_amdgcn_s_setprio(1);
#pragma unroll
    for (int i = 0; i < 4; ++i)
#pragma unroll
      for (int ni = 0; ni < 4; ++ni)
        acc[i][ni] = __builtin_amdgcn_mfma_f32_16x16x32_bf16(afr[i], bfr[ni], acc[i][ni], 0, 0, 0);
    __builtin_amdgcn_s_setprio(0);
  }

  const float* bp = bias + (size_t)e * bstride;
  float bv[4];
#pragma unroll
  for (int ni = 0; ni < 4; ++ni) bv[ni] = bp[bn + wn + ni * 16 + lr];
#pragma unroll
  for (int mi = 0; mi < 4; ++mi) {
#pragma unroll
    for (int j = 0; j < 4; ++j) {
      const int slot = bm + wm + mi * 16 + hi * 4 + j;
#pragma unroll
      for (int ni = 0; ni < 4; ++ni) {
        const int colg = bn + wn + ni * 16 + lr;
        Cb[(size_t)slot * N + colg] = (bf16_t)(acc[mi][ni][j] + bv[ni]);
      }
    }
  }
}

// ---------------- setup mega-kernel: all conversions + router + zero ----------------
DEV_INLINE void dev_conv8(const float* __restrict__ src, bf16_t* __restrict__ dst, int sub) {
  int i = sub * 256 + threadIdx.x;
  const float4* s = (const float4*)src + (size_t)i * 2;
  float4 v0 = s[0], v1 = s[1];
  bf16x8 o;
  o[0] = (bf16_t)v0.x; o[1] = (bf16_t)v0.y; o[2] = (bf16_t)v0.z; o[3] = (bf16_t)v0.w;
  o[4] = (bf16_t)v1.x; o[5] = (bf16_t)v1.y; o[6] = (bf16_t)v1.z; o[7] = (bf16_t)v1.w;
  *((bf16x8*)dst + i) = o;
}

__global__ __launch_bounds__(256) void k_setup(
    const float* __restrict__ x, const float* __restrict__ d1W,
    const float* __restrict__ d2W, const float* __restrict__ sWin,
    const float* __restrict__ sWo, const float* __restrict__ eW1,
    const float* __restrict__ eW2, const float* __restrict__ sWc,
    const float* __restrict__ rW, const float* __restrict__ rb,
    const float* __restrict__ mW, const float* __restrict__ mb,
    bf16_t* __restrict__ xb, bf16_t* __restrict__ wd1, bf16_t* __restrict__ wd2,
    bf16_t* __restrict__ wsin, bf16_t* __restrict__ wsout,
    bf16_t* __restrict__ we1, bf16_t* __restrict__ we2, bf16_t* __restrict__ wconv,
    float* __restrict__ bw3, int* __restrict__ top2e, float* __restrict__ top2w,
    int* __restrict__ fill, int* __restrict__ idx, bf16_t* __restrict__ zpad) {
  const int b = blockIdx.x;
  if (b < 4096) { dev_conv8(x, xb, b); return; }
  if (b < 8192) { dev_conv8(d1W, wd1, b - 4096); return; }
  if (b < 10240) { dev_conv8(d2W, wd2, b - 8192); return; }
  if (b < 10752) { dev_conv8(sWin, wsin, b - 10240); return; }
  if (b < 11264) { dev_conv8(sWo, wsout, b - 10752); return; }
  if (b < 15360) { dev_conv8(eW1, we1, b - 11264); return; }
  if (b < 17408) { dev_conv8(eW2, we2, b - 15360); return; }
  if (b < 19456) {  // convw: [S][S][K] f32 -> [S][K*S] bf16
    int i = (b - 17408) * 256 + threadIdx.x;
    size_t flat = (size_t)i * 8;
    int s = (int)(flat >> 12);
    int col = (int)(flat & 4095);
    int k = col >> 10;
    int si0 = col & 1023;
    const float* sp = sWc + (size_t)s * 4096 + k;
    bf16x8 o;
#pragma unroll
    for (int j = 0; j < 8; ++j) o[j] = (bf16_t)sp[(size_t)(si0 + j) * 4];
    *(bf16x8*)(wconv + flat) = o;
    return;
  }
  if (b < 21504) {  // router
    int wave = threadIdx.x >> 6, lane = threadIdx.x & 63;
    int t = (b - 19456) * 4 + wave;
    const float* xr = x + (size_t)t * DDIM;
    float xv[16];
#pragma unroll
    for (int i = 0; i < 16; i += 4) *(float4*)&xv[i] = *(const float4*)&xr[lane * 16 + i];
    float acc[11];
#pragma unroll
    for (int j = 0; j < 11; ++j) {
      const float* w = (j < 3) ? (rW + j * DDIM) : (mW + (j - 3) * DDIM);
      float s = 0.f;
#pragma unroll
      for (int i = 0; i < 16; i += 4) {
        float4 wv = *(const float4*)&w[lane * 16 + i];
        s += xv[i] * wv.x + xv[i + 1] * wv.y + xv[i + 2] * wv.z + xv[i + 3] * wv.w;
      }
      acc[j] = s;
    }
#pragma unroll
    for (int j = 0; j < 11; ++j)
      for (int off = 32; off; off >>= 1) acc[j] += __shfl_xor(acc[j], off);
    if (lane == 0) {
      float l0 = acc[0] + rb[0], l1 = acc[1] + rb[1], l2 = acc[2] + rb[2];
      float mx = fmaxf(l0, fmaxf(l1, l2));
      float e0 = expf(l0 - mx), e1 = expf(l1 - mx), e2 = expf(l2 - mx);
      float inv = 1.f / (e0 + e1 + e2);
      float w2 = e2 * inv;
      bw3[t * 3 + 0] = e0 * inv; bw3[t * 3 + 1] = e1 * inv; bw3[t * 3 + 2] = w2;
      float lg[8];
#pragma unroll
      for (int e = 0; e < 8; ++e) lg[e] = acc[3 + e] + mb[e];
      int i0 = 0;
#pragma unroll
      for (int e = 1; e < 8; ++e) if (lg[e] > lg[i0]) i0 = e;
      int i1 = -1;
#pragma unroll
      for (int e = 0; e < 8; ++e) {
        if (e == i0) continue;
        if (i1 < 0 || lg[e] > lg[i1]) i1 = e;
      }
      float ee = expf(lg[i1] - lg[i0]);
      float w0 = 1.f / (1.f + ee), w1 = ee / (1.f + ee);
      top2e[t * 2 + 0] = i0; top2e[t * 2 + 1] = i1;
      top2w[t * 2 + 0] = w2 * w0; top2w[t * 2 + 1] = w2 * w1;
    }
    return;
  }
  // zero fill/idx/zpad (68 blocks -> covers all of idx[MAXROWS])
  int i = (b - 21504) * 256 + threadIdx.x;
  if (i < NEXP) fill[i] = 0;
  if (i < 128) zpad[i] = (bf16_t)0.f;
  if (i < MAXROWS) idx[i] = 0;
}

// ---------------- count + scan fused (one block) ----------------
__global__ __launch_bounds__(1024) void k_count_scan(const int* __restrict__ top2e,
                                                     int* __restrict__ base,
                                                     int* __restrict__ ntiles,
                                                     int* __restrict__ tile_e,
                                                     int* __restrict__ tile_row) {
  __shared__ int hist[NEXP];
  const int tid = threadIdx.x;
  if (tid < NEXP) hist[tid] = 0;
  __syncthreads();
  int c[NEXP];
#pragma unroll
  for (int e = 0; e < NEXP; ++e) c[e] = 0;
#pragma unroll
  for (int j = 0; j < 2 * NTOK / 1024; ++j) {
    int v = top2e[j * 1024 + tid];
#pragma unroll
    for (int e = 0; e < NEXP; ++e) c[e] += (v == e) ? 1 : 0;
  }
#pragma unroll
  for (int e = 0; e < NEXP; ++e)
    for (int off = 32; off; off >>= 1) c[e] += __shfl_xor(c[e], off);
  if ((tid & 63) == 0) {
#pragma unroll
    for (int e = 0; e < NEXP; ++e) atomicAdd(&hist[e], c[e]);
  }
  __syncthreads();
  if (tid == 0) {
    int b = 0, tt = 0;
    for (int e = 0; e < NEXP; ++e) {
      base[e] = b;
      int nt = (hist[e] + 127) >> 7;
      for (int j = 0; j < nt; ++j) { tile_e[tt] = e; tile_row[tt] = b + j * 128; ++tt; }
      b += nt * 128;
    }
    *ntiles = tt;
  }
}

// ---------------- scatter (round-8 proven) ----------------
__global__ __launch_bounds__(256) void k_scatter(const int* __restrict__ top2e,
                                                 const float* __restrict__ top2w,
                                                 const int* __restrict__ base,
                                                 int* __restrict__ fill,
                                                 int* __restrict__ idx,
                                                 int* __restrict__ slotmap) {
  __shared__ int lcnt[NEXP];
  __shared__ int lbase[NEXP];
  const int tid = threadIdx.x;
  const int t = blockIdx.x * 256 + tid;
  if (tid < NEXP) lcnt[tid] = 0;
  __syncthreads();
  const int e0 = top2e[t * 2 + 0], e1 = top2e[t * 2 + 1];
  const int s0 = atomicAdd(&lcnt[e0], 1);
  const int s1 = atomicAdd(&lcnt[e1], 1);
  __syncthreads();
  if (tid < NEXP) lbase[tid] = atomicAdd(&fill[tid], lcnt[tid]);
  __syncthreads();
  const int p0 = base[e0] + lbase[e0] + s0;
  const int p1 = base[e1] + lbase[e1] + s1;
  idx[p0] = t; idx[p1] = t;
  slotmap[t * 2 + 0] = p0;
  slotmap[t * 2 + 1] = p1;
}

// ---------------- phase 1: dense fc1 | moe fc1 | wsin ----------------
__global__ __launch_bounds__(256) void k_phase1(
    const bf16_t* __restrict__ xb, const bf16_t* __restrict__ wd1,
    const float* __restrict__ d1b, bf16_t* __restrict__ Cc,
    const bf16_t* __restrict__ we1, const float* __restrict__ eb1,
    bf16_t* __restrict__ mo,
    const int* __restrict__ ntl, const int* __restrict__ t_e,
    const int* __restrict__ t_row, const int* __restrict__ idx,
    const bf16_t* __restrict__ wsin, const float* __restrict__ sbin,
    bf16_t* __restrict__ th) {
  __shared__ __align__(16) char lds[32768];
  const int b = blockIdx.x;
  if (b < 4096) {
    dev_gemm_fc1(lds, b, xb, wd1, wd1 + (size_t)HDIM * DDIM, Cc, d1b, d1b + HDIM,
                 HDIM, DDIM);
  } else if (b < 5184) {
    dev_moe_fc1(lds, b - 4096, xb, we1, (size_t)2 * HEXP * DDIM, mo, eb1, 2 * HEXP,
                ntl, t_e, t_row, idx, HEXP, DDIM);
  } else {
    dev_gemm<EPI_BF16>(lds, b - 5184, 8, 64, xb, wsin, th, nullptr, sbin,
                       nullptr, 0, SDIM, DDIM);
  }
}

// ---------------- phase 2: d2 | conv | moe fc2 ----------------
__global__ __launch_bounds__(256) void k_phase2(
    const bf16_t* __restrict__ Cc, const bf16_t* __restrict__ wd2,
    const float* __restrict__ d2b, const float* __restrict__ bw3,
    float* __restrict__ out,
    const bf16_t* __restrict__ th, const bf16_t* __restrict__ wconv,
    const float* __restrict__ sbc, bf16_t* __restrict__ tsq,
    const bf16_t* __restrict__ zpad,
    const bf16_t* __restrict__ mo, const bf16_t* __restrict__ we2,
    const float* __restrict__ eb2, bf16_t* __restrict__ eo,
    const int* __restrict__ ntl, const int* __restrict__ t_e,
    const int* __restrict__ t_row) {
  __shared__ __align__(16) char lds[32768];
  const int b = blockIdx.x;
  if (b < 512) {
    dev_gemm<EPI_OUT_W>(lds, b, 8, 64, Cc, wd2, nullptr, out, d2b, bw3, 3,
                        DDIM, HDIM);
  } else if (b < 1024) {
    dev_gemm_conv(lds, b - 512, th, wconv, tsq, sbc, zpad);
  } else {
    dev_moe_fc2(lds, b - 1024, mo, we2, (size_t)DDIM * HEXP, eo, eb2, DDIM,
                ntl, t_e, t_row, DDIM, HEXP);
  }
}

// ---------------- wsout (standalone: += out, must not overlap combine) ----------------
__global__ __launch_bounds__(256) void k_wsout(
    const bf16_t* __restrict__ tsq, const bf16_t* __restrict__ wsout,
    float* __restrict__ out, const float* __restrict__ sbo,
    const float* __restrict__ bw3) {
  __shared__ __align__(16) char lds[32768];
  dev_gemm<EPI_OUT_A>(lds, blockIdx.x, 8, 64, tsq, wsout, nullptr, out, sbo,
                      bw3 + 1, 3, DDIM, SDIM);
}

// ---------------- MoE combine: out[t] += g0*eo[s0] + g1*eo[s1] ----------------
__global__ __launch_bounds__(256) void k_combine(const bf16_t* __restrict__ eo,
                                                 const int* __restrict__ slotmap,
                                                 const float* __restrict__ top2w,
                                                 float* __restrict__ out) {
  int wave = threadIdx.x >> 6, lane = threadIdx.x & 63;
  int t = blockIdx.x * 4 + wave;
  const int s0 = slotmap[t * 2 + 0], s1 = slotmap[t * 2 + 1];
  const float g0 = top2w[t * 2 + 0], g1 = top2w[t * 2 + 1];
  const bf16x8* r0 = (const bf16x8*)(eo + (size_t)s0 * DDIM);
  const bf16x8* r1 = (const bf16x8*)(eo + (size_t)s1 * DDIM);
  float* orow = out + (size_t)t * DDIM;
#pragma unroll
  for (int i = 0; i < 2; ++i) {
    const int d = lane + i * 64;
    bf16x8 a = r0[d], b = r1[d];
    float vo[8];
    *(float4*)&vo[0] = *(const float4*)&orow[d * 8];
    *(float4*)&vo[4] = *(const float4*)&orow[d * 8 + 4];
#pragma unroll
    for (int j = 0; j < 8; ++j) vo[j] += g0 * (float)a[j] + g1 * (float)b[j];
    *(float4*)&orow[d * 8] = *(float4*)&vo[0];
    *(float4*)&orow[d * 8 + 4] = *(float4*)&vo[4];
  }
}

// ---------------------------------------------------------------------------
extern "C" void kernel_launch(void* const* d_in, const int* in_sizes, int n_in,
                              void* d_out, int out_size, void* d_ws, size_t ws_size,
                              hipStream_t stream) {
  (void)in_sizes; (void)n_in; (void)out_size; (void)ws_size;
  const float* x    = (const float*)d_in[0];
  const float* rW   = (const float*)d_in[1];
  const float* rb   = (const float*)d_in[2];
  const float* d1W  = (const float*)d_in[3];
  const float* d1b  = (const float*)d_in[4];
  const float* d2W  = (const float*)d_in[5];
  const float* d2b  = (const float*)d_in[6];
  const float* sWin = (const float*)d_in[7];
  const float* sbin = (const float*)d_in[8];
  const float* sWc  = (const float*)d_in[9];
  const float* sbc  = (const float*)d_in[10];
  const float* sWo  = (const float*)d_in[11];
  const float* sbo  = (const float*)d_in[12];
  const float* mW   = (const float*)d_in[13];
  const float* mb   = (const float*)d_in[14];
  const float* eW1  = (const float*)d_in[15];
  const float* eb1  = (const float*)d_in[16];
  const float* eW2  = (const float*)d_in[17];
  const float* eb2  = (const float*)d_in[18];
  float* out = (float*)d_out;

  char* ws = (char*)d_ws;
  size_t off = 0;
  auto alloc = [&](size_t bytes) -> void* {
    void* p = ws + off;
    off += (bytes + 255) & ~(size_t)255;
    return p;
  };
  bf16_t* xb    = (bf16_t*)alloc((size_t)NTOK * DDIM * 2);
  bf16_t* wd1   = (bf16_t*)alloc((size_t)2 * HDIM * DDIM * 2);
  bf16_t* wd2   = (bf16_t*)alloc((size_t)DDIM * HDIM * 2);
  bf16_t* wsin  = (bf16_t*)alloc((size_t)SDIM * DDIM * 2);
  bf16_t* wconv = (bf16_t*)alloc((size_t)SDIM * SDIM * 4 * 2);
  bf16_t* wsout = (bf16_t*)alloc((size_t)DDIM * SDIM * 2);
  bf16_t* we1   = (bf16_t*)alloc((size_t)NEXP * 2 * HEXP * DDIM * 2);
  bf16_t* we2   = (bf16_t*)alloc((size_t)NEXP * DDIM * HEXP * 2);
  bf16_t* Cc    = (bf16_t*)alloc((size_t)NTOK * HDIM * 2);
  bf16_t* Dd    = (bf16_t*)alloc((size_t)NTOK * HDIM * 2);  // eo [0,35.7MB) | mo @36MB
  bf16_t* th    = (bf16_t*)alloc((size_t)NTOK * SDIM * 2);
  bf16_t* tsq   = (bf16_t*)alloc((size_t)NTOK * SDIM * 2);
  float*  bw3   = (float*)alloc((size_t)NTOK * 3 * 4);
  int*    top2e = (int*)alloc((size_t)NTOK * 2 * 4);
  float*  top2w = (float*)alloc((size_t)NTOK * 2 * 4);
  int*    slotm = (int*)alloc((size_t)NTOK * 2 * 4);
  int*    fill  = (int*)alloc(NEXP * 4);
  int*    basep = (int*)alloc((NEXP + 1) * 4);
  int*    ntl   = (int*)alloc(4);
  int*    t_e   = (int*)alloc(MAXTILES * 4);
  int*    t_row = (int*)alloc(MAXTILES * 4);
  int*    idx   = (int*)alloc(MAXROWS * 4);
  bf16_t* zpad  = (bf16_t*)alloc(256);
  bf16_t* eo = Dd;
  bf16_t* mo = Dd + (size_t)18 * 1024 * 1024;

  k_setup<<<21572, 256, 0, stream>>>(
      x, d1W, d2W, sWin, sWo, eW1, eW2, sWc, rW, rb, mW, mb,
      xb, wd1, wd2, wsin, wsout, we1, we2, wconv,
      bw3, top2e, top2w, fill, idx, zpad);
  k_count_scan<<<1, 1024, 0, stream>>>(top2e, basep, ntl, t_e, t_row);
  k_scatter<<<NTOK / 256, 256, 0, stream>>>(top2e, top2w, basep, fill, idx, slotm);

  k_phase1<<<5696, 256, 0, stream>>>(
      xb, wd1, d1b, Cc, we1, eb1, mo, ntl, t_e, t_row, idx, wsin, sbin, th);
  k_phase2<<<2112, 256, 0, stream>>>(
      Cc, wd2, d2b, bw3, out, th, wconv, sbc, tsq, zpad,
      mo, we2, eb2, eo, ntl, t_e, t_row);
  k_wsout<<<512, 256, 0, stream>>>(tsq, wsout, out, sbo, bw3);
  k_combine<<<NTOK / 4, 256, 0, stream>>>(eo, slotm, top2w, out);
}

// Round 18
// 588.779 us; speedup vs baseline: 1.1752x; 1.0004x over previous
//
#include <hip/hip_runtime.h>
#include <hip/hip_bf16.h>
#include <cstdint>

typedef __bf16 bf16_t;
typedef __bf16 bf16x8 __attribute__((ext_vector_type(8)));
typedef float f32x4 __attribute__((ext_vector_type(4)));

#define DEV_INLINE __device__ __forceinline__

#define NTOK 8192
#define DDIM 1024
#define HDIM 4096
#define SDIM 1024
#define NEXP 8
#define HEXP 512
#define TSEQ 2048
#define MAXTILES 136
#define MAXROWS (MAXTILES * 128)

#define VMCNT(n) asm volatile("s_waitcnt vmcnt(" #n ")" ::: "memory")
#define BARF() asm volatile("s_barrier" ::: "memory")

DEV_INLINE void gload16(const bf16_t* g, bf16_t* l) {
  __builtin_amdgcn_global_load_lds((const __attribute__((address_space(1))) void*)g,
                                   (__attribute__((address_space(3))) void*)l, 16, 0, 0);
}

// sub-grid XCD swizzle (sub-range bases are %8==0 so global mapping holds)
DEV_INLINE void submap(int sub, int nbx, int nby, int& bx, int& by) {
  const int nwg = nbx * nby;
  int id = sub;
  if ((nwg & 7) == 0) id = (id & 7) * (nwg >> 3) + (id >> 3);
  bx = id % nbx;
  by = id / nbx;
}

constexpr int EPI_BF16 = 0;
constexpr int EPI_OUT_W = 1;
constexpr int EPI_OUT_A = 2;

// ---------------- device GEMM cores (round-13/15 proven bodies) ----------------
template <int EPI>
DEV_INLINE void dev_gemm(char* lds, int sub, int nbx, int nby,
                         const bf16_t* __restrict__ A, const bf16_t* __restrict__ B,
                         bf16_t* __restrict__ Cb, float* __restrict__ Cf,
                         const float* __restrict__ bias,
                         const float* __restrict__ scale, int sstride,
                         int N, int K) {
  constexpr int BUF = 16384;
  const int tid = threadIdx.x;
  const int lane = tid & 63;
  const int wave = tid >> 6;
  const int lr = lane & 15;
  const int hi = lane >> 4;

  int bx, by;
  submap(sub, nbx, nby, bx, by);

  const int bm = by * 128;
  const int bn = bx * 128;
  const int wm = (wave >> 1) * 64;
  const int wn = (wave & 1) * 64;

  const int srow = tid >> 2;
  const int scol = 8 * ((tid & 3) ^ ((tid >> 3) & 3));
  const bf16_t* Asrc = A + (size_t)(bm + srow) * K + scol;
  const bf16_t* Bsrc = B + (size_t)(bn + srow) * K + scol;
  const size_t r64K = (size_t)64 * K;
  const int NT = K >> 5;

  f32x4 acc[4][4];
#pragma unroll
  for (int a = 0; a < 4; ++a)
#pragma unroll
    for (int b = 0; b < 4; ++b)
#pragma unroll
      for (int j = 0; j < 4; ++j) acc[a][b][j] = 0.f;

  auto stage = [&](int t) {
    char* l = lds + (t & 1) * BUF + tid * 16;
    const bf16_t* ga = Asrc + (size_t)t * 32;
    const bf16_t* gb = Bsrc + (size_t)t * 32;
    gload16(ga, (bf16_t*)l);
    gload16(ga + r64K, (bf16_t*)(l + 4096));
    gload16(gb, (bf16_t*)(l + 8192));
    gload16(gb + r64K, (bf16_t*)(l + 12288));
  };
  auto rdA = [&](int buf, int row) -> bf16x8 {
    int off = buf + (row << 6) + ((hi ^ ((row >> 1) & 3)) << 4);
    return *(const bf16x8*)(lds + off);
  };
  auto rdB = [&](int buf, int row) -> bf16x8 {
    int off = buf + 8192 + (row << 6) + ((hi ^ ((row >> 1) & 3)) << 4);
    return *(const bf16x8*)(lds + off);
  };

  stage(0);

  for (int t = 0; t < NT; ++t) {
    VMCNT(0);
    BARF();
    const int buf = (t & 1) * BUF;
    bf16x8 bfr[4], afr[4];
#pragma unroll
    for (int ni = 0; ni < 4; ++ni) bfr[ni] = rdB(buf, wn + ni * 16 + lr);
#pragma unroll
    for (int i = 0; i < 4; ++i) afr[i] = rdA(buf, wm + i * 16 + lr);
    if (t + 1 < NT) stage(t + 1);
    __builtin_amdgcn_s_setprio(1);
#pragma unroll
    for (int i = 0; i < 4; ++i)
#pragma unroll
      for (int ni = 0; ni < 4; ++ni)
        acc[i][ni] = __builtin_amdgcn_mfma_f32_16x16x32_bf16(afr[i], bfr[ni], acc[i][ni], 0, 0, 0);
    __builtin_amdgcn_s_setprio(0);
  }

  float bv[4];
#pragma unroll
  for (int ni = 0; ni < 4; ++ni) bv[ni] = bias[bn + wn + ni * 16 + lr];
#pragma unroll
  for (int mi = 0; mi < 4; ++mi) {
#pragma unroll
    for (int j = 0; j < 4; ++j) {
      const int rowg = bm + wm + mi * 16 + hi * 4 + j;
      float sc = 0.f;
      if constexpr (EPI == EPI_OUT_W || EPI == EPI_OUT_A)
        sc = scale[(size_t)rowg * sstride];
#pragma unroll
      for (int ni = 0; ni < 4; ++ni) {
        const int colg = bn + wn + ni * 16 + lr;
        float v = acc[mi][ni][j] + bv[ni];
        if constexpr (EPI == EPI_BF16) {
          Cb[(size_t)rowg * N + colg] = (bf16_t)v;
        } else if constexpr (EPI == EPI_OUT_W) {
          Cf[(size_t)rowg * N + colg] = sc * v;
        } else {
          Cf[(size_t)rowg * N + colg] += sc * v;
        }
      }
    }
  }
}

// fused fc1, BN=64/half (round-13 proven, 196us standalone)
DEV_INLINE void dev_gemm_fc1(char* lds, int sub,
                             const bf16_t* __restrict__ A, const bf16_t* __restrict__ Ba,
                             const bf16_t* __restrict__ Bb, bf16_t* __restrict__ C,
                             const float* __restrict__ bias_a, const float* __restrict__ bias_b,
                             int N, int K) {
  constexpr int BUF = 16384;
  const int tid = threadIdx.x;
  const int lane = tid & 63;
  const int wave = tid >> 6;
  const int lr = lane & 15;
  const int hi = lane >> 4;

  int bx, by;
  submap(sub, 64, 64, bx, by);

  const int bm = by * 128;
  const int bn = bx * 64;
  const int wm = (wave >> 1) * 64;
  const int wn = (wave & 1) * 32;

  const int srow = tid >> 2;
  const int scol = 8 * ((tid & 3) ^ ((tid >> 3) & 3));
  const bf16_t* Asrc = A + (size_t)(bm + srow) * K + scol;
  const bf16_t* Basrc = Ba + (size_t)(bn + srow) * K + scol;
  const bf16_t* Bbsrc = Bb + (size_t)(bn + srow) * K + scol;
  const size_t r64K = (size_t)64 * K;
  const int NT = K >> 5;

  f32x4 aca[4][2], acb[4][2];
#pragma unroll
  for (int a = 0; a < 4; ++a)
#pragma unroll
    for (int b = 0; b < 2; ++b)
#pragma unroll
      for (int j = 0; j < 4; ++j) { aca[a][b][j] = 0.f; acb[a][b][j] = 0.f; }

  auto stage = [&](int t) {
    char* l = lds + (t & 1) * BUF + tid * 16;
    const bf16_t* ga = Asrc + (size_t)t * 32;
    gload16(ga, (bf16_t*)l);
    gload16(ga + r64K, (bf16_t*)(l + 4096));
    gload16(Basrc + (size_t)t * 32, (bf16_t*)(l + 8192));
    gload16(Bbsrc + (size_t)t * 32, (bf16_t*)(l + 12288));
  };
  auto rd = [&](int base, int row) -> bf16x8 {
    int off = base + (row << 6) + ((hi ^ ((row >> 1) & 3)) << 4);
    return *(const bf16x8*)(lds + off);
  };

  stage(0);

  for (int t = 0; t < NT; ++t) {
    VMCNT(0);
    BARF();
    const int buf = (t & 1) * BUF;
    bf16x8 afr[4], bfa[2], bfb[2];
#pragma unroll
    for (int i = 0; i < 4; ++i) afr[i] = rd(buf, wm + i * 16 + lr);
#pragma unroll
    for (int ni = 0; ni < 2; ++ni) bfa[ni] = rd(buf + 8192, wn + ni * 16 + lr);
#pragma unroll
    for (int ni = 0; ni < 2; ++ni) bfb[ni] = rd(buf + 12288, wn + ni * 16 + lr);
    if (t + 1 < NT) stage(t + 1);
    __builtin_amdgcn_s_setprio(1);
#pragma unroll
    for (int i = 0; i < 4; ++i)
#pragma unroll
      for (int ni = 0; ni < 2; ++ni) {
        aca[i][ni] = __builtin_amdgcn_mfma_f32_16x16x32_bf16(afr[i], bfa[ni], aca[i][ni], 0, 0, 0);
        acb[i][ni] = __builtin_amdgcn_mfma_f32_16x16x32_bf16(afr[i], bfb[ni], acb[i][ni], 0, 0, 0);
      }
    __builtin_amdgcn_s_setprio(0);
  }

  float bva[2], bvb[2];
#pragma unroll
  for (int ni = 0; ni < 2; ++ni) {
    bva[ni] = bias_a[bn + wn + ni * 16 + lr];
    bvb[ni] = bias_b[bn + wn + ni * 16 + lr];
  }
#pragma unroll
  for (int mi = 0; mi < 4; ++mi) {
#pragma unroll
    for (int j = 0; j < 4; ++j) {
      const int rowg = bm + wm + mi * 16 + hi * 4 + j;
#pragma unroll
      for (int ni = 0; ni < 2; ++ni) {
        const int colg = bn + wn + ni * 16 + lr;
        float va = aca[mi][ni][j] + bva[ni];
        float vb = acb[mi][ni][j] + bvb[ni];
        float s = va / (1.f + __expf(-va));
        C[(size_t)rowg * N + colg] = (bf16_t)(s * vb);
      }
    }
  }
}

// causal-conv GEMM, no im2col (round-11 proven)
DEV_INLINE void dev_gemm_conv(char* lds, int sub,
                              const bf16_t* __restrict__ h, const bf16_t* __restrict__ Bw,
                              bf16_t* __restrict__ Cb, const float* __restrict__ bias,
                              const bf16_t* __restrict__ zpad) {
  constexpr int N = SDIM;
  constexpr int K = SDIM * 4;
  constexpr int BUF = 16384;
  const int tid = threadIdx.x;
  const int lane = tid & 63;
  const int wave = tid >> 6;
  const int lr = lane & 15;
  const int hi = lane >> 4;

  int bx, by;
  submap(sub, 8, 64, bx, by);

  const int bm = by * 128;
  const int bn = bx * 128;
  const int wm = (wave >> 1) * 64;
  const int wn = (wave & 1) * 64;

  const int srow = tid >> 2;
  const int scol = 8 * ((tid & 3) ^ ((tid >> 3) & 3));
  const int row0 = bm + srow;
  const int tt0 = row0 & (TSEQ - 1);
  const bf16_t* Bsrc = Bw + (size_t)(bn + srow) * K + scol;
  const size_t r64K = (size_t)64 * K;
  const int NT = K >> 5;

  f32x4 acc[4][4];
#pragma unroll
  for (int a = 0; a < 4; ++a)
#pragma unroll
    for (int b = 0; b < 4; ++b)
#pragma unroll
      for (int j = 0; j < 4; ++j) acc[a][b][j] = 0.f;

  auto stage = [&](int t) {
    char* l = lds + (t & 1) * BUF + tid * 16;
    const int k = t >> 5;
    const int si = (t & 31) * 32 + scol;
    const bf16_t* ga0 = (tt0 + k >= 3)
        ? h + (size_t)(row0 + k - 3) * SDIM + si : zpad;
    const bf16_t* ga1 = h + (size_t)(row0 + 64 + k - 3) * SDIM + si;
    gload16(ga0, (bf16_t*)l);
    gload16(ga1, (bf16_t*)(l + 4096));
    const bf16_t* gb = Bsrc + (size_t)t * 32;
    gload16(gb, (bf16_t*)(l + 8192));
    gload16(gb + r64K, (bf16_t*)(l + 12288));
  };
  auto rdA = [&](int buf, int row) -> bf16x8 {
    int off = buf + (row << 6) + ((hi ^ ((row >> 1) & 3)) << 4);
    return *(const bf16x8*)(lds + off);
  };
  auto rdB = [&](int buf, int row) -> bf16x8 {
    int off = buf + 8192 + (row << 6) + ((hi ^ ((row >> 1) & 3)) << 4);
    return *(const bf16x8*)(lds + off);
  };

  stage(0);

  for (int t = 0; t < NT; ++t) {
    VMCNT(0);
    BARF();
    const int buf = (t & 1) * BUF;
    bf16x8 bfr[4], afr[4];
#pragma unroll
    for (int ni = 0; ni < 4; ++ni) bfr[ni] = rdB(buf, wn + ni * 16 + lr);
#pragma unroll
    for (int i = 0; i < 4; ++i) afr[i] = rdA(buf, wm + i * 16 + lr);
    if (t + 1 < NT) stage(t + 1);
    __builtin_amdgcn_s_setprio(1);
#pragma unroll
    for (int i = 0; i < 4; ++i)
#pragma unroll
      for (int ni = 0; ni < 4; ++ni)
        acc[i][ni] = __builtin_amdgcn_mfma_f32_16x16x32_bf16(afr[i], bfr[ni], acc[i][ni], 0, 0, 0);
    __builtin_amdgcn_s_setprio(0);
  }

  float bv[4];
#pragma unroll
  for (int ni = 0; ni < 4; ++ni) bv[ni] = bias[bn + wn + ni * 16 + lr];
#pragma unroll
  for (int mi = 0; mi < 4; ++mi) {
#pragma unroll
    for (int j = 0; j < 4; ++j) {
      const int rowg = bm + wm + mi * 16 + hi * 4 + j;
#pragma unroll
      for (int ni = 0; ni < 4; ++ni) {
        const int colg = bn + wn + ni * 16 + lr;
        Cb[(size_t)rowg * N + colg] = (bf16_t)(acc[mi][ni][j] + bv[ni]);
      }
    }
  }
}

// fused MoE fc1, BN=64/half (round-13 proven)
DEV_INLINE void dev_moe_fc1(char* lds, int sub,
                            const bf16_t* __restrict__ A, const bf16_t* __restrict__ Bw, size_t zB,
                            bf16_t* __restrict__ C, const float* __restrict__ bias, int bstride,
                            const int* __restrict__ ntiles_p, const int* __restrict__ tile_e,
                            const int* __restrict__ tile_row, const int* __restrict__ idx,
                            int N, int K) {
  constexpr int BUF = 16384;
  const int tid = threadIdx.x;
  const int lane = tid & 63;
  const int wave = tid >> 6;
  const int lr = lane & 15;
  const int hi = lane >> 4;

  int bx, by;
  submap(sub, MAXTILES, 8, bx, by);

  const int ntiles = *ntiles_p;
  if (bx >= ntiles) return;
  const int e = tile_e[bx];
  const int bm = tile_row[bx];
  const int bn = by * 64;
  const int wm = (wave >> 1) * 64;
  const int wn = (wave & 1) * 32;

  const int srow = tid >> 2;
  const int scol = 8 * ((tid & 3) ^ ((tid >> 3) & 3));
  const int atok0 = idx[bm + srow];
  const int atok1 = idx[bm + srow + 64];
  const bf16_t* Asrc0 = A + (size_t)atok0 * K + scol;
  const bf16_t* Asrc1 = A + (size_t)atok1 * K + scol;
  const bf16_t* Basrc = Bw + (size_t)e * zB + (size_t)(bn + srow) * K + scol;
  const bf16_t* Bbsrc = Basrc + (size_t)HEXP * K;
  const int NT = K >> 5;

  f32x4 aca[4][2], acb[4][2];
#pragma unroll
  for (int a = 0; a < 4; ++a)
#pragma unroll
    for (int b = 0; b < 2; ++b)
#pragma unroll
      for (int j = 0; j < 4; ++j) { aca[a][b][j] = 0.f; acb[a][b][j] = 0.f; }

  auto stage = [&](int t) {
    char* l = lds + (t & 1) * BUF + tid * 16;
    gload16(Asrc0 + (size_t)t * 32, (bf16_t*)l);
    gload16(Asrc1 + (size_t)t * 32, (bf16_t*)(l + 4096));
    gload16(Basrc + (size_t)t * 32, (bf16_t*)(l + 8192));
    gload16(Bbsrc + (size_t)t * 32, (bf16_t*)(l + 12288));
  };
  auto rd = [&](int base, int row) -> bf16x8 {
    int off = base + (row << 6) + ((hi ^ ((row >> 1) & 3)) << 4);
    return *(const bf16x8*)(lds + off);
  };

  stage(0);

  for (int t = 0; t < NT; ++t) {
    VMCNT(0);
    BARF();
    const int buf = (t & 1) * BUF;
    bf16x8 afr[4], bfa[2], bfb[2];
#pragma unroll
    for (int i = 0; i < 4; ++i) afr[i] = rd(buf, wm + i * 16 + lr);
#pragma unroll
    for (int ni = 0; ni < 2; ++ni) bfa[ni] = rd(buf + 8192, wn + ni * 16 + lr);
#pragma unroll
    for (int ni = 0; ni < 2; ++ni) bfb[ni] = rd(buf + 12288, wn + ni * 16 + lr);
    if (t + 1 < NT) stage(t + 1);
    __builtin_amdgcn_s_setprio(1);
#pragma unroll
    for (int i = 0; i < 4; ++i)
#pragma unroll
      for (int ni = 0; ni < 2; ++ni) {
        aca[i][ni] = __builtin_amdgcn_mfma_f32_16x16x32_bf16(afr[i], bfa[ni], aca[i][ni], 0, 0, 0);
        acb[i][ni] = __builtin_amdgcn_mfma_f32_16x16x32_bf16(afr[i], bfb[ni], acb[i][ni], 0, 0, 0);
      }
    __builtin_amdgcn_s_setprio(0);
  }

  const float* bpa = bias + (size_t)e * bstride;
  const float* bpb = bpa + HEXP;
  float bva[2], bvb[2];
#pragma unroll
  for (int ni = 0; ni < 2; ++ni) {
    bva[ni] = bpa[bn + wn + ni * 16 + lr];
    bvb[ni] = bpb[bn + wn + ni * 16 + lr];
  }
#pragma unroll
  for (int mi = 0; mi < 4; ++mi) {
#pragma unroll
    for (int j = 0; j < 4; ++j) {
      const int slot = bm + wm + mi * 16 + hi * 4 + j;
#pragma unroll
      for (int ni = 0; ni < 2; ++ni) {
        const int colg = bn + wn + ni * 16 + lr;
        float va = aca[mi][ni][j] + bva[ni];
        float vb = acb[mi][ni][j] + bvb[ni];
        float s = va / (1.f + __expf(-va));
        C[(size_t)slot * N + colg] = (bf16_t)(s * vb);
      }
    }
  }
}

// MoE fc2: slot-linear A -> eo slot rows (round-11 proven)
DEV_INLINE void dev_moe_fc2(char* lds, int sub,
                            const bf16_t* __restrict__ A, const bf16_t* __restrict__ Bw, size_t zB,
                            bf16_t* __restrict__ Cb, const float* __restrict__ bias, int bstride,
                            const int* __restrict__ ntiles_p, const int* __restrict__ tile_e,
                            const int* __restrict__ tile_row,
                            int N, int K) {
  constexpr int BUF = 16384;
  const int tid = threadIdx.x;
  const int lane = tid & 63;
  const int wave = tid >> 6;
  const int lr = lane & 15;
  const int hi = lane >> 4;

  int bx, by;
  submap(sub, MAXTILES, 8, bx, by);

  const int ntiles = *ntiles_p;
  if (bx >= ntiles) return;
  const int e = tile_e[bx];
  const int bm = tile_row[bx];
  const int bn = by * 128;
  const int wm = (wave >> 1) * 64;
  const int wn = (wave & 1) * 64;

  const int srow = tid >> 2;
  const int scol = 8 * ((tid & 3) ^ ((tid >> 3) & 3));
  const bf16_t* Asrc = A + (size_t)(bm + srow) * K + scol;
  const bf16_t* Bsrc = Bw + (size_t)e * zB + (size_t)(bn + srow) * K + scol;
  const size_t r64K = (size_t)64 * K;
  const int NT = K >> 5;

  f32x4 acc[4][4];
#pragma unroll
  for (int a = 0; a < 4; ++a)
#pragma unroll
    for (int b = 0; b < 4; ++b)
#pragma unroll
      for (int j = 0; j < 4; ++j) acc[a][b][j] = 0.f;

  auto stage = [&](int t) {
    char* l = lds + (t & 1) * BUF + tid * 16;
    gload16(Asrc + (size_t)t * 32, (bf16_t*)l);
    gload16(Asrc + (size_t)t * 32 + r64K, (bf16_t*)(l + 4096));
    gload16(Bsrc + (size_t)t * 32, (bf16_t*)(l + 8192));
    gload16(Bsrc + (size_t)t * 32 + r64K, (bf16_t*)(l + 12288));
  };
  auto rdA = [&](int buf, int row) -> bf16x8 {
    int off = buf + (row << 6) + ((hi ^ ((row >> 1) & 3)) << 4);
    return *(const bf16x8*)(lds + off);
  };
  auto rdB = [&](int buf, int row) -> bf16x8 {
    int off = buf + 8192 + (row << 6) + ((hi ^ ((row >> 1) & 3)) << 4);
    return *(const bf16x8*)(lds + off);
  };

  stage(0);

  for (int t = 0; t < NT; ++t) {
    VMCNT(0);
    BARF();
    const int buf = (t & 1) * BUF;
    bf16x8 bfr[4], afr[4];
#pragma unroll
    for (int ni = 0; ni < 4; ++ni) bfr[ni] = rdB(buf, wn + ni * 16 + lr);
#pragma unroll
    for (int i = 0; i < 4; ++i) afr[i] = rdA(buf, wm + i * 16 + lr);
    if (t + 1 < NT) stage(t + 1);
    __builtin_amdgcn_s_setprio(1);
#pragma unroll
    for (int i = 0; i < 4; ++i)
#pragma unroll
      for (int ni = 0; ni < 4; ++ni)
        acc[i][ni] = __builtin_amdgcn_mfma_f32_16x16x32_bf16(afr[i], bfr[ni], acc[i][ni], 0, 0, 0);
    __builtin_amdgcn_s_setprio(0);
  }

  const float* bp = bias + (size_t)e * bstride;
  float bv[4];
#pragma unroll
  for (int ni = 0; ni < 4; ++ni) bv[ni] = bp[bn + wn + ni * 16 + lr];
#pragma unroll
  for (int mi = 0; mi < 4; ++mi) {
#pragma unroll
    for (int j = 0; j < 4; ++j) {
      const int slot = bm + wm + mi * 16 + hi * 4 + j;
#pragma unroll
      for (int ni = 0; ni < 4; ++ni) {
        const int colg = bn + wn + ni * 16 + lr;
        Cb[(size_t)slot * N + colg] = (bf16_t)(acc[mi][ni][j] + bv[ni]);
      }
    }
  }
}

// ---------------- setup mega-kernel: all conversions + router + zero ----------------
DEV_INLINE void dev_conv8(const float* __restrict__ src, bf16_t* __restrict__ dst, int sub) {
  int i = sub * 256 + threadIdx.x;
  const float4* s = (const float4*)src + (size_t)i * 2;
  float4 v0 = s[0], v1 = s[1];
  bf16x8 o;
  o[0] = (bf16_t)v0.x; o[1] = (bf16_t)v0.y; o[2] = (bf16_t)v0.z; o[3] = (bf16_t)v0.w;
  o[4] = (bf16_t)v1.x; o[5] = (bf16_t)v1.y; o[6] = (bf16_t)v1.z; o[7] = (bf16_t)v1.w;
  *((bf16x8*)dst + i) = o;
}

__global__ __launch_bounds__(256) void k_setup(
    const float* __restrict__ x, const float* __restrict__ d1W,
    const float* __restrict__ d2W, const float* __restrict__ sWin,
    const float* __restrict__ sWo, const float* __restrict__ eW1,
    const float* __restrict__ eW2, const float* __restrict__ sWc,
    const float* __restrict__ rW, const float* __restrict__ rb,
    const float* __restrict__ mW, const float* __restrict__ mb,
    bf16_t* __restrict__ xb, bf16_t* __restrict__ wd1, bf16_t* __restrict__ wd2,
    bf16_t* __restrict__ wsin, bf16_t* __restrict__ wsout,
    bf16_t* __restrict__ we1, bf16_t* __restrict__ we2, bf16_t* __restrict__ wconv,
    float* __restrict__ bw3, int* __restrict__ top2e, float* __restrict__ top2w,
    int* __restrict__ fill, int* __restrict__ idx, bf16_t* __restrict__ zpad) {
  const int b = blockIdx.x;
  if (b < 4096) { dev_conv8(x, xb, b); return; }
  if (b < 8192) { dev_conv8(d1W, wd1, b - 4096); return; }
  if (b < 10240) { dev_conv8(d2W, wd2, b - 8192); return; }
  if (b < 10752) { dev_conv8(sWin, wsin, b - 10240); return; }
  if (b < 11264) { dev_conv8(sWo, wsout, b - 10752); return; }
  if (b < 15360) { dev_conv8(eW1, we1, b - 11264); return; }
  if (b < 17408) { dev_conv8(eW2, we2, b - 15360); return; }
  if (b < 19456) {  // convw: [S][S][K] f32 -> [S][K*S] bf16
    int i = (b - 17408) * 256 + threadIdx.x;
    size_t flat = (size_t)i * 8;
    int s = (int)(flat >> 12);
    int col = (int)(flat & 4095);
    int k = col >> 10;
    int si0 = col & 1023;
    const float* sp = sWc + (size_t)s * 4096 + k;
    bf16x8 o;
#pragma unroll
    for (int j = 0; j < 8; ++j) o[j] = (bf16_t)sp[(size_t)(si0 + j) * 4];
    *(bf16x8*)(wconv + flat) = o;
    return;
  }
  if (b < 21504) {  // router
    int wave = threadIdx.x >> 6, lane = threadIdx.x & 63;
    int t = (b - 19456) * 4 + wave;
    const float* xr = x + (size_t)t * DDIM;
    float xv[16];
#pragma unroll
    for (int i = 0; i < 16; i += 4) *(float4*)&xv[i] = *(const float4*)&xr[lane * 16 + i];
    float acc[11];
#pragma unroll
    for (int j = 0; j < 11; ++j) {
      const float* w = (j < 3) ? (rW + j * DDIM) : (mW + (j - 3) * DDIM);
      float s = 0.f;
#pragma unroll
      for (int i = 0; i < 16; i += 4) {
        float4 wv = *(const float4*)&w[lane * 16 + i];
        s += xv[i] * wv.x + xv[i + 1] * wv.y + xv[i + 2] * wv.z + xv[i + 3] * wv.w;
      }
      acc[j] = s;
    }
#pragma unroll
    for (int j = 0; j < 11; ++j)
      for (int off = 32; off; off >>= 1) acc[j] += __shfl_xor(acc[j], off);
    if (lane == 0) {
      float l0 = acc[0] + rb[0], l1 = acc[1] + rb[1], l2 = acc[2] + rb[2];
      float mx = fmaxf(l0, fmaxf(l1, l2));
      float e0 = expf(l0 - mx), e1 = expf(l1 - mx), e2 = expf(l2 - mx);
      float inv = 1.f / (e0 + e1 + e2);
      float w2 = e2 * inv;
      bw3[t * 3 + 0] = e0 * inv; bw3[t * 3 + 1] = e1 * inv; bw3[t * 3 + 2] = w2;
      float lg[8];
#pragma unroll
      for (int e = 0; e < 8; ++e) lg[e] = acc[3 + e] + mb[e];
      int i0 = 0;
#pragma unroll
      for (int e = 1; e < 8; ++e) if (lg[e] > lg[i0]) i0 = e;
      int i1 = -1;
#pragma unroll
      for (int e = 0; e < 8; ++e) {
        if (e == i0) continue;
        if (i1 < 0 || lg[e] > lg[i1]) i1 = e;
      }
      float ee = expf(lg[i1] - lg[i0]);
      float w0 = 1.f / (1.f + ee), w1 = ee / (1.f + ee);
      top2e[t * 2 + 0] = i0; top2e[t * 2 + 1] = i1;
      top2w[t * 2 + 0] = w2 * w0; top2w[t * 2 + 1] = w2 * w1;
    }
    return;
  }
  // zero fill/idx/zpad (68 blocks -> covers all of idx[MAXROWS])
  int i = (b - 21504) * 256 + threadIdx.x;
  if (i < NEXP) fill[i] = 0;
  if (i < 128) zpad[i] = (bf16_t)0.f;
  if (i < MAXROWS) idx[i] = 0;
}

// ---------------- count + scan fused (one block) ----------------
__global__ __launch_bounds__(1024) void k_count_scan(const int* __restrict__ top2e,
                                                     int* __restrict__ base,
                                                     int* __restrict__ ntiles,
                                                     int* __restrict__ tile_e,
                                                     int* __restrict__ tile_row) {
  __shared__ int hist[NEXP];
  const int tid = threadIdx.x;
  if (tid < NEXP) hist[tid] = 0;
  __syncthreads();
  int c[NEXP];
#pragma unroll
  for (int e = 0; e < NEXP; ++e) c[e] = 0;
#pragma unroll
  for (int j = 0; j < 2 * NTOK / 1024; ++j) {
    int v = top2e[j * 1024 + tid];
#pragma unroll
    for (int e = 0; e < NEXP; ++e) c[e] += (v == e) ? 1 : 0;
  }
#pragma unroll
  for (int e = 0; e < NEXP; ++e)
    for (int off = 32; off; off >>= 1) c[e] += __shfl_xor(c[e], off);
  if ((tid & 63) == 0) {
#pragma unroll
    for (int e = 0; e < NEXP; ++e) atomicAdd(&hist[e], c[e]);
  }
  __syncthreads();
  if (tid == 0) {
    int b = 0, tt = 0;
    for (int e = 0; e < NEXP; ++e) {
      base[e] = b;
      int nt = (hist[e] + 127) >> 7;
      for (int j = 0; j < nt; ++j) { tile_e[tt] = e; tile_row[tt] = b + j * 128; ++tt; }
      b += nt * 128;
    }
    *ntiles = tt;
  }
}

// ---------------- scatter (round-8 proven) ----------------
__global__ __launch_bounds__(256) void k_scatter(const int* __restrict__ top2e,
                                                 const float* __restrict__ top2w,
                                                 const int* __restrict__ base,
                                                 int* __restrict__ fill,
                                                 int* __restrict__ idx,
                                                 int* __restrict__ slotmap) {
  __shared__ int lcnt[NEXP];
  __shared__ int lbase[NEXP];
  const int tid = threadIdx.x;
  const int t = blockIdx.x * 256 + tid;
  if (tid < NEXP) lcnt[tid] = 0;
  __syncthreads();
  const int e0 = top2e[t * 2 + 0], e1 = top2e[t * 2 + 1];
  const int s0 = atomicAdd(&lcnt[e0], 1);
  const int s1 = atomicAdd(&lcnt[e1], 1);
  __syncthreads();
  if (tid < NEXP) lbase[tid] = atomicAdd(&fill[tid], lcnt[tid]);
  __syncthreads();
  const int p0 = base[e0] + lbase[e0] + s0;
  const int p1 = base[e1] + lbase[e1] + s1;
  idx[p0] = t; idx[p1] = t;
  slotmap[t * 2 + 0] = p0;
  slotmap[t * 2 + 1] = p1;
}

// ---------------- phase 1: dense fc1 | moe fc1 | wsin ----------------
__global__ __launch_bounds__(256) void k_phase1(
    const bf16_t* __restrict__ xb, const bf16_t* __restrict__ wd1,
    const float* __restrict__ d1b, bf16_t* __restrict__ Cc,
    const bf16_t* __restrict__ we1, const float* __restrict__ eb1,
    bf16_t* __restrict__ mo,
    const int* __restrict__ ntl, const int* __restrict__ t_e,
    const int* __restrict__ t_row, const int* __restrict__ idx,
    const bf16_t* __restrict__ wsin, const float* __restrict__ sbin,
    bf16_t* __restrict__ th) {
  __shared__ __align__(16) char lds[32768];
  const int b = blockIdx.x;
  if (b < 4096) {
    dev_gemm_fc1(lds, b, xb, wd1, wd1 + (size_t)HDIM * DDIM, Cc, d1b, d1b + HDIM,
                 HDIM, DDIM);
  } else if (b < 5184) {
    dev_moe_fc1(lds, b - 4096, xb, we1, (size_t)2 * HEXP * DDIM, mo, eb1, 2 * HEXP,
                ntl, t_e, t_row, idx, HEXP, DDIM);
  } else {
    dev_gemm<EPI_BF16>(lds, b - 5184, 8, 64, xb, wsin, th, nullptr, sbin,
                       nullptr, 0, SDIM, DDIM);
  }
}

// ---------------- phase 2: d2 | conv | moe fc2 ----------------
__global__ __launch_bounds__(256) void k_phase2(
    const bf16_t* __restrict__ Cc, const bf16_t* __restrict__ wd2,
    const float* __restrict__ d2b, const float* __restrict__ bw3,
    float* __restrict__ out,
    const bf16_t* __restrict__ th, const bf16_t* __restrict__ wconv,
    const float* __restrict__ sbc, bf16_t* __restrict__ tsq,
    const bf16_t* __restrict__ zpad,
    const bf16_t* __restrict__ mo, const bf16_t* __restrict__ we2,
    const float* __restrict__ eb2, bf16_t* __restrict__ eo,
    const int* __restrict__ ntl, const int* __restrict__ t_e,
    const int* __restrict__ t_row) {
  __shared__ __align__(16) char lds[32768];
  const int b = blockIdx.x;
  if (b < 512) {
    dev_gemm<EPI_OUT_W>(lds, b, 8, 64, Cc, wd2, nullptr, out, d2b, bw3, 3,
                        DDIM, HDIM);
  } else if (b < 1024) {
    dev_gemm_conv(lds, b - 512, th, wconv, tsq, sbc, zpad);
  } else {
    dev_moe_fc2(lds, b - 1024, mo, we2, (size_t)DDIM * HEXP, eo, eb2, DDIM,
                ntl, t_e, t_row, DDIM, HEXP);
  }
}

// ---------------- wsout (standalone: += out, must not overlap combine) ----------------
__global__ __launch_bounds__(256) void k_wsout(
    const bf16_t* __restrict__ tsq, const bf16_t* __restrict__ wsout,
    float* __restrict__ out, const float* __restrict__ sbo,
    const float* __restrict__ bw3) {
  __shared__ __align__(16) char lds[32768];
  dev_gemm<EPI_OUT_A>(lds, blockIdx.x, 8, 64, tsq, wsout, nullptr, out, sbo,
                      bw3 + 1, 3, DDIM, SDIM);
}

// ---------------- MoE combine: out[t] += g0*eo[s0] + g1*eo[s1] ----------------
__global__ __launch_bounds__(256) void k_combine(const bf16_t* __restrict__ eo,
                                                 const int* __restrict__ slotmap,
                                                 const float* __restrict__ top2w,
                                                 float* __restrict__ out) {
  int wave = threadIdx.x >> 6, lane = threadIdx.x & 63;
  int t = blockIdx.x * 4 + wave;
  const int s0 = slotmap[t * 2 + 0], s1 = slotmap[t * 2 + 1];
  const float g0 = top2w[t * 2 + 0], g1 = top2w[t * 2 + 1];
  const bf16x8* r0 = (const bf16x8*)(eo + (size_t)s0 * DDIM);
  const bf16x8* r1 = (const bf16x8*)(eo + (size_t)s1 * DDIM);
  float* orow = out + (size_t)t * DDIM;
#pragma unroll
  for (int i = 0; i < 2; ++i) {
    const int d = lane + i * 64;
    bf16x8 a = r0[d], b = r1[d];
    float vo[8];
    *(float4*)&vo[0] = *(const float4*)&orow[d * 8];
    *(float4*)&vo[4] = *(const float4*)&orow[d * 8 + 4];
#pragma unroll
    for (int j = 0; j < 8; ++j) vo[j] += g0 * (float)a[j] + g1 * (float)b[j];
    *(float4*)&orow[d * 8] = *(float4*)&vo[0];
    *(float4*)&orow[d * 8 + 4] = *(float4*)&vo[4];
  }
}

// ---------------------------------------------------------------------------
extern "C" void kernel_launch(void* const* d_in, const int* in_sizes, int n_in,
                              void* d_out, int out_size, void* d_ws, size_t ws_size,
                              hipStream_t stream) {
  (void)in_sizes; (void)n_in; (void)out_size; (void)ws_size;
  const float* x    = (const float*)d_in[0];
  const float* rW   = (const float*)d_in[1];
  const float* rb   = (const float*)d_in[2];
  const float* d1W  = (const float*)d_in[3];
  const float* d1b  = (const float*)d_in[4];
  const float* d2W  = (const float*)d_in[5];
  const float* d2b  = (const float*)d_in[6];
  const float* sWin = (const float*)d_in[7];
  const float* sbin = (const float*)d_in[8];
  const float* sWc  = (const float*)d_in[9];
  const float* sbc  = (const float*)d_in[10];
  const float* sWo  = (const float*)d_in[11];
  const float* sbo  = (const float*)d_in[12];
  const float* mW   = (const float*)d_in[13];
  const float* mb   = (const float*)d_in[14];
  const float* eW1  = (const float*)d_in[15];
  const float* eb1  = (const float*)d_in[16];
  const float* eW2  = (const float*)d_in[17];
  const float* eb2  = (const float*)d_in[18];
  float* out = (float*)d_out;

  char* ws = (char*)d_ws;
  size_t off = 0;
  auto alloc = [&](size_t bytes) -> void* {
    void* p = ws + off;
    off += (bytes + 255) & ~(size_t)255;
    return p;
  };
  bf16_t* xb    = (bf16_t*)alloc((size_t)NTOK * DDIM * 2);
  bf16_t* wd1   = (bf16_t*)alloc((size_t)2 * HDIM * DDIM * 2);
  bf16_t* wd2   = (bf16_t*)alloc((size_t)DDIM * HDIM * 2);
  bf16_t* wsin  = (bf16_t*)alloc((size_t)SDIM * DDIM * 2);
  bf16_t* wconv = (bf16_t*)alloc((size_t)SDIM * SDIM * 4 * 2);
  bf16_t* wsout = (bf16_t*)alloc((size_t)DDIM * SDIM * 2);
  bf16_t* we1   = (bf16_t*)alloc((size_t)NEXP * 2 * HEXP * DDIM * 2);
  bf16_t* we2   = (bf16_t*)alloc((size_t)NEXP * DDIM * HEXP * 2);
  bf16_t* Cc    = (bf16_t*)alloc((size_t)NTOK * HDIM * 2);
  bf16_t* Dd    = (bf16_t*)alloc((size_t)NTOK * HDIM * 2);  // eo [0,35.7MB) | mo @36MB
  bf16_t* th    = (bf16_t*)alloc((size_t)NTOK * SDIM * 2);
  bf16_t* tsq   = (bf16_t*)alloc((size_t)NTOK * SDIM * 2);
  float*  bw3   = (float*)alloc((size_t)NTOK * 3 * 4);
  int*    top2e = (int*)alloc((size_t)NTOK * 2 * 4);
  float*  top2w = (float*)alloc((size_t)NTOK * 2 * 4);
  int*    slotm = (int*)alloc((size_t)NTOK * 2 * 4);
  int*    fill  = (int*)alloc(NEXP * 4);
  int*    basep = (int*)alloc((NEXP + 1) * 4);
  int*    ntl   = (int*)alloc(4);
  int*    t_e   = (int*)alloc(MAXTILES * 4);
  int*    t_row = (int*)alloc(MAXTILES * 4);
  int*    idx   = (int*)alloc(MAXROWS * 4);
  bf16_t* zpad  = (bf16_t*)alloc(256);
  bf16_t* eo = Dd;
  bf16_t* mo = Dd + (size_t)18 * 1024 * 1024;

  k_setup<<<21572, 256, 0, stream>>>(
      x, d1W, d2W, sWin, sWo, eW1, eW2, sWc, rW, rb, mW, mb,
      xb, wd1, wd2, wsin, wsout, we1, we2, wconv,
      bw3, top2e, top2w, fill, idx, zpad);
  k_count_scan<<<1, 1024, 0, stream>>>(top2e, basep, ntl, t_e, t_row);
  k_scatter<<<NTOK / 256, 256, 0, stream>>>(top2e, top2w, basep, fill, idx, slotm);

  k_phase1<<<5696, 256, 0, stream>>>(
      xb, wd1, d1b, Cc, we1, eb1, mo, ntl, t_e, t_row, idx, wsin, sbin, th);
  k_phase2<<<2112, 256, 0, stream>>>(
      Cc, wd2, d2b, bw3, out, th, wconv, sbc, tsq, zpad,
      mo, we2, eb2, eo, ntl, t_e, t_row);
  k_wsout<<<512, 256, 0, stream>>>(tsq, wsout, out, sbo, bw3);
  k_combine<<<NTOK / 4, 256, 0, stream>>>(eo, slotm, top2w, out);
}